// Round 3
// baseline (3300.800 us; speedup 1.0000x reference)
//
#include <hip/hip_runtime.h>
#include <math.h>

#define DH 128
#define NRBF 16
#define EB 128   // edges per k_edge block

typedef unsigned short ushort_t;
typedef __attribute__((ext_vector_type(8))) short short8;
typedef __attribute__((ext_vector_type(4))) float floatx4;

__device__ __forceinline__ float silu_f(float v) {
    return v / (1.f + __expf(-v));
}

__device__ __forceinline__ unsigned short f2bf(float f) {
    unsigned int u = __float_as_uint(f);
    u += 0x7FFFu + ((u >> 16) & 1u);   // RNE
    return (unsigned short)(u >> 16);
}
__device__ __forceinline__ float bflo(unsigned u) { return __uint_as_float(u << 16); }
__device__ __forceinline__ float bfhi(unsigned u) { return __uint_as_float(u & 0xffff0000u); }

// Detect whether edge_index arrived as int64 (odd 32-bit words all zero) or int32.
__global__ void k_detect(const int* __restrict__ ei, int* __restrict__ flag) {
    if (threadIdx.x == 0) {
        int z = 0;
#pragma unroll
        for (int i = 0; i < 8; ++i) z |= ei[2 * i + 1];
        *flag = (z == 0) ? 1 : 0;
    }
}

__device__ __forceinline__ int load_dst(const int* ei, int is64, int e, int E) {
    return is64 ? ei[2 * E + 2 * e] : ei[E + e];
}
__device__ __forceinline__ int load_src(const int* ei, int is64, int e, int E) {
    return is64 ? ei[2 * e] : ei[e];
}

// ---------------- counting sort by dst ----------------
__global__ void k_hist(const int* __restrict__ ei, const int* __restrict__ flag,
                       int* __restrict__ counts, int E) {
    const int e = blockIdx.x * 256 + threadIdx.x;
    if (e < E) atomicAdd(&counts[load_dst(ei, *flag, e, E)], 1);
}

__global__ __launch_bounds__(1024) void k_scan(const int* __restrict__ counts,
                                               int* __restrict__ cursor, int N) {
    __shared__ int wsum[16];
    __shared__ int sCarry;
    const int tid = threadIdx.x, lane = tid & 63, wid = tid >> 6;
    if (tid == 0) sCarry = 0;
    __syncthreads();
    for (int c0 = 0; c0 < N; c0 += 1024) {
        const int i = c0 + tid;
        const int v = (i < N) ? counts[i] : 0;
        int incl = v;
#pragma unroll
        for (int d = 1; d < 64; d <<= 1) {
            int t = __shfl_up(incl, d, 64);
            if (lane >= d) incl += t;
        }
        if (lane == 63) wsum[wid] = incl;
        __syncthreads();
        if (wid == 0) {
            int s = (lane < 16) ? wsum[lane] : 0;
#pragma unroll
            for (int d = 1; d < 16; d <<= 1) {
                int t = __shfl_up(s, d, 64);
                if (lane >= d) s += t;
            }
            if (lane < 16) wsum[lane] = s;
        }
        __syncthreads();
        const int base = sCarry + (wid > 0 ? wsum[wid - 1] : 0);
        if (i < N) cursor[i] = base + incl - v;   // exclusive prefix
        __syncthreads();
        if (tid == 0) sCarry += wsum[15];
        __syncthreads();
    }
}

__global__ void k_scatter(const int* __restrict__ ei, const int* __restrict__ flag,
                          int* __restrict__ cursor, int* __restrict__ perm, int E) {
    const int e = blockIdx.x * 256 + threadIdx.x;
    if (e < E) {
        const int d = load_dst(ei, *flag, e, E);
        const int pos = atomicAdd(&cursor[d], 1);
        perm[pos] = e;
    }
}

// ---------------------------------------------------------------------------
// Pre-permute Wm2 into bf16 fragment-linear layout:
// W2f[u*8 + {0..7}] with u = (kc*4+lg)*128 + col holds
//   Wm2[kc*32+4lg+{0..3}][col] , Wm2[kc*32+16+4lg+{0..3}][col]
// ---------------------------------------------------------------------------
__global__ void k_w2f(const float* __restrict__ Wm2, ushort_t* __restrict__ W2f) {
    const int u = blockIdx.x * 256 + threadIdx.x;   // 0..2047
    const int col = u & 127, lgc = u >> 7;
    const int lg = lgc & 3, kc = lgc >> 2;
    unsigned o[4];
#pragma unroll
    for (int j = 0; j < 2; ++j) {
        o[j] = (unsigned)f2bf(Wm2[(kc * 32 + 4 * lg + 2 * j) * DH + col]) |
               ((unsigned)f2bf(Wm2[(kc * 32 + 4 * lg + 2 * j + 1) * DH + col]) << 16);
        o[2 + j] = (unsigned)f2bf(Wm2[(kc * 32 + 16 + 4 * lg + 2 * j) * DH + col]) |
                   ((unsigned)f2bf(Wm2[(kc * 32 + 16 + 4 * lg + 2 * j + 1) * DH + col]) << 16);
    }
    *(uint4*)(W2f + 8 * u) = make_uint4(o[0], o[1], o[2], o[3]);
}

// ---------------------------------------------------------------------------
// Kernel 1: A = h @ Wm1[0:128,:] + bm1 ; B = h @ Wm1[128:256,:]  -> bf16
// ---------------------------------------------------------------------------
__global__ __launch_bounds__(256) void k_precompute_ab(
    const float* __restrict__ h, const float* __restrict__ Wm1, const float* __restrict__ bm1,
    ushort_t* __restrict__ Abf, ushort_t* __restrict__ Bbf, int N)
{
    __shared__ float sH[DH][36];
    __shared__ float sW[16][256];
    const int tid = threadIdx.x;
    const int n0 = blockIdx.x * 32;

    {
        const int n = tid >> 3;
        const int c0 = (tid & 7) * 16;
        const int gn = n0 + n;
#pragma unroll
        for (int i = 0; i < 4; ++i) {
            float4 v = make_float4(0.f, 0.f, 0.f, 0.f);
            if (gn < N) v = *(const float4*)(h + (size_t)gn * DH + c0 + 4 * i);
            sH[c0 + 4 * i + 0][n] = v.x;
            sH[c0 + 4 * i + 1][n] = v.y;
            sH[c0 + 4 * i + 2][n] = v.z;
            sH[c0 + 4 * i + 3][n] = v.w;
        }
    }

    const int ng = tid & 7;
    const int jg = tid >> 3;
    const int sr = tid >> 4;
    const int sc = (tid & 15) * 16;

    float acc[4][8];
#pragma unroll
    for (int i = 0; i < 4; ++i)
#pragma unroll
        for (int j = 0; j < 8; ++j) acc[i][j] = 0.f;

    float4 rw[4];
#pragma unroll
    for (int i = 0; i < 4; ++i) {
        const int c = sc + 4 * i;
        const float* p = (c < DH) ? (Wm1 + (size_t)sr * DH + c)
                                  : (Wm1 + (size_t)(DH + sr) * DH + (c - DH));
        rw[i] = *(const float4*)p;
    }

    for (int t = 0; t < 8; ++t) {
        __syncthreads();
#pragma unroll
        for (int i = 0; i < 4; ++i) *(float4*)&sW[sr][sc + 4 * i] = rw[i];
        __syncthreads();
        if (t < 7) {
            const int k0 = 16 * (t + 1);
#pragma unroll
            for (int i = 0; i < 4; ++i) {
                const int c = sc + 4 * i;
                const float* p = (c < DH) ? (Wm1 + (size_t)(k0 + sr) * DH + c)
                                          : (Wm1 + (size_t)(DH + k0 + sr) * DH + (c - DH));
                rw[i] = *(const float4*)p;
            }
        }
#pragma unroll
        for (int kk = 0; kk < 16; ++kk) {
            const float4 a  = *(const float4*)&sH[t * 16 + kk][ng * 4];
            const float4 b0 = *(const float4*)&sW[kk][jg * 8];
            const float4 b1 = *(const float4*)&sW[kk][jg * 8 + 4];
            const float av[4] = {a.x, a.y, a.z, a.w};
            const float bv[8] = {b0.x, b0.y, b0.z, b0.w, b1.x, b1.y, b1.z, b1.w};
#pragma unroll
            for (int i = 0; i < 4; ++i)
#pragma unroll
                for (int j = 0; j < 8; ++j)
                    acc[i][j] = fmaf(av[i], bv[j], acc[i][j]);
        }
    }

    const int j0 = jg * 8;
#pragma unroll
    for (int i = 0; i < 4; ++i) {
        const int gn = n0 + ng * 4 + i;
        if (gn >= N) continue;
        float o[8];
        if (j0 < DH) {
#pragma unroll
            for (int j = 0; j < 8; ++j) o[j] = acc[i][j] + bm1[j0 + j];
            uint2 p0, p1;
            p0.x = (unsigned)f2bf(o[0]) | ((unsigned)f2bf(o[1]) << 16);
            p0.y = (unsigned)f2bf(o[2]) | ((unsigned)f2bf(o[3]) << 16);
            p1.x = (unsigned)f2bf(o[4]) | ((unsigned)f2bf(o[5]) << 16);
            p1.y = (unsigned)f2bf(o[6]) | ((unsigned)f2bf(o[7]) << 16);
            *(uint2*)(Abf + (size_t)gn * DH + j0) = p0;
            *(uint2*)(Abf + (size_t)gn * DH + j0 + 4) = p1;
        } else {
            const int jb = j0 - DH;
            uint2 p0, p1;
            p0.x = (unsigned)f2bf(acc[i][0]) | ((unsigned)f2bf(acc[i][1]) << 16);
            p0.y = (unsigned)f2bf(acc[i][2]) | ((unsigned)f2bf(acc[i][3]) << 16);
            p1.x = (unsigned)f2bf(acc[i][4]) | ((unsigned)f2bf(acc[i][5]) << 16);
            p1.y = (unsigned)f2bf(acc[i][6]) | ((unsigned)f2bf(acc[i][7]) << 16);
            *(uint2*)(Bbf + (size_t)gn * DH + jb) = p0;
            *(uint2*)(Bbf + (size_t)gn * DH + jb + 4) = p1;
        }
    }
}

// ---------------------------------------------------------------------------
// Kernel 2: register-direct edge kernel.
// Each lane builds its own MFMA A-fragments (no LDS round-trip for hidden):
//   lane(lr,lg) of wave wv handles edges m0+mi*16+lr, k in {32kc+4lg+j, 32kc+16+4lg+j}
// hidden = silu(A[src]+B[dst]+rbf@W1c)  (bf16 gathers, fp32 math)
// m = (hidden @ Wm2 + bm2) * ew via MFMA; run-merged atomicAdd into agg.
// ---------------------------------------------------------------------------
__global__ __launch_bounds__(256, 3) void k_edge(
    const float* __restrict__ x, const int* __restrict__ ei, const float* __restrict__ ew,
    const float* __restrict__ Wm1, const ushort_t* __restrict__ W2f, const float* __restrict__ bm2,
    const ushort_t* __restrict__ Abf, const ushort_t* __restrict__ Bbf,
    float* __restrict__ agg, const int* __restrict__ flag,
    const int* __restrict__ perm, int use_perm, int N, int E)
{
    __shared__ float    sW1c[NRBF][DH];   // 8 KB: Wm1 rows 256..271 (rbf part)
    __shared__ ushort_t sW2f[16384];      // 32 KB: fragment-linear bf16 Wm2
    __shared__ int   sSrc[EB];
    __shared__ int   sDst[EB];
    __shared__ float sEw[EB];

    const int tid = threadIdx.x;
    const int e0 = blockIdx.x * EB;

    // stage rbf weight rows (fp32) : 512 float4
    {
        const float4* s4 = (const float4*)(Wm1 + 256 * DH);
        float4* d4 = (float4*)&sW1c[0][0];
        d4[tid] = s4[tid];
        d4[tid + 256] = s4[tid + 256];
    }
    // stage pre-permuted Wm2 : 2048 uint4
    {
        const uint4* s4 = (const uint4*)W2f;
        uint4* d4 = (uint4*)sW2f;
#pragma unroll
        for (int i = 0; i < 8; ++i) d4[tid + 256 * i] = s4[tid + 256 * i];
    }
    if (tid < EB) {
        const int slot = e0 + tid;
        int s = 0, d = 0;
        float w = 0.f;
        if (slot < E) {
            const int e = use_perm ? perm[slot] : slot;
            const int is64 = *flag;
            s = load_src(ei, is64, e, E);
            d = load_dst(ei, is64, e, E);
            w = ew[e];
        }
        sSrc[tid] = s; sDst[tid] = d; sEw[tid] = w;
    }
    __syncthreads();

    const int lane = tid & 63;
    const int wv   = tid >> 6;
    const int m0   = wv * 32;
    const int lr   = lane & 15;
    const int lg   = lane >> 4;

    // ---- phase 1: build A-fragments directly in registers ----
    union FragU { unsigned u[4]; short8 s8; };
    FragU afrag[2][4];

#pragma unroll
    for (int mi = 0; mi < 2; ++mi) {
        const int e = m0 + mi * 16 + lr;
        const int s = sSrc[e], d = sDst[e];
        const ushort_t* Ap = Abf + (size_t)s * DH + 4 * lg;
        const ushort_t* Bp = Bbf + (size_t)d * DH + 4 * lg;

        float4 hv[8];
#pragma unroll
        for (int g = 0; g < 8; ++g) {
            const int k0 = (g >> 1) * 32 + (g & 1) * 16;   // + 4*lg folded into Ap/Bp
            const uint2 av = *(const uint2*)(Ap + k0);
            const uint2 bv = *(const uint2*)(Bp + k0);
            hv[g] = make_float4(bflo(av.x) + bflo(bv.x), bfhi(av.x) + bfhi(bv.x),
                                bflo(av.y) + bflo(bv.y), bfhi(av.y) + bfhi(bv.y));
        }

        const float2 xs = *(const float2*)(x + 2 * s);
        const float2 xd = *(const float2*)(x + 2 * d);
        const float dxv = xs.x - xd.x, dyv = xs.y - xd.y;
        const float r = sqrtf(dxv * dxv + dyv * dyv + 1e-8f);
        const float WIDTH = 0.09428090415820634f;  // sqrt(2)/15
        const float GAMMA = 56.25f;                // 1/(2*WIDTH^2)
        float rb[NRBF];
#pragma unroll
        for (int q = 0; q < NRBF; ++q) {
            const float t = r - (float)q * WIDTH;
            rb[q] = __expf(-GAMMA * t * t);
        }
#pragma unroll
        for (int q = 0; q < NRBF; ++q) {
            const float rq = rb[q];
#pragma unroll
            for (int g = 0; g < 8; ++g) {
                const int k0 = (g >> 1) * 32 + (g & 1) * 16 + 4 * lg;
                const float4 w4 = *(const float4*)&sW1c[q][k0];  // broadcast read
                hv[g].x = fmaf(rq, w4.x, hv[g].x);
                hv[g].y = fmaf(rq, w4.y, hv[g].y);
                hv[g].z = fmaf(rq, w4.z, hv[g].z);
                hv[g].w = fmaf(rq, w4.w, hv[g].w);
            }
        }
#pragma unroll
        for (int kc = 0; kc < 4; ++kc) {
            const float4 a = hv[2 * kc];
            const float4 b = hv[2 * kc + 1];
            afrag[mi][kc].u[0] = (unsigned)f2bf(silu_f(a.x)) | ((unsigned)f2bf(silu_f(a.y)) << 16);
            afrag[mi][kc].u[1] = (unsigned)f2bf(silu_f(a.z)) | ((unsigned)f2bf(silu_f(a.w)) << 16);
            afrag[mi][kc].u[2] = (unsigned)f2bf(silu_f(b.x)) | ((unsigned)f2bf(silu_f(b.y)) << 16);
            afrag[mi][kc].u[3] = (unsigned)f2bf(silu_f(b.z)) | ((unsigned)f2bf(silu_f(b.w)) << 16);
        }
    }

    // ---- phase 2: MFMA  C[128e][128j] = hid @ Wm2 ----
    floatx4 acc[2][8];
#pragma unroll
    for (int mi = 0; mi < 2; ++mi)
#pragma unroll
        for (int ni = 0; ni < 8; ++ni) acc[mi][ni] = (floatx4){0.f, 0.f, 0.f, 0.f};

#pragma unroll
    for (int kc = 0; kc < 4; ++kc) {
        const ushort_t* wbase = sW2f + ((size_t)(kc * 4 + lg) * 128 + lr) * 8;
        __builtin_amdgcn_s_setprio(1);
#pragma unroll
        for (int ni = 0; ni < 8; ++ni) {
            const short8 bf = *(const short8*)(wbase + ni * 128);
            acc[0][ni] = __builtin_amdgcn_mfma_f32_16x16x32_bf16(afrag[0][kc].s8, bf, acc[0][ni], 0, 0, 0);
            acc[1][ni] = __builtin_amdgcn_mfma_f32_16x16x32_bf16(afrag[1][kc].s8, bf, acc[1][ni], 0, 0, 0);
        }
        __builtin_amdgcn_s_setprio(0);
    }

    // ---- phase 3: bias, edge-weight, run-merged atomic scatter ----
    // C layout: col = ni*16 + lr ; edge slot = m0 + mi*16 + 4*lg + r
#pragma unroll
    for (int ni = 0; ni < 8; ++ni) {
        const int col = ni * 16 + lr;
        const float bc = bm2[col];
#pragma unroll
        for (int mi = 0; mi < 2; ++mi) {
            const int sbase = m0 + mi * 16 + 4 * lg;
            int cur = sDst[sbase];
            float av = (acc[mi][ni][0] + bc) * sEw[sbase];
#pragma unroll
            for (int r = 1; r < 4; ++r) {
                const int d = sDst[sbase + r];
                const float v = (acc[mi][ni][r] + bc) * sEw[sbase + r];
                if (d == cur) av += v;
                else {
                    atomicAdd(agg + (size_t)cur * DH + col, av);
                    cur = d; av = v;
                }
            }
            atomicAdd(agg + (size_t)cur * DH + col, av);
        }
    }
}

// ---------------------------------------------------------------------------
// Kernel 3: node MLP + residual + LayerNorm. 32 nodes/block, 256 threads.
// ---------------------------------------------------------------------------
__global__ __launch_bounds__(256) void k_node(
    const float* __restrict__ h, const float* __restrict__ agg,
    const float* __restrict__ Wh1, const float* __restrict__ bh1,
    const float* __restrict__ Wh2, const float* __restrict__ bh2,
    const float* __restrict__ ln_g, const float* __restrict__ ln_b,
    float* __restrict__ out, int N)
{
    __shared__ float sU[2 * DH][36];
    __shared__ float sHid[DH][36];
    __shared__ float sW[16][DH];
    __shared__ float sMean[32], sRstd[32];
    const int tid = threadIdx.x;
    const int n0 = blockIdx.x * 32;

    {
        const int n = tid >> 3;
        const int c0 = (tid & 7) * 16;
        const int gn = n0 + n;
#pragma unroll
        for (int i = 0; i < 4; ++i) {
            float4 v = make_float4(0.f, 0.f, 0.f, 0.f);
            if (gn < N) v = *(const float4*)(h + (size_t)gn * DH + c0 + 4 * i);
            sU[c0 + 4 * i + 0][n] = v.x; sU[c0 + 4 * i + 1][n] = v.y;
            sU[c0 + 4 * i + 2][n] = v.z; sU[c0 + 4 * i + 3][n] = v.w;
        }
#pragma unroll
        for (int i = 0; i < 4; ++i) {
            float4 v = make_float4(0.f, 0.f, 0.f, 0.f);
            if (gn < N) v = *(const float4*)(agg + (size_t)gn * DH + c0 + 4 * i);
            sU[DH + c0 + 4 * i + 0][n] = v.x; sU[DH + c0 + 4 * i + 1][n] = v.y;
            sU[DH + c0 + 4 * i + 2][n] = v.z; sU[DH + c0 + 4 * i + 3][n] = v.w;
        }
    }

    const int ng = tid & 7;
    const int jg = tid >> 3;
    const int sr = tid >> 4;
    const int sc = (tid & 15) * 8;

    float acc[4][4];
#pragma unroll
    for (int i = 0; i < 4; ++i)
#pragma unroll
        for (int j = 0; j < 4; ++j) acc[i][j] = 0.f;

    float4 rw[2];
    rw[0] = *(const float4*)(Wh1 + (size_t)sr * DH + sc);
    rw[1] = *(const float4*)(Wh1 + (size_t)sr * DH + sc + 4);
    for (int t = 0; t < 16; ++t) {
        __syncthreads();
        *(float4*)&sW[sr][sc]     = rw[0];
        *(float4*)&sW[sr][sc + 4] = rw[1];
        __syncthreads();
        if (t < 15) {
            const int k0 = 16 * (t + 1);
            rw[0] = *(const float4*)(Wh1 + (size_t)(k0 + sr) * DH + sc);
            rw[1] = *(const float4*)(Wh1 + (size_t)(k0 + sr) * DH + sc + 4);
        }
#pragma unroll
        for (int kk = 0; kk < 16; ++kk) {
            const float4 a = *(const float4*)&sU[t * 16 + kk][ng * 4];
            const float4 b = *(const float4*)&sW[kk][jg * 4];
            const float av[4] = {a.x, a.y, a.z, a.w};
            const float bv[4] = {b.x, b.y, b.z, b.w};
#pragma unroll
            for (int i = 0; i < 4; ++i)
#pragma unroll
                for (int j = 0; j < 4; ++j)
                    acc[i][j] = fmaf(av[i], bv[j], acc[i][j]);
        }
    }
#pragma unroll
    for (int jj = 0; jj < 4; ++jj) {
        const float bb = bh1[jg * 4 + jj];
#pragma unroll
        for (int i = 0; i < 4; ++i)
            sHid[jg * 4 + jj][ng * 4 + i] = silu_f(acc[i][jj] + bb);
    }

    float acc2[4][4];
#pragma unroll
    for (int i = 0; i < 4; ++i)
#pragma unroll
        for (int j = 0; j < 4; ++j) acc2[i][j] = 0.f;

    rw[0] = *(const float4*)(Wh2 + (size_t)sr * DH + sc);
    rw[1] = *(const float4*)(Wh2 + (size_t)sr * DH + sc + 4);
    for (int t = 0; t < 8; ++t) {
        __syncthreads();
        *(float4*)&sW[sr][sc]     = rw[0];
        *(float4*)&sW[sr][sc + 4] = rw[1];
        __syncthreads();
        if (t < 7) {
            const int k0 = 16 * (t + 1);
            rw[0] = *(const float4*)(Wh2 + (size_t)(k0 + sr) * DH + sc);
            rw[1] = *(const float4*)(Wh2 + (size_t)(k0 + sr) * DH + sc + 4);
        }
#pragma unroll
        for (int kk = 0; kk < 16; ++kk) {
            const float4 a = *(const float4*)&sHid[t * 16 + kk][ng * 4];
            const float4 b = *(const float4*)&sW[kk][jg * 4];
            const float av[4] = {a.x, a.y, a.z, a.w};
            const float bv[4] = {b.x, b.y, b.z, b.w};
#pragma unroll
            for (int i = 0; i < 4; ++i)
#pragma unroll
                for (int j = 0; j < 4; ++j)
                    acc2[i][j] = fmaf(av[i], bv[j], acc2[i][j]);
        }
    }

#pragma unroll
    for (int jj = 0; jj < 4; ++jj) {
        const float bb = bh2[jg * 4 + jj];
#pragma unroll
        for (int i = 0; i < 4; ++i) {
            const int gn = n0 + ng * 4 + i;
            float hv = 0.f;
            if (gn < N) hv = h[(size_t)gn * DH + jg * 4 + jj];
            sU[jg * 4 + jj][ng * 4 + i] = acc2[i][jj] + bb + hv;
        }
    }
    __syncthreads();

    {
        const int n = tid >> 3, sub = tid & 7;
        float s1 = 0.f, s2 = 0.f;
#pragma unroll
        for (int i = 0; i < 16; ++i) {
            const float z = sU[sub + 8 * i][n];
            s1 += z; s2 += z * z;
        }
#pragma unroll
        for (int m = 1; m < 8; m <<= 1) {
            s1 += __shfl_xor(s1, m, 64);
            s2 += __shfl_xor(s2, m, 64);
        }
        if (sub == 0) {
            const float mean = s1 * (1.f / 128.f);
            const float var = s2 * (1.f / 128.f) - mean * mean;
            sMean[n] = mean;
            sRstd[n] = rsqrtf(var + 1e-5f);
        }
    }
    __syncthreads();
    {
        const int n = tid >> 3, c0 = (tid & 7) * 16;
        const int gn = n0 + n;
        if (gn < N) {
            const float mean = sMean[n], rstd = sRstd[n];
#pragma unroll
            for (int i = 0; i < 4; ++i) {
                const float4 g4 = *(const float4*)(ln_g + c0 + 4 * i);
                const float4 b4 = *(const float4*)(ln_b + c0 + 4 * i);
                float4 o;
                o.x = (sU[c0 + 4 * i + 0][n] - mean) * rstd * g4.x + b4.x;
                o.y = (sU[c0 + 4 * i + 1][n] - mean) * rstd * g4.y + b4.y;
                o.z = (sU[c0 + 4 * i + 2][n] - mean) * rstd * g4.z + b4.z;
                o.w = (sU[c0 + 4 * i + 3][n] - mean) * rstd * g4.w + b4.w;
                *(float4*)(out + (size_t)gn * DH + c0 + 4 * i) = o;
            }
        }
    }
}

extern "C" void kernel_launch(void* const* d_in, const int* in_sizes, int n_in,
                              void* d_out, int out_size, void* d_ws, size_t ws_size,
                              hipStream_t stream)
{
    (void)n_in; (void)out_size;
    const float* h   = (const float*)d_in[0];
    const float* x   = (const float*)d_in[1];
    const int*   ei  = (const int*)d_in[2];
    const float* ew  = (const float*)d_in[3];
    const float* Wm1 = (const float*)d_in[4];
    const float* bm1 = (const float*)d_in[5];
    const float* Wm2 = (const float*)d_in[6];
    const float* bm2 = (const float*)d_in[7];
    const float* Wh1 = (const float*)d_in[8];
    const float* bh1 = (const float*)d_in[9];
    const float* Wh2 = (const float*)d_in[10];
    const float* bh2 = (const float*)d_in[11];
    const float* lng = (const float*)d_in[12];
    const float* lnb = (const float*)d_in[13];
    float* out = (float*)d_out;

    const int N = in_sizes[0] / DH;
    const int E = in_sizes[3];

    float*    agg = (float*)d_ws;
    ushort_t* Abf = (ushort_t*)(agg + (size_t)N * DH);
    ushort_t* Bbf = Abf + (size_t)N * DH;
    ushort_t* W2f = Bbf + (size_t)N * DH;
    int* counts = (int*)(W2f + 16384);
    int* cursor = counts + N;
    int* perm   = cursor + N;
    int* flag   = perm + E;

    const size_t need = (size_t)N * DH * 8 + 32768 + (size_t)(2 * N + E + 1) * 4;
    const int use_sort = (ws_size >= need) ? 1 : 0;
    if (!use_sort) flag = counts;  // minimal layout (no sort arrays)

    hipMemsetAsync(agg, 0, (size_t)N * DH * sizeof(float), stream);
    k_detect<<<1, 64, 0, stream>>>(ei, flag);
    if (use_sort) {
        hipMemsetAsync(counts, 0, (size_t)N * sizeof(int), stream);
        k_hist<<<(E + 255) / 256, 256, 0, stream>>>(ei, flag, counts, E);
        k_scan<<<1, 1024, 0, stream>>>(counts, cursor, N);
        k_scatter<<<(E + 255) / 256, 256, 0, stream>>>(ei, flag, cursor, perm, E);
    }
    k_w2f<<<8, 256, 0, stream>>>(Wm2, W2f);
    k_precompute_ab<<<(N + 31) / 32, 256, 0, stream>>>(h, Wm1, bm1, Abf, Bbf, N);
    k_edge<<<(E + EB - 1) / EB, 256, 0, stream>>>(x, ei, ew, Wm1, W2f, bm2, Abf, Bbf,
                                                  agg, flag, perm, use_sort, N, E);
    k_node<<<(N + 31) / 32, 256, 0, stream>>>(h, agg, Wh1, bh1, Wh2, bh2, lng, lnb, out, N);
}

// Round 4
// 686.962 us; speedup vs baseline: 4.8049x; 4.8049x over previous
//
#include <hip/hip_runtime.h>
#include <math.h>

#define DH 128
#define NRBF 16
#define EB 128   // edges per k_edge block

typedef unsigned short ushort_t;
typedef __attribute__((ext_vector_type(8))) short short8;
typedef __attribute__((ext_vector_type(4))) float floatx4;

__device__ __forceinline__ float silu_f(float v) {
    return v / (1.f + __expf(-v));
}

__device__ __forceinline__ unsigned short f2bf(float f) {
    unsigned int u = __float_as_uint(f);
    u += 0x7FFFu + ((u >> 16) & 1u);   // RNE
    return (unsigned short)(u >> 16);
}
__device__ __forceinline__ float bflo(unsigned u) { return __uint_as_float(u << 16); }
__device__ __forceinline__ float bfhi(unsigned u) { return __uint_as_float(u & 0xffff0000u); }

// Detect whether edge_index arrived as int64 (odd 32-bit words all zero) or int32.
__global__ void k_detect(const int* __restrict__ ei, int* __restrict__ flag) {
    if (threadIdx.x == 0) {
        int z = 0;
#pragma unroll
        for (int i = 0; i < 8; ++i) z |= ei[2 * i + 1];
        *flag = (z == 0) ? 1 : 0;
    }
}

__device__ __forceinline__ int load_dst(const int* ei, int is64, int e, int E) {
    return is64 ? ei[2 * E + 2 * e] : ei[E + e];
}
__device__ __forceinline__ int load_src(const int* ei, int is64, int e, int E) {
    return is64 ? ei[2 * e] : ei[e];
}

// ---------------- counting sort by dst ----------------
__global__ void k_hist(const int* __restrict__ ei, const int* __restrict__ flag,
                       int* __restrict__ counts, int E) {
    const int e = blockIdx.x * 256 + threadIdx.x;
    if (e < E) atomicAdd(&counts[load_dst(ei, *flag, e, E)], 1);
}

__global__ __launch_bounds__(1024) void k_scan(const int* __restrict__ counts,
                                               int* __restrict__ cursor, int N) {
    __shared__ int wsum[16];
    __shared__ int sCarry;
    const int tid = threadIdx.x, lane = tid & 63, wid = tid >> 6;
    if (tid == 0) sCarry = 0;
    __syncthreads();
    for (int c0 = 0; c0 < N; c0 += 1024) {
        const int i = c0 + tid;
        const int v = (i < N) ? counts[i] : 0;
        int incl = v;
#pragma unroll
        for (int d = 1; d < 64; d <<= 1) {
            int t = __shfl_up(incl, d, 64);
            if (lane >= d) incl += t;
        }
        if (lane == 63) wsum[wid] = incl;
        __syncthreads();
        if (wid == 0) {
            int s = (lane < 16) ? wsum[lane] : 0;
#pragma unroll
            for (int d = 1; d < 16; d <<= 1) {
                int t = __shfl_up(s, d, 64);
                if (lane >= d) s += t;
            }
            if (lane < 16) wsum[lane] = s;
        }
        __syncthreads();
        const int base = sCarry + (wid > 0 ? wsum[wid - 1] : 0);
        if (i < N) cursor[i] = base + incl - v;   // exclusive prefix
        __syncthreads();
        if (tid == 0) sCarry += wsum[15];
        __syncthreads();
    }
}

__global__ void k_scatter(const int* __restrict__ ei, const int* __restrict__ flag,
                          int* __restrict__ cursor, int* __restrict__ perm, int E) {
    const int e = blockIdx.x * 256 + threadIdx.x;
    if (e < E) {
        const int d = load_dst(ei, *flag, e, E);
        const int pos = atomicAdd(&cursor[d], 1);
        perm[pos] = e;
    }
}

// ---------------------------------------------------------------------------
// Pre-permute Wm2 into bf16 fragment-linear layout:
// W2f[u*8 + {0..7}] with u = (kc*4+lg)*128 + col holds
//   Wm2[kc*32+4lg+{0..3}][col] , Wm2[kc*32+16+4lg+{0..3}][col]
// ---------------------------------------------------------------------------
__global__ void k_w2f(const float* __restrict__ Wm2, ushort_t* __restrict__ W2f) {
    const int u = blockIdx.x * 256 + threadIdx.x;   // 0..2047
    const int col = u & 127, lgc = u >> 7;
    const int lg = lgc & 3, kc = lgc >> 2;
    unsigned o[4];
#pragma unroll
    for (int j = 0; j < 2; ++j) {
        o[j] = (unsigned)f2bf(Wm2[(kc * 32 + 4 * lg + 2 * j) * DH + col]) |
               ((unsigned)f2bf(Wm2[(kc * 32 + 4 * lg + 2 * j + 1) * DH + col]) << 16);
        o[2 + j] = (unsigned)f2bf(Wm2[(kc * 32 + 16 + 4 * lg + 2 * j) * DH + col]) |
                   ((unsigned)f2bf(Wm2[(kc * 32 + 16 + 4 * lg + 2 * j + 1) * DH + col]) << 16);
    }
    *(uint4*)(W2f + 8 * u) = make_uint4(o[0], o[1], o[2], o[3]);
}

// ---------------------------------------------------------------------------
// Kernel 1: A = h @ Wm1[0:128,:] + bm1 ; B = h @ Wm1[128:256,:]  -> bf16
// ---------------------------------------------------------------------------
__global__ __launch_bounds__(256) void k_precompute_ab(
    const float* __restrict__ h, const float* __restrict__ Wm1, const float* __restrict__ bm1,
    ushort_t* __restrict__ Abf, ushort_t* __restrict__ Bbf, int N)
{
    __shared__ float sH[DH][36];
    __shared__ float sW[16][256];
    const int tid = threadIdx.x;
    const int n0 = blockIdx.x * 32;

    {
        const int n = tid >> 3;
        const int c0 = (tid & 7) * 16;
        const int gn = n0 + n;
#pragma unroll
        for (int i = 0; i < 4; ++i) {
            float4 v = make_float4(0.f, 0.f, 0.f, 0.f);
            if (gn < N) v = *(const float4*)(h + (size_t)gn * DH + c0 + 4 * i);
            sH[c0 + 4 * i + 0][n] = v.x;
            sH[c0 + 4 * i + 1][n] = v.y;
            sH[c0 + 4 * i + 2][n] = v.z;
            sH[c0 + 4 * i + 3][n] = v.w;
        }
    }

    const int ng = tid & 7;
    const int jg = tid >> 3;
    const int sr = tid >> 4;
    const int sc = (tid & 15) * 16;

    float acc[4][8];
#pragma unroll
    for (int i = 0; i < 4; ++i)
#pragma unroll
        for (int j = 0; j < 8; ++j) acc[i][j] = 0.f;

    float4 rw[4];
#pragma unroll
    for (int i = 0; i < 4; ++i) {
        const int c = sc + 4 * i;
        const float* p = (c < DH) ? (Wm1 + (size_t)sr * DH + c)
                                  : (Wm1 + (size_t)(DH + sr) * DH + (c - DH));
        rw[i] = *(const float4*)p;
    }

    for (int t = 0; t < 8; ++t) {
        __syncthreads();
#pragma unroll
        for (int i = 0; i < 4; ++i) *(float4*)&sW[sr][sc + 4 * i] = rw[i];
        __syncthreads();
        if (t < 7) {
            const int k0 = 16 * (t + 1);
#pragma unroll
            for (int i = 0; i < 4; ++i) {
                const int c = sc + 4 * i;
                const float* p = (c < DH) ? (Wm1 + (size_t)(k0 + sr) * DH + c)
                                          : (Wm1 + (size_t)(DH + k0 + sr) * DH + (c - DH));
                rw[i] = *(const float4*)p;
            }
        }
#pragma unroll
        for (int kk = 0; kk < 16; ++kk) {
            const float4 a  = *(const float4*)&sH[t * 16 + kk][ng * 4];
            const float4 b0 = *(const float4*)&sW[kk][jg * 8];
            const float4 b1 = *(const float4*)&sW[kk][jg * 8 + 4];
            const float av[4] = {a.x, a.y, a.z, a.w};
            const float bv[8] = {b0.x, b0.y, b0.z, b0.w, b1.x, b1.y, b1.z, b1.w};
#pragma unroll
            for (int i = 0; i < 4; ++i)
#pragma unroll
                for (int j = 0; j < 8; ++j)
                    acc[i][j] = fmaf(av[i], bv[j], acc[i][j]);
        }
    }

    const int j0 = jg * 8;
#pragma unroll
    for (int i = 0; i < 4; ++i) {
        const int gn = n0 + ng * 4 + i;
        if (gn >= N) continue;
        float o[8];
        if (j0 < DH) {
#pragma unroll
            for (int j = 0; j < 8; ++j) o[j] = acc[i][j] + bm1[j0 + j];
            uint2 p0, p1;
            p0.x = (unsigned)f2bf(o[0]) | ((unsigned)f2bf(o[1]) << 16);
            p0.y = (unsigned)f2bf(o[2]) | ((unsigned)f2bf(o[3]) << 16);
            p1.x = (unsigned)f2bf(o[4]) | ((unsigned)f2bf(o[5]) << 16);
            p1.y = (unsigned)f2bf(o[6]) | ((unsigned)f2bf(o[7]) << 16);
            *(uint2*)(Abf + (size_t)gn * DH + j0) = p0;
            *(uint2*)(Abf + (size_t)gn * DH + j0 + 4) = p1;
        } else {
            const int jb = j0 - DH;
            uint2 p0, p1;
            p0.x = (unsigned)f2bf(acc[i][0]) | ((unsigned)f2bf(acc[i][1]) << 16);
            p0.y = (unsigned)f2bf(acc[i][2]) | ((unsigned)f2bf(acc[i][3]) << 16);
            p1.x = (unsigned)f2bf(acc[i][4]) | ((unsigned)f2bf(acc[i][5]) << 16);
            p1.y = (unsigned)f2bf(acc[i][6]) | ((unsigned)f2bf(acc[i][7]) << 16);
            *(uint2*)(Bbf + (size_t)gn * DH + jb) = p0;
            *(uint2*)(Bbf + (size_t)gn * DH + jb + 4) = p1;
        }
    }
}

// ---------------------------------------------------------------------------
// Kernel 2: edge kernel, LDS-staged hidden with XOR-swizzled [e][k] layout.
// Phase 1 (2 thr/edge, coalesced 16B gathers):
//   hidden = silu(A[src]+B[dst]+rbf@W1c) -> bf16 -> sHid (swizzled chunks)
// Phase 2: MFMA m = hidden @ Wm2 (pre-permuted W2f, conflict-free reads).
//   No barrier between phases: wave wv only reads edge rows it wrote.
// Phase 3: bias, edge-weight, run-merged atomicAdd into agg (sorted dst).
// ---------------------------------------------------------------------------
__global__ __launch_bounds__(256, 2) void k_edge(
    const float* __restrict__ x, const int* __restrict__ ei, const float* __restrict__ ew,
    const float* __restrict__ Wm1, const ushort_t* __restrict__ W2f, const float* __restrict__ bm2,
    const ushort_t* __restrict__ Abf, const ushort_t* __restrict__ Bbf,
    float* __restrict__ agg, const int* __restrict__ flag,
    const int* __restrict__ perm, int use_perm, int N, int E)
{
    __shared__ __align__(16) ushort_t sHid[EB * DH];  // 32 KB, [e][k] w/ chunk^= (e&7)
    __shared__ __align__(16) ushort_t sW2f[16384];    // 32 KB fragment-linear Wm2
    __shared__ float sW1c[NRBF][DH];                  // 8 KB rbf weight rows
    __shared__ int   sSrc[EB];
    __shared__ int   sDst[EB];
    __shared__ float sEw[EB];

    const int tid = threadIdx.x;
    const int e0 = blockIdx.x * EB;

    // stage rbf weight rows (fp32) : 512 float4
    {
        const float4* s4 = (const float4*)(Wm1 + 256 * DH);
        float4* d4 = (float4*)&sW1c[0][0];
        d4[tid] = s4[tid];
        d4[tid + 256] = s4[tid + 256];
    }
    // stage pre-permuted Wm2 : 2048 uint4
    {
        const uint4* s4 = (const uint4*)W2f;
        uint4* d4 = (uint4*)sW2f;
#pragma unroll
        for (int i = 0; i < 8; ++i) d4[tid + 256 * i] = s4[tid + 256 * i];
    }
    if (tid < EB) {
        const int slot = e0 + tid;
        int s = 0, d = 0;
        float w = 0.f;
        if (slot < E) {
            const int e = use_perm ? perm[slot] : slot;
            const int is64 = *flag;
            s = load_src(ei, is64, e, E);
            d = load_dst(ei, is64, e, E);
            w = ew[e];
        }
        sSrc[tid] = s; sDst[tid] = d; sEw[tid] = w;
    }
    __syncthreads();

    // ---- phase 1: build hidden. thread covers edge e = tid>>1, 64 cols ----
    {
        const int e  = tid >> 1;
        const int p  = tid & 1;           // half selector (cols p*64..p*64+63)
        const int s = sSrc[e], d = sDst[e];
        const uint4* pA = (const uint4*)(Abf + (size_t)s * DH + 64 * p);
        const uint4* pB = (const uint4*)(Bbf + (size_t)d * DH + 64 * p);
        uint4 ua[8], ub[8];
#pragma unroll
        for (int i = 0; i < 8; ++i) { ua[i] = pA[i]; ub[i] = pB[i]; }

        const float2 xs = *(const float2*)(x + 2 * s);
        const float2 xd = *(const float2*)(x + 2 * d);
        const float dxv = xs.x - xd.x, dyv = xs.y - xd.y;
        const float r = sqrtf(dxv * dxv + dyv * dyv + 1e-8f);
        const float WIDTH = 0.09428090415820634f;  // sqrt(2)/15
        const float GAMMA = 56.25f;                // 1/(2*WIDTH^2)
        float rb[NRBF];
#pragma unroll
        for (int q = 0; q < NRBF; ++q) {
            const float t = r - (float)q * WIDTH;
            rb[q] = __expf(-GAMMA * t * t);
        }

        float hv[8][8];
#pragma unroll
        for (int i = 0; i < 8; ++i) {
            hv[i][0] = bflo(ua[i].x) + bflo(ub[i].x);
            hv[i][1] = bfhi(ua[i].x) + bfhi(ub[i].x);
            hv[i][2] = bflo(ua[i].y) + bflo(ub[i].y);
            hv[i][3] = bfhi(ua[i].y) + bfhi(ub[i].y);
            hv[i][4] = bflo(ua[i].z) + bflo(ub[i].z);
            hv[i][5] = bfhi(ua[i].z) + bfhi(ub[i].z);
            hv[i][6] = bflo(ua[i].w) + bflo(ub[i].w);
            hv[i][7] = bfhi(ua[i].w) + bfhi(ub[i].w);
        }
#pragma unroll
        for (int q = 0; q < NRBF; ++q) {
            const float rq = rb[q];
#pragma unroll
            for (int i = 0; i < 8; ++i) {
                const float4 w0 = *(const float4*)&sW1c[q][64 * p + 8 * i];
                const float4 w1 = *(const float4*)&sW1c[q][64 * p + 8 * i + 4];
                hv[i][0] = fmaf(rq, w0.x, hv[i][0]);
                hv[i][1] = fmaf(rq, w0.y, hv[i][1]);
                hv[i][2] = fmaf(rq, w0.z, hv[i][2]);
                hv[i][3] = fmaf(rq, w0.w, hv[i][3]);
                hv[i][4] = fmaf(rq, w1.x, hv[i][4]);
                hv[i][5] = fmaf(rq, w1.y, hv[i][5]);
                hv[i][6] = fmaf(rq, w1.z, hv[i][6]);
                hv[i][7] = fmaf(rq, w1.w, hv[i][7]);
            }
        }
        // silu + pack + swizzled store (chunk index = 8p+i, XOR e&7)
        uint4* rowp = (uint4*)(sHid + e * DH);
        const int swz = e & 7;
#pragma unroll
        for (int i = 0; i < 8; ++i) {
            uint4 pk;
            pk.x = (unsigned)f2bf(silu_f(hv[i][0])) | ((unsigned)f2bf(silu_f(hv[i][1])) << 16);
            pk.y = (unsigned)f2bf(silu_f(hv[i][2])) | ((unsigned)f2bf(silu_f(hv[i][3])) << 16);
            pk.z = (unsigned)f2bf(silu_f(hv[i][4])) | ((unsigned)f2bf(silu_f(hv[i][5])) << 16);
            pk.w = (unsigned)f2bf(silu_f(hv[i][6])) | ((unsigned)f2bf(silu_f(hv[i][7])) << 16);
            rowp[(8 * p + i) ^ swz] = pk;
        }
    }
    // NO __syncthreads(): wave wv (tid 64wv..64wv+63) wrote edges 32wv..32wv+31
    // and below reads only edges m0..m0+31 = the same rows (in-wave lgkmcnt order).

    const int lane = tid & 63;
    const int wv   = tid >> 6;
    const int m0   = wv * 32;
    const int lr   = lane & 15;
    const int lg   = lane >> 4;

    // ---- phase 2: MFMA  C[128e][128j] = hid @ Wm2 ----
    floatx4 acc[2][8];
#pragma unroll
    for (int mi = 0; mi < 2; ++mi)
#pragma unroll
        for (int ni = 0; ni < 8; ++ni) acc[mi][ni] = (floatx4){0.f, 0.f, 0.f, 0.f};

    union FragU { unsigned u[4]; short8 s8; };

#pragma unroll
    for (int kc = 0; kc < 4; ++kc) {
        // A-fragment byte offsets within row: b1 = 64kc + 8lg, b2 = b1 + 32
        const int b1 = 64 * kc + 8 * lg;
        const int b2 = b1 + 32;
        FragU af[2];
#pragma unroll
        for (int mi = 0; mi < 2; ++mi) {
            const int e2 = m0 + mi * 16 + lr;
            const char* rbase = (const char*)(sHid + e2 * DH);
            const int swz = (e2 & 7) << 4;
            const uint2 lo = *(const uint2*)(rbase + ((b1 & ~15) ^ swz) + (b1 & 15));
            const uint2 hi = *(const uint2*)(rbase + ((b2 & ~15) ^ swz) + (b2 & 15));
            af[mi].u[0] = lo.x; af[mi].u[1] = lo.y;
            af[mi].u[2] = hi.x; af[mi].u[3] = hi.y;
        }
        const ushort_t* wbase = sW2f + ((size_t)(kc * 4 + lg) * 128 + lr) * 8;
        __builtin_amdgcn_s_setprio(1);
#pragma unroll
        for (int ni = 0; ni < 8; ++ni) {
            const short8 bf = *(const short8*)(wbase + ni * 128);
            acc[0][ni] = __builtin_amdgcn_mfma_f32_16x16x32_bf16(af[0].s8, bf, acc[0][ni], 0, 0, 0);
            acc[1][ni] = __builtin_amdgcn_mfma_f32_16x16x32_bf16(af[1].s8, bf, acc[1][ni], 0, 0, 0);
        }
        __builtin_amdgcn_s_setprio(0);
    }

    // ---- phase 3: bias, edge-weight, run-merged atomic scatter ----
    // C layout: col = ni*16 + lr ; edge slot = m0 + mi*16 + 4*lg + r
#pragma unroll
    for (int ni = 0; ni < 8; ++ni) {
        const int col = ni * 16 + lr;
        const float bc = bm2[col];
#pragma unroll
        for (int mi = 0; mi < 2; ++mi) {
            const int sbase = m0 + mi * 16 + 4 * lg;
            int cur = sDst[sbase];
            float av = (acc[mi][ni][0] + bc) * sEw[sbase];
#pragma unroll
            for (int r = 1; r < 4; ++r) {
                const int d = sDst[sbase + r];
                const float v = (acc[mi][ni][r] + bc) * sEw[sbase + r];
                if (d == cur) av += v;
                else {
                    atomicAdd(agg + (size_t)cur * DH + col, av);
                    cur = d; av = v;
                }
            }
            atomicAdd(agg + (size_t)cur * DH + col, av);
        }
    }
}

// ---------------------------------------------------------------------------
// Kernel 3: node MLP + residual + LayerNorm. 32 nodes/block, 256 threads.
// ---------------------------------------------------------------------------
__global__ __launch_bounds__(256) void k_node(
    const float* __restrict__ h, const float* __restrict__ agg,
    const float* __restrict__ Wh1, const float* __restrict__ bh1,
    const float* __restrict__ Wh2, const float* __restrict__ bh2,
    const float* __restrict__ ln_g, const float* __restrict__ ln_b,
    float* __restrict__ out, int N)
{
    __shared__ float sU[2 * DH][36];
    __shared__ float sHid[DH][36];
    __shared__ float sW[16][DH];
    __shared__ float sMean[32], sRstd[32];
    const int tid = threadIdx.x;
    const int n0 = blockIdx.x * 32;

    {
        const int n = tid >> 3;
        const int c0 = (tid & 7) * 16;
        const int gn = n0 + n;
#pragma unroll
        for (int i = 0; i < 4; ++i) {
            float4 v = make_float4(0.f, 0.f, 0.f, 0.f);
            if (gn < N) v = *(const float4*)(h + (size_t)gn * DH + c0 + 4 * i);
            sU[c0 + 4 * i + 0][n] = v.x; sU[c0 + 4 * i + 1][n] = v.y;
            sU[c0 + 4 * i + 2][n] = v.z; sU[c0 + 4 * i + 3][n] = v.w;
        }
#pragma unroll
        for (int i = 0; i < 4; ++i) {
            float4 v = make_float4(0.f, 0.f, 0.f, 0.f);
            if (gn < N) v = *(const float4*)(agg + (size_t)gn * DH + c0 + 4 * i);
            sU[DH + c0 + 4 * i + 0][n] = v.x; sU[DH + c0 + 4 * i + 1][n] = v.y;
            sU[DH + c0 + 4 * i + 2][n] = v.z; sU[DH + c0 + 4 * i + 3][n] = v.w;
        }
    }

    const int ng = tid & 7;
    const int jg = tid >> 3;
    const int sr = tid >> 4;
    const int sc = (tid & 15) * 8;

    float acc[4][4];
#pragma unroll
    for (int i = 0; i < 4; ++i)
#pragma unroll
        for (int j = 0; j < 4; ++j) acc[i][j] = 0.f;

    float4 rw[2];
    rw[0] = *(const float4*)(Wh1 + (size_t)sr * DH + sc);
    rw[1] = *(const float4*)(Wh1 + (size_t)sr * DH + sc + 4);
    for (int t = 0; t < 16; ++t) {
        __syncthreads();
        *(float4*)&sW[sr][sc]     = rw[0];
        *(float4*)&sW[sr][sc + 4] = rw[1];
        __syncthreads();
        if (t < 15) {
            const int k0 = 16 * (t + 1);
            rw[0] = *(const float4*)(Wh1 + (size_t)(k0 + sr) * DH + sc);
            rw[1] = *(const float4*)(Wh1 + (size_t)(k0 + sr) * DH + sc + 4);
        }
#pragma unroll
        for (int kk = 0; kk < 16; ++kk) {
            const float4 a = *(const float4*)&sU[t * 16 + kk][ng * 4];
            const float4 b = *(const float4*)&sW[kk][jg * 4];
            const float av[4] = {a.x, a.y, a.z, a.w};
            const float bv[4] = {b.x, b.y, b.z, b.w};
#pragma unroll
            for (int i = 0; i < 4; ++i)
#pragma unroll
                for (int j = 0; j < 4; ++j)
                    acc[i][j] = fmaf(av[i], bv[j], acc[i][j]);
        }
    }
#pragma unroll
    for (int jj = 0; jj < 4; ++jj) {
        const float bb = bh1[jg * 4 + jj];
#pragma unroll
        for (int i = 0; i < 4; ++i)
            sHid[jg * 4 + jj][ng * 4 + i] = silu_f(acc[i][jj] + bb);
    }

    float acc2[4][4];
#pragma unroll
    for (int i = 0; i < 4; ++i)
#pragma unroll
        for (int j = 0; j < 4; ++j) acc2[i][j] = 0.f;

    rw[0] = *(const float4*)(Wh2 + (size_t)sr * DH + sc);
    rw[1] = *(const float4*)(Wh2 + (size_t)sr * DH + sc + 4);
    for (int t = 0; t < 8; ++t) {
        __syncthreads();
        *(float4*)&sW[sr][sc]     = rw[0];
        *(float4*)&sW[sr][sc + 4] = rw[1];
        __syncthreads();
        if (t < 7) {
            const int k0 = 16 * (t + 1);
            rw[0] = *(const float4*)(Wh2 + (size_t)(k0 + sr) * DH + sc);
            rw[1] = *(const float4*)(Wh2 + (size_t)(k0 + sr) * DH + sc + 4);
        }
#pragma unroll
        for (int kk = 0; kk < 16; ++kk) {
            const float4 a = *(const float4*)&sHid[t * 16 + kk][ng * 4];
            const float4 b = *(const float4*)&sW[kk][jg * 4];
            const float av[4] = {a.x, a.y, a.z, a.w};
            const float bv[4] = {b.x, b.y, b.z, b.w};
#pragma unroll
            for (int i = 0; i < 4; ++i)
#pragma unroll
                for (int j = 0; j < 4; ++j)
                    acc2[i][j] = fmaf(av[i], bv[j], acc2[i][j]);
        }
    }

#pragma unroll
    for (int jj = 0; jj < 4; ++jj) {
        const float bb = bh2[jg * 4 + jj];
#pragma unroll
        for (int i = 0; i < 4; ++i) {
            const int gn = n0 + ng * 4 + i;
            float hv = 0.f;
            if (gn < N) hv = h[(size_t)gn * DH + jg * 4 + jj];
            sU[jg * 4 + jj][ng * 4 + i] = acc2[i][jj] + bb + hv;
        }
    }
    __syncthreads();

    {
        const int n = tid >> 3, sub = tid & 7;
        float s1 = 0.f, s2 = 0.f;
#pragma unroll
        for (int i = 0; i < 16; ++i) {
            const float z = sU[sub + 8 * i][n];
            s1 += z; s2 += z * z;
        }
#pragma unroll
        for (int m = 1; m < 8; m <<= 1) {
            s1 += __shfl_xor(s1, m, 64);
            s2 += __shfl_xor(s2, m, 64);
        }
        if (sub == 0) {
            const float mean = s1 * (1.f / 128.f);
            const float var = s2 * (1.f / 128.f) - mean * mean;
            sMean[n] = mean;
            sRstd[n] = rsqrtf(var + 1e-5f);
        }
    }
    __syncthreads();
    {
        const int n = tid >> 3, c0 = (tid & 7) * 16;
        const int gn = n0 + n;
        if (gn < N) {
            const float mean = sMean[n], rstd = sRstd[n];
#pragma unroll
            for (int i = 0; i < 4; ++i) {
                const float4 g4 = *(const float4*)(ln_g + c0 + 4 * i);
                const float4 b4 = *(const float4*)(ln_b + c0 + 4 * i);
                float4 o;
                o.x = (sU[c0 + 4 * i + 0][n] - mean) * rstd * g4.x + b4.x;
                o.y = (sU[c0 + 4 * i + 1][n] - mean) * rstd * g4.y + b4.y;
                o.z = (sU[c0 + 4 * i + 2][n] - mean) * rstd * g4.z + b4.z;
                o.w = (sU[c0 + 4 * i + 3][n] - mean) * rstd * g4.w + b4.w;
                *(float4*)(out + (size_t)gn * DH + c0 + 4 * i) = o;
            }
        }
    }
}

extern "C" void kernel_launch(void* const* d_in, const int* in_sizes, int n_in,
                              void* d_out, int out_size, void* d_ws, size_t ws_size,
                              hipStream_t stream)
{
    (void)n_in; (void)out_size;
    const float* h   = (const float*)d_in[0];
    const float* x   = (const float*)d_in[1];
    const int*   ei  = (const int*)d_in[2];
    const float* ew  = (const float*)d_in[3];
    const float* Wm1 = (const float*)d_in[4];
    const float* bm1 = (const float*)d_in[5];
    const float* Wm2 = (const float*)d_in[6];
    const float* bm2 = (const float*)d_in[7];
    const float* Wh1 = (const float*)d_in[8];
    const float* bh1 = (const float*)d_in[9];
    const float* Wh2 = (const float*)d_in[10];
    const float* bh2 = (const float*)d_in[11];
    const float* lng = (const float*)d_in[12];
    const float* lnb = (const float*)d_in[13];
    float* out = (float*)d_out;

    const int N = in_sizes[0] / DH;
    const int E = in_sizes[3];

    float*    agg = (float*)d_ws;
    ushort_t* Abf = (ushort_t*)(agg + (size_t)N * DH);
    ushort_t* Bbf = Abf + (size_t)N * DH;
    ushort_t* W2f = Bbf + (size_t)N * DH;
    int* counts = (int*)(W2f + 16384);
    int* cursor = counts + N;
    int* perm   = cursor + N;
    int* flag   = perm + E;

    const size_t need = (size_t)N * DH * 8 + 32768 + (size_t)(2 * N + E + 1) * 4;
    const int use_sort = (ws_size >= need) ? 1 : 0;
    if (!use_sort) flag = counts;  // minimal layout (no sort arrays)

    hipMemsetAsync(agg, 0, (size_t)N * DH * sizeof(float), stream);
    k_detect<<<1, 64, 0, stream>>>(ei, flag);
    if (use_sort) {
        hipMemsetAsync(counts, 0, (size_t)N * sizeof(int), stream);
        k_hist<<<(E + 255) / 256, 256, 0, stream>>>(ei, flag, counts, E);
        k_scan<<<1, 1024, 0, stream>>>(counts, cursor, N);
        k_scatter<<<(E + 255) / 256, 256, 0, stream>>>(ei, flag, cursor, perm, E);
    }
    k_w2f<<<8, 256, 0, stream>>>(Wm2, W2f);
    k_precompute_ab<<<(N + 31) / 32, 256, 0, stream>>>(h, Wm1, bm1, Abf, Bbf, N);
    k_edge<<<(E + EB - 1) / EB, 256, 0, stream>>>(x, ei, ew, Wm1, W2f, bm2, Abf, Bbf,
                                                  agg, flag, perm, use_sort, N, E);
    k_node<<<(N + 31) / 32, 256, 0, stream>>>(h, agg, Wh1, bh1, Wh2, bh2, lng, lnb, out, N);
}

// Round 5
// 670.884 us; speedup vs baseline: 4.9201x; 1.0240x over previous
//
#include <hip/hip_runtime.h>
#include <hip/hip_bf16.h>
#include <math.h>

#define DH 128
#define NRBF 16
#define EB 128   // edges per k_edge block
#define NTAB 1025

typedef unsigned short ushort_t;
typedef __attribute__((ext_vector_type(8))) short short8;
typedef __attribute__((ext_vector_type(4))) float floatx4;

__device__ __forceinline__ float silu_f(float v) {
    return v / (1.f + __expf(-v));
}

__device__ __forceinline__ unsigned pk_bf16(float lo, float hi) {
    __hip_bfloat162 h = __float22bfloat162_rn(make_float2(lo, hi));
    union { __hip_bfloat162 h2; unsigned u; } cv;
    cv.h2 = h;
    return cv.u;
}
__device__ __forceinline__ float bflo(unsigned u) { return __uint_as_float(u << 16); }
__device__ __forceinline__ float bfhi(unsigned u) { return __uint_as_float(u & 0xffff0000u); }

// int64 vs int32 edge_index layout: int64 little-endian -> odd 32-bit words all 0.
__device__ __forceinline__ int detect64(const int* __restrict__ ei) {
    int z = 0;
#pragma unroll
    for (int i = 0; i < 8; ++i) z |= ei[2 * i + 1];
    return (z == 0) ? 1 : 0;
}
__device__ __forceinline__ int load_dst(const int* ei, int is64, int e, int E) {
    return is64 ? ei[2 * E + 2 * e] : ei[E + e];
}
__device__ __forceinline__ int load_src(const int* ei, int is64, int e, int E) {
    return is64 ? ei[2 * e] : ei[e];
}

// ---------------------------------------------------------------------------
// Merged: histogram (blocks < nb_hist) | RBF table rows | W2f fragment-permute
// T[i][j] = sum_q exp(-GAMMA*(i*DELTA - q*WIDTH)^2) * Wm1[256+q][j]
// W2f[u*8+{0..7}], u=(kc*4+lg)*128+col  <- Wm2 rows {32kc+4lg+j, +16} col
// ---------------------------------------------------------------------------
__global__ __launch_bounds__(256) void k_hist_prep(
    const int* __restrict__ ei, int* __restrict__ counts, int E,
    const float* __restrict__ Wm1, const float* __restrict__ Wm2,
    float* __restrict__ T, ushort_t* __restrict__ W2f, int nb_hist)
{
    const int b = blockIdx.x, tid = threadIdx.x;
    if (b < nb_hist) {
        const int e = b * 256 + tid;
        if (e < E) {
            const int is64 = detect64(ei);
            atomicAdd(&counts[load_dst(ei, is64, e, E)], 1);
        }
        return;
    }
    const int b2 = b - nb_hist;
    if (b2 < NTAB) {
        if (tid < DH) {
            const float WIDTH = 0.09428090415820634f;  // sqrt(2)/15
            const float GAMMA = 56.25f;                // 1/(2*WIDTH^2)
            const float DELTA = 1.4142135623730951f / 1024.0f;
            const float r = (float)b2 * DELTA;
            float acc = 0.f;
#pragma unroll
            for (int q = 0; q < NRBF; ++q) {
                const float dr = r - (float)q * WIDTH;
                acc = fmaf(__expf(-GAMMA * dr * dr), Wm1[(256 + q) * DH + tid], acc);
            }
            T[(size_t)b2 * DH + tid] = acc;
        }
        return;
    }
    // W2f permute: 8 blocks x 256 threads cover u = 0..2047
    const int u = (b2 - NTAB) * 256 + tid;
    const int col = u & 127, lgc = u >> 7;
    const int lg = lgc & 3, kc = lgc >> 2;
    unsigned o[4];
#pragma unroll
    for (int j = 0; j < 2; ++j) {
        o[j]     = pk_bf16(Wm2[(kc * 32 + 4 * lg + 2 * j) * DH + col],
                           Wm2[(kc * 32 + 4 * lg + 2 * j + 1) * DH + col]);
        o[2 + j] = pk_bf16(Wm2[(kc * 32 + 16 + 4 * lg + 2 * j) * DH + col],
                           Wm2[(kc * 32 + 16 + 4 * lg + 2 * j + 1) * DH + col]);
    }
    *(uint4*)(W2f + 8 * u) = make_uint4(o[0], o[1], o[2], o[3]);
}

// ---------------------------------------------------------------------------
// Exclusive prefix sum of counts -> cursor. int4 vectorized, 4096/iter.
// ---------------------------------------------------------------------------
__global__ __launch_bounds__(1024) void k_scan(const int* __restrict__ counts,
                                               int* __restrict__ cursor, int N) {
    __shared__ int wsum[16];
    __shared__ int sCarry;
    const int tid = threadIdx.x, lane = tid & 63, wid = tid >> 6;
    if (tid == 0) sCarry = 0;
    __syncthreads();
    for (int c0 = 0; c0 < N; c0 += 4096) {
        const int idx = c0 + tid * 4;
        int4 v = make_int4(0, 0, 0, 0);
        if (idx < N) v = *(const int4*)(counts + idx);  // tail reads are in-ws, garbage cancels
        const int t01 = v.x + v.y;
        const int t012 = t01 + v.z;
        const int tot = t012 + v.w;
        int incl = tot;
#pragma unroll
        for (int d = 1; d < 64; d <<= 1) {
            int t = __shfl_up(incl, d, 64);
            if (lane >= d) incl += t;
        }
        if (lane == 63) wsum[wid] = incl;
        __syncthreads();
        if (wid == 0) {
            int s = (lane < 16) ? wsum[lane] : 0;
#pragma unroll
            for (int d = 1; d < 16; d <<= 1) {
                int t = __shfl_up(s, d, 64);
                if (lane >= d) s += t;
            }
            if (lane < 16) wsum[lane] = s;
        }
        __syncthreads();
        const int ex = sCarry + (wid > 0 ? wsum[wid - 1] : 0) + incl - tot;
        if (idx + 3 < N) {
            *(int4*)(cursor + idx) = make_int4(ex, ex + v.x, ex + t01, ex + t012);
        } else if (idx < N) {
            cursor[idx] = ex;
            if (idx + 1 < N) cursor[idx + 1] = ex + v.x;
            if (idx + 2 < N) cursor[idx + 2] = ex + t01;
        }
        __syncthreads();
        if (tid == 0) sCarry += wsum[15];
        __syncthreads();
    }
}

// ---------------------------------------------------------------------------
// Merged: scatter (blocks < nb_scat) | precompute A/B -> bf16
// A = h @ Wm1[0:128,:] + bm1 ; B = h @ Wm1[128:256,:]
// ---------------------------------------------------------------------------
__global__ __launch_bounds__(256) void k_scatter_pre(
    const int* __restrict__ ei, int* __restrict__ cursor, int* __restrict__ perm, int E,
    const float* __restrict__ h, const float* __restrict__ Wm1, const float* __restrict__ bm1,
    ushort_t* __restrict__ Abf, ushort_t* __restrict__ Bbf, int N, int nb_scat)
{
    __shared__ float sH[DH][36];
    __shared__ float sW[16][256];
    const int tid = threadIdx.x;

    if ((int)blockIdx.x < nb_scat) {
        const int e = blockIdx.x * 256 + tid;
        if (e < E) {
            const int is64 = detect64(ei);
            const int d = load_dst(ei, is64, e, E);
            const int pos = atomicAdd(&cursor[d], 1);
            perm[pos] = e;
        }
        return;
    }

    const int n0 = (blockIdx.x - nb_scat) * 32;
    {
        const int n = tid >> 3;
        const int c0 = (tid & 7) * 16;
        const int gn = n0 + n;
#pragma unroll
        for (int i = 0; i < 4; ++i) {
            float4 v = make_float4(0.f, 0.f, 0.f, 0.f);
            if (gn < N) v = *(const float4*)(h + (size_t)gn * DH + c0 + 4 * i);
            sH[c0 + 4 * i + 0][n] = v.x;
            sH[c0 + 4 * i + 1][n] = v.y;
            sH[c0 + 4 * i + 2][n] = v.z;
            sH[c0 + 4 * i + 3][n] = v.w;
        }
    }

    const int ng = tid & 7;
    const int jg = tid >> 3;
    const int sr = tid >> 4;
    const int sc = (tid & 15) * 16;

    float acc[4][8];
#pragma unroll
    for (int i = 0; i < 4; ++i)
#pragma unroll
        for (int j = 0; j < 8; ++j) acc[i][j] = 0.f;

    float4 rw[4];
#pragma unroll
    for (int i = 0; i < 4; ++i) {
        const int c = sc + 4 * i;
        const float* p = (c < DH) ? (Wm1 + (size_t)sr * DH + c)
                                  : (Wm1 + (size_t)(DH + sr) * DH + (c - DH));
        rw[i] = *(const float4*)p;
    }

    for (int t = 0; t < 8; ++t) {
        __syncthreads();
#pragma unroll
        for (int i = 0; i < 4; ++i) *(float4*)&sW[sr][sc + 4 * i] = rw[i];
        __syncthreads();
        if (t < 7) {
            const int k0 = 16 * (t + 1);
#pragma unroll
            for (int i = 0; i < 4; ++i) {
                const int c = sc + 4 * i;
                const float* p = (c < DH) ? (Wm1 + (size_t)(k0 + sr) * DH + c)
                                          : (Wm1 + (size_t)(DH + k0 + sr) * DH + (c - DH));
                rw[i] = *(const float4*)p;
            }
        }
#pragma unroll
        for (int kk = 0; kk < 16; ++kk) {
            const float4 a  = *(const float4*)&sH[t * 16 + kk][ng * 4];
            const float4 b0 = *(const float4*)&sW[kk][jg * 8];
            const float4 b1 = *(const float4*)&sW[kk][jg * 8 + 4];
            const float av[4] = {a.x, a.y, a.z, a.w};
            const float bv[8] = {b0.x, b0.y, b0.z, b0.w, b1.x, b1.y, b1.z, b1.w};
#pragma unroll
            for (int i = 0; i < 4; ++i)
#pragma unroll
                for (int j = 0; j < 8; ++j)
                    acc[i][j] = fmaf(av[i], bv[j], acc[i][j]);
        }
    }

    const int j0 = jg * 8;
#pragma unroll
    for (int i = 0; i < 4; ++i) {
        const int gn = n0 + ng * 4 + i;
        if (gn >= N) continue;
        if (j0 < DH) {
            float o[8];
#pragma unroll
            for (int j = 0; j < 8; ++j) o[j] = acc[i][j] + bm1[j0 + j];
            uint2 p0, p1;
            p0.x = pk_bf16(o[0], o[1]); p0.y = pk_bf16(o[2], o[3]);
            p1.x = pk_bf16(o[4], o[5]); p1.y = pk_bf16(o[6], o[7]);
            *(uint2*)(Abf + (size_t)gn * DH + j0) = p0;
            *(uint2*)(Abf + (size_t)gn * DH + j0 + 4) = p1;
        } else {
            const int jb = j0 - DH;
            uint2 p0, p1;
            p0.x = pk_bf16(acc[i][0], acc[i][1]); p0.y = pk_bf16(acc[i][2], acc[i][3]);
            p1.x = pk_bf16(acc[i][4], acc[i][5]); p1.y = pk_bf16(acc[i][6], acc[i][7]);
            *(uint2*)(Bbf + (size_t)gn * DH + jb) = p0;
            *(uint2*)(Bbf + (size_t)gn * DH + jb + 4) = p1;
        }
    }
}

// ---------------------------------------------------------------------------
// Edge kernel. Phase 1 (2 thr/edge): hidden = silu(A[src]+B[dst]+T[round(r)])
//   -> bf16 -> sHid ([e][k], XOR-swizzled 16B chunks). No phase1->2 barrier
//   (wave reads only rows it wrote). Phase 2: MFMA, B-frags straight from
//   global W2f (L1-resident, coalesced). Phase 3: run-merged atomicAdd.
// LDS ~34 KB -> 4 blocks/CU.
// ---------------------------------------------------------------------------
__global__ __launch_bounds__(256, 4) void k_edge(
    const float* __restrict__ x, const int* __restrict__ ei, const float* __restrict__ ew,
    const ushort_t* __restrict__ W2f, const float* __restrict__ bm2,
    const ushort_t* __restrict__ Abf, const ushort_t* __restrict__ Bbf,
    const float* __restrict__ T, float* __restrict__ agg,
    const int* __restrict__ perm, int use_perm, int N, int E)
{
    __shared__ __align__(16) ushort_t sHid[EB * DH];  // 32 KB
    __shared__ int   sSrc[EB];
    __shared__ int   sDst[EB];
    __shared__ float sEw[EB];

    const int tid = threadIdx.x;
    const int e0 = blockIdx.x * EB;

    if (tid < EB) {
        const int slot = e0 + tid;
        int s = 0, d = 0;
        float w = 0.f;
        if (slot < E) {
            const int e = use_perm ? perm[slot] : slot;
            const int is64 = detect64(ei);
            s = load_src(ei, is64, e, E);
            d = load_dst(ei, is64, e, E);
            w = ew[e];
        }
        sSrc[tid] = s; sDst[tid] = d; sEw[tid] = w;
    }
    __syncthreads();

    // ---- phase 1 ----
    {
        const int e = tid >> 1;
        const int p = tid & 1;
        const int s = sSrc[e], d = sDst[e];
        const float2 xs = *(const float2*)(x + 2 * s);
        const float2 xd = *(const float2*)(x + 2 * d);
        const float dxv = xs.x - xd.x, dyv = xs.y - xd.y;
        const float r = sqrtf(dxv * dxv + dyv * dyv + 1e-8f);
        int ti = (int)(r * 724.0773439350246f + 0.5f);   // 1024/sqrt(2)
        ti = min(ti, NTAB - 1);

        const uint4*  pA = (const uint4*)(Abf + (size_t)s * DH + 64 * p);
        const uint4*  pB = (const uint4*)(Bbf + (size_t)d * DH + 64 * p);
        const float4* pT = (const float4*)(T + (size_t)ti * DH + 64 * p);
        uint4* rowp = (uint4*)(sHid + e * DH);
        const int swz = e & 7;
#pragma unroll
        for (int i = 0; i < 8; ++i) {
            const uint4 a = pA[i];
            const uint4 b = pB[i];
            const float4 t0 = pT[2 * i];
            const float4 t1 = pT[2 * i + 1];
            const float v0 = bflo(a.x) + bflo(b.x) + t0.x;
            const float v1 = bfhi(a.x) + bfhi(b.x) + t0.y;
            const float v2 = bflo(a.y) + bflo(b.y) + t0.z;
            const float v3 = bfhi(a.y) + bfhi(b.y) + t0.w;
            const float v4 = bflo(a.z) + bflo(b.z) + t1.x;
            const float v5 = bfhi(a.z) + bfhi(b.z) + t1.y;
            const float v6 = bflo(a.w) + bflo(b.w) + t1.z;
            const float v7 = bfhi(a.w) + bfhi(b.w) + t1.w;
            uint4 pk;
            pk.x = pk_bf16(silu_f(v0), silu_f(v1));
            pk.y = pk_bf16(silu_f(v2), silu_f(v3));
            pk.z = pk_bf16(silu_f(v4), silu_f(v5));
            pk.w = pk_bf16(silu_f(v6), silu_f(v7));
            rowp[(8 * p + i) ^ swz] = pk;
        }
    }
    // NO __syncthreads(): wave wv wrote rows 32wv..32wv+31 and reads only those.

    const int lane = tid & 63;
    const int wv   = tid >> 6;
    const int m0   = wv * 32;
    const int lr   = lane & 15;
    const int lg   = lane >> 4;

    // ---- phase 2: MFMA  C[128e][128j] = hid @ Wm2 ----
    floatx4 acc[2][8];
#pragma unroll
    for (int mi = 0; mi < 2; ++mi)
#pragma unroll
        for (int ni = 0; ni < 8; ++ni) acc[mi][ni] = (floatx4){0.f, 0.f, 0.f, 0.f};

    union FragU { unsigned u[4]; short8 s8; };

#pragma unroll
    for (int kc = 0; kc < 4; ++kc) {
        const int b1 = 64 * kc + 8 * lg;
        const int b2 = b1 + 32;
        FragU af[2];
#pragma unroll
        for (int mi = 0; mi < 2; ++mi) {
            const int e2 = m0 + mi * 16 + lr;
            const char* rbase = (const char*)(sHid + e2 * DH);
            const int swz = (e2 & 7) << 4;
            const uint2 lo = *(const uint2*)(rbase + ((b1 & ~15) ^ swz) + (b1 & 15));
            const uint2 hi = *(const uint2*)(rbase + ((b2 & ~15) ^ swz) + (b2 & 15));
            af[mi].u[0] = lo.x; af[mi].u[1] = lo.y;
            af[mi].u[2] = hi.x; af[mi].u[3] = hi.y;
        }
        const ushort_t* wbase = W2f + ((size_t)(kc * 4 + lg) * 128 + lr) * 8;
        __builtin_amdgcn_s_setprio(1);
#pragma unroll
        for (int ni = 0; ni < 8; ++ni) {
            const short8 bf = *(const short8*)(wbase + ni * 128);
            acc[0][ni] = __builtin_amdgcn_mfma_f32_16x16x32_bf16(af[0].s8, bf, acc[0][ni], 0, 0, 0);
            acc[1][ni] = __builtin_amdgcn_mfma_f32_16x16x32_bf16(af[1].s8, bf, acc[1][ni], 0, 0, 0);
        }
        __builtin_amdgcn_s_setprio(0);
    }

    // ---- phase 3: bias, edge-weight, run-merged atomic scatter ----
#pragma unroll
    for (int ni = 0; ni < 8; ++ni) {
        const int col = ni * 16 + lr;
        const float bc = bm2[col];
#pragma unroll
        for (int mi = 0; mi < 2; ++mi) {
            const int sbase = m0 + mi * 16 + 4 * lg;
            int cur = sDst[sbase];
            float av = (acc[mi][ni][0] + bc) * sEw[sbase];
#pragma unroll
            for (int r = 1; r < 4; ++r) {
                const int d = sDst[sbase + r];
                const float v = (acc[mi][ni][r] + bc) * sEw[sbase + r];
                if (d == cur) av += v;
                else {
                    atomicAdd(agg + (size_t)cur * DH + col, av);
                    cur = d; av = v;
                }
            }
            atomicAdd(agg + (size_t)cur * DH + col, av);
        }
    }
}

// ---------------------------------------------------------------------------
// Node MLP + residual + LayerNorm. 32 nodes/block, 256 threads.
// ---------------------------------------------------------------------------
__global__ __launch_bounds__(256) void k_node(
    const float* __restrict__ h, const float* __restrict__ agg,
    const float* __restrict__ Wh1, const float* __restrict__ bh1,
    const float* __restrict__ Wh2, const float* __restrict__ bh2,
    const float* __restrict__ ln_g, const float* __restrict__ ln_b,
    float* __restrict__ out, int N)
{
    __shared__ float sU[2 * DH][36];
    __shared__ float sHid[DH][36];
    __shared__ float sW[16][DH];
    __shared__ float sMean[32], sRstd[32];
    const int tid = threadIdx.x;
    const int n0 = blockIdx.x * 32;

    {
        const int n = tid >> 3;
        const int c0 = (tid & 7) * 16;
        const int gn = n0 + n;
#pragma unroll
        for (int i = 0; i < 4; ++i) {
            float4 v = make_float4(0.f, 0.f, 0.f, 0.f);
            if (gn < N) v = *(const float4*)(h + (size_t)gn * DH + c0 + 4 * i);
            sU[c0 + 4 * i + 0][n] = v.x; sU[c0 + 4 * i + 1][n] = v.y;
            sU[c0 + 4 * i + 2][n] = v.z; sU[c0 + 4 * i + 3][n] = v.w;
        }
#pragma unroll
        for (int i = 0; i < 4; ++i) {
            float4 v = make_float4(0.f, 0.f, 0.f, 0.f);
            if (gn < N) v = *(const float4*)(agg + (size_t)gn * DH + c0 + 4 * i);
            sU[DH + c0 + 4 * i + 0][n] = v.x; sU[DH + c0 + 4 * i + 1][n] = v.y;
            sU[DH + c0 + 4 * i + 2][n] = v.z; sU[DH + c0 + 4 * i + 3][n] = v.w;
        }
    }

    const int ng = tid & 7;
    const int jg = tid >> 3;
    const int sr = tid >> 4;
    const int sc = (tid & 15) * 8;

    float acc[4][4];
#pragma unroll
    for (int i = 0; i < 4; ++i)
#pragma unroll
        for (int j = 0; j < 4; ++j) acc[i][j] = 0.f;

    float4 rw[2];
    rw[0] = *(const float4*)(Wh1 + (size_t)sr * DH + sc);
    rw[1] = *(const float4*)(Wh1 + (size_t)sr * DH + sc + 4);
    for (int t = 0; t < 16; ++t) {
        __syncthreads();
        *(float4*)&sW[sr][sc]     = rw[0];
        *(float4*)&sW[sr][sc + 4] = rw[1];
        __syncthreads();
        if (t < 15) {
            const int k0 = 16 * (t + 1);
            rw[0] = *(const float4*)(Wh1 + (size_t)(k0 + sr) * DH + sc);
            rw[1] = *(const float4*)(Wh1 + (size_t)(k0 + sr) * DH + sc + 4);
        }
#pragma unroll
        for (int kk = 0; kk < 16; ++kk) {
            const float4 a = *(const float4*)&sU[t * 16 + kk][ng * 4];
            const float4 b = *(const float4*)&sW[kk][jg * 4];
            const float av[4] = {a.x, a.y, a.z, a.w};
            const float bv[4] = {b.x, b.y, b.z, b.w};
#pragma unroll
            for (int i = 0; i < 4; ++i)
#pragma unroll
                for (int j = 0; j < 4; ++j)
                    acc[i][j] = fmaf(av[i], bv[j], acc[i][j]);
        }
    }
#pragma unroll
    for (int jj = 0; jj < 4; ++jj) {
        const float bb = bh1[jg * 4 + jj];
#pragma unroll
        for (int i = 0; i < 4; ++i)
            sHid[jg * 4 + jj][ng * 4 + i] = silu_f(acc[i][jj] + bb);
    }

    float acc2[4][4];
#pragma unroll
    for (int i = 0; i < 4; ++i)
#pragma unroll
        for (int j = 0; j < 4; ++j) acc2[i][j] = 0.f;

    rw[0] = *(const float4*)(Wh2 + (size_t)sr * DH + sc);
    rw[1] = *(const float4*)(Wh2 + (size_t)sr * DH + sc + 4);
    for (int t = 0; t < 8; ++t) {
        __syncthreads();
        *(float4*)&sW[sr][sc]     = rw[0];
        *(float4*)&sW[sr][sc + 4] = rw[1];
        __syncthreads();
        if (t < 7) {
            const int k0 = 16 * (t + 1);
            rw[0] = *(const float4*)(Wh2 + (size_t)(k0 + sr) * DH + sc);
            rw[1] = *(const float4*)(Wh2 + (size_t)(k0 + sr) * DH + sc + 4);
        }
#pragma unroll
        for (int kk = 0; kk < 16; ++kk) {
            const float4 a = *(const float4*)&sHid[t * 16 + kk][ng * 4];
            const float4 b = *(const float4*)&sW[kk][jg * 4];
            const float av[4] = {a.x, a.y, a.z, a.w};
            const float bv[4] = {b.x, b.y, b.z, b.w};
#pragma unroll
            for (int i = 0; i < 4; ++i)
#pragma unroll
                for (int j = 0; j < 4; ++j)
                    acc2[i][j] = fmaf(av[i], bv[j], acc2[i][j]);
        }
    }

#pragma unroll
    for (int jj = 0; jj < 4; ++jj) {
        const float bb = bh2[jg * 4 + jj];
#pragma unroll
        for (int i = 0; i < 4; ++i) {
            const int gn = n0 + ng * 4 + i;
            float hv = 0.f;
            if (gn < N) hv = h[(size_t)gn * DH + jg * 4 + jj];
            sU[jg * 4 + jj][ng * 4 + i] = acc2[i][jj] + bb + hv;
        }
    }
    __syncthreads();

    {
        const int n = tid >> 3, sub = tid & 7;
        float s1 = 0.f, s2 = 0.f;
#pragma unroll
        for (int i = 0; i < 16; ++i) {
            const float z = sU[sub + 8 * i][n];
            s1 += z; s2 += z * z;
        }
#pragma unroll
        for (int m = 1; m < 8; m <<= 1) {
            s1 += __shfl_xor(s1, m, 64);
            s2 += __shfl_xor(s2, m, 64);
        }
        if (sub == 0) {
            const float mean = s1 * (1.f / 128.f);
            const float var = s2 * (1.f / 128.f) - mean * mean;
            sMean[n] = mean;
            sRstd[n] = rsqrtf(var + 1e-5f);
        }
    }
    __syncthreads();
    {
        const int n = tid >> 3, c0 = (tid & 7) * 16;
        const int gn = n0 + n;
        if (gn < N) {
            const float mean = sMean[n], rstd = sRstd[n];
#pragma unroll
            for (int i = 0; i < 4; ++i) {
                const float4 g4 = *(const float4*)(ln_g + c0 + 4 * i);
                const float4 b4 = *(const float4*)(ln_b + c0 + 4 * i);
                float4 o;
                o.x = (sU[c0 + 4 * i + 0][n] - mean) * rstd * g4.x + b4.x;
                o.y = (sU[c0 + 4 * i + 1][n] - mean) * rstd * g4.y + b4.y;
                o.z = (sU[c0 + 4 * i + 2][n] - mean) * rstd * g4.z + b4.z;
                o.w = (sU[c0 + 4 * i + 3][n] - mean) * rstd * g4.w + b4.w;
                *(float4*)(out + (size_t)gn * DH + c0 + 4 * i) = o;
            }
        }
    }
}

extern "C" void kernel_launch(void* const* d_in, const int* in_sizes, int n_in,
                              void* d_out, int out_size, void* d_ws, size_t ws_size,
                              hipStream_t stream)
{
    (void)n_in; (void)out_size;
    const float* h   = (const float*)d_in[0];
    const float* x   = (const float*)d_in[1];
    const int*   ei  = (const int*)d_in[2];
    const float* ew  = (const float*)d_in[3];
    const float* Wm1 = (const float*)d_in[4];
    const float* bm1 = (const float*)d_in[5];
    const float* Wm2 = (const float*)d_in[6];
    const float* bm2 = (const float*)d_in[7];
    const float* Wh1 = (const float*)d_in[8];
    const float* bh1 = (const float*)d_in[9];
    const float* Wh2 = (const float*)d_in[10];
    const float* bh2 = (const float*)d_in[11];
    const float* lng = (const float*)d_in[12];
    const float* lnb = (const float*)d_in[13];
    float* out = (float*)d_out;

    const int N = in_sizes[0] / DH;
    const int E = in_sizes[3];

    // ws layout: agg | counts | cursor | perm | Abf | Bbf | W2f | T
    float* agg   = (float*)d_ws;
    int* counts  = (int*)(agg + (size_t)N * DH);
    int* cursor  = counts + N;
    int* perm    = cursor + N;
    ushort_t* Abf = (ushort_t*)(perm + E);
    ushort_t* Bbf = Abf + (size_t)N * DH;
    ushort_t* W2f = Bbf + (size_t)N * DH;
    float* T      = (float*)(W2f + 16384);

    const size_t need = (size_t)N * DH * 4 + (size_t)(2 * N + E) * 4
                      + (size_t)N * DH * 4 + 32768 + (size_t)NTAB * DH * 4 + 64;
    const int use_sort = (ws_size >= need) ? 1 : 0;

    const int nb_hist = use_sort ? (E + 255) / 256 : 0;
    const int nb_prep = NTAB + 8;
    const int nb_scat = nb_hist;
    const int nb_pre  = (N + 31) / 32;

    // zero agg (+ counts, contiguous) in one memset
    hipMemsetAsync(agg, 0, (size_t)N * DH * sizeof(float) + (use_sort ? (size_t)N * 4 : 0), stream);
    k_hist_prep<<<nb_hist + nb_prep, 256, 0, stream>>>(ei, counts, E, Wm1, Wm2, T, W2f, nb_hist);
    if (use_sort)
        k_scan<<<1, 1024, 0, stream>>>(counts, cursor, N);
    k_scatter_pre<<<nb_scat + nb_pre, 256, 0, stream>>>(ei, cursor, perm, E,
                                                        h, Wm1, bm1, Abf, Bbf, N, nb_scat);
    k_edge<<<(E + EB - 1) / EB, 256, 0, stream>>>(x, ei, ew, W2f, bm2, Abf, Bbf, T,
                                                  agg, perm, use_sort, N, E);
    k_node<<<(N + 31) / 32, 256, 0, stream>>>(h, agg, Wh1, bh1, Wh2, bh2, lng, lnb, out, N);
}

// Round 6
// 662.346 us; speedup vs baseline: 4.9835x; 1.0129x over previous
//
#include <hip/hip_runtime.h>
#include <hip/hip_bf16.h>
#include <math.h>

#define DH 128
#define NRBF 16
#define EB 128   // edges per k_edge block (processed in two 64-edge halves)
#define NTAB 1025

typedef unsigned short ushort_t;
typedef __attribute__((ext_vector_type(8))) short short8;
typedef __attribute__((ext_vector_type(4))) float floatx4;

__device__ __forceinline__ float silu_f(float v) {
    return v / (1.f + __expf(-v));
}

__device__ __forceinline__ unsigned pk_bf16(float lo, float hi) {
    __hip_bfloat162 h = __float22bfloat162_rn(make_float2(lo, hi));
    union { __hip_bfloat162 h2; unsigned u; } cv;
    cv.h2 = h;
    return cv.u;
}
__device__ __forceinline__ float bflo(unsigned u) { return __uint_as_float(u << 16); }
__device__ __forceinline__ float bfhi(unsigned u) { return __uint_as_float(u & 0xffff0000u); }

// int64 vs int32 edge_index layout: int64 little-endian -> odd 32-bit words all 0.
__device__ __forceinline__ int detect64(const int* __restrict__ ei) {
    int z = 0;
#pragma unroll
    for (int i = 0; i < 8; ++i) z |= ei[2 * i + 1];
    return (z == 0) ? 1 : 0;
}
__device__ __forceinline__ int load_dst(const int* ei, int is64, int e, int E) {
    return is64 ? ei[2 * E + 2 * e] : ei[E + e];
}
__device__ __forceinline__ int load_src(const int* ei, int is64, int e, int E) {
    return is64 ? ei[2 * e] : ei[e];
}

// ---------------------------------------------------------------------------
// Merged: histogram (blocks < nb_hist) | RBF table rows | W2f fragment-permute
// ---------------------------------------------------------------------------
__global__ __launch_bounds__(256) void k_hist_prep(
    const int* __restrict__ ei, int* __restrict__ counts, int E,
    const float* __restrict__ Wm1, const float* __restrict__ Wm2,
    float* __restrict__ T, ushort_t* __restrict__ W2f, int nb_hist)
{
    const int b = blockIdx.x, tid = threadIdx.x;
    if (b < nb_hist) {
        const int e = b * 256 + tid;
        if (e < E) {
            const int is64 = detect64(ei);
            atomicAdd(&counts[load_dst(ei, is64, e, E)], 1);
        }
        return;
    }
    const int b2 = b - nb_hist;
    if (b2 < NTAB) {
        if (tid < DH) {
            const float WIDTH = 0.09428090415820634f;  // sqrt(2)/15
            const float GAMMA = 56.25f;                // 1/(2*WIDTH^2)
            const float DELTA = 1.4142135623730951f / 1024.0f;
            const float r = (float)b2 * DELTA;
            float acc = 0.f;
#pragma unroll
            for (int q = 0; q < NRBF; ++q) {
                const float dr = r - (float)q * WIDTH;
                acc = fmaf(__expf(-GAMMA * dr * dr), Wm1[(256 + q) * DH + tid], acc);
            }
            T[(size_t)b2 * DH + tid] = acc;
        }
        return;
    }
    // W2f permute: 8 blocks x 256 threads cover u = 0..2047
    const int u = (b2 - NTAB) * 256 + tid;
    const int col = u & 127, lgc = u >> 7;
    const int lg = lgc & 3, kc = lgc >> 2;
    unsigned o[4];
#pragma unroll
    for (int j = 0; j < 2; ++j) {
        o[j]     = pk_bf16(Wm2[(kc * 32 + 4 * lg + 2 * j) * DH + col],
                           Wm2[(kc * 32 + 4 * lg + 2 * j + 1) * DH + col]);
        o[2 + j] = pk_bf16(Wm2[(kc * 32 + 16 + 4 * lg + 2 * j) * DH + col],
                           Wm2[(kc * 32 + 16 + 4 * lg + 2 * j + 1) * DH + col]);
    }
    *(uint4*)(W2f + 8 * u) = make_uint4(o[0], o[1], o[2], o[3]);
}

// ---------------------------------------------------------------------------
// Exclusive prefix sum of counts -> cursor. int4 vectorized, 4096/iter.
// ---------------------------------------------------------------------------
__global__ __launch_bounds__(1024) void k_scan(const int* __restrict__ counts,
                                               int* __restrict__ cursor, int N) {
    __shared__ int wsum[16];
    __shared__ int sCarry;
    const int tid = threadIdx.x, lane = tid & 63, wid = tid >> 6;
    if (tid == 0) sCarry = 0;
    __syncthreads();
    for (int c0 = 0; c0 < N; c0 += 4096) {
        const int idx = c0 + tid * 4;
        int4 v = make_int4(0, 0, 0, 0);
        if (idx < N) v = *(const int4*)(counts + idx);
        const int t01 = v.x + v.y;
        const int t012 = t01 + v.z;
        const int tot = t012 + v.w;
        int incl = tot;
#pragma unroll
        for (int d = 1; d < 64; d <<= 1) {
            int t = __shfl_up(incl, d, 64);
            if (lane >= d) incl += t;
        }
        if (lane == 63) wsum[wid] = incl;
        __syncthreads();
        if (wid == 0) {
            int s = (lane < 16) ? wsum[lane] : 0;
#pragma unroll
            for (int d = 1; d < 16; d <<= 1) {
                int t = __shfl_up(s, d, 64);
                if (lane >= d) s += t;
            }
            if (lane < 16) wsum[lane] = s;
        }
        __syncthreads();
        const int ex = sCarry + (wid > 0 ? wsum[wid - 1] : 0) + incl - tot;
        if (idx + 3 < N) {
            *(int4*)(cursor + idx) = make_int4(ex, ex + v.x, ex + t01, ex + t012);
        } else if (idx < N) {
            cursor[idx] = ex;
            if (idx + 1 < N) cursor[idx + 1] = ex + v.x;
            if (idx + 2 < N) cursor[idx + 2] = ex + t01;
        }
        __syncthreads();
        if (tid == 0) sCarry += wsum[15];
        __syncthreads();
    }
}

// ---------------------------------------------------------------------------
// Merged: scatter (blocks < nb_scat) | precompute A/B -> bf16
// ---------------------------------------------------------------------------
__global__ __launch_bounds__(256) void k_scatter_pre(
    const int* __restrict__ ei, int* __restrict__ cursor, int* __restrict__ perm, int E,
    const float* __restrict__ h, const float* __restrict__ Wm1, const float* __restrict__ bm1,
    ushort_t* __restrict__ Abf, ushort_t* __restrict__ Bbf, int N, int nb_scat)
{
    __shared__ float sH[DH][36];
    __shared__ float sW[16][256];
    const int tid = threadIdx.x;

    if ((int)blockIdx.x < nb_scat) {
        const int e = blockIdx.x * 256 + tid;
        if (e < E) {
            const int is64 = detect64(ei);
            const int d = load_dst(ei, is64, e, E);
            const int pos = atomicAdd(&cursor[d], 1);
            perm[pos] = e;
        }
        return;
    }

    const int n0 = (blockIdx.x - nb_scat) * 32;
    {
        const int n = tid >> 3;
        const int c0 = (tid & 7) * 16;
        const int gn = n0 + n;
#pragma unroll
        for (int i = 0; i < 4; ++i) {
            float4 v = make_float4(0.f, 0.f, 0.f, 0.f);
            if (gn < N) v = *(const float4*)(h + (size_t)gn * DH + c0 + 4 * i);
            sH[c0 + 4 * i + 0][n] = v.x;
            sH[c0 + 4 * i + 1][n] = v.y;
            sH[c0 + 4 * i + 2][n] = v.z;
            sH[c0 + 4 * i + 3][n] = v.w;
        }
    }

    const int ng = tid & 7;
    const int jg = tid >> 3;
    const int sr = tid >> 4;
    const int sc = (tid & 15) * 16;

    float acc[4][8];
#pragma unroll
    for (int i = 0; i < 4; ++i)
#pragma unroll
        for (int j = 0; j < 8; ++j) acc[i][j] = 0.f;

    float4 rw[4];
#pragma unroll
    for (int i = 0; i < 4; ++i) {
        const int c = sc + 4 * i;
        const float* p = (c < DH) ? (Wm1 + (size_t)sr * DH + c)
                                  : (Wm1 + (size_t)(DH + sr) * DH + (c - DH));
        rw[i] = *(const float4*)p;
    }

    for (int t = 0; t < 8; ++t) {
        __syncthreads();
#pragma unroll
        for (int i = 0; i < 4; ++i) *(float4*)&sW[sr][sc + 4 * i] = rw[i];
        __syncthreads();
        if (t < 7) {
            const int k0 = 16 * (t + 1);
#pragma unroll
            for (int i = 0; i < 4; ++i) {
                const int c = sc + 4 * i;
                const float* p = (c < DH) ? (Wm1 + (size_t)(k0 + sr) * DH + c)
                                          : (Wm1 + (size_t)(DH + k0 + sr) * DH + (c - DH));
                rw[i] = *(const float4*)p;
            }
        }
#pragma unroll
        for (int kk = 0; kk < 16; ++kk) {
            const float4 a  = *(const float4*)&sH[t * 16 + kk][ng * 4];
            const float4 b0 = *(const float4*)&sW[kk][jg * 8];
            const float4 b1 = *(const float4*)&sW[kk][jg * 8 + 4];
            const float av[4] = {a.x, a.y, a.z, a.w};
            const float bv[8] = {b0.x, b0.y, b0.z, b0.w, b1.x, b1.y, b1.z, b1.w};
#pragma unroll
            for (int i = 0; i < 4; ++i)
#pragma unroll
                for (int j = 0; j < 8; ++j)
                    acc[i][j] = fmaf(av[i], bv[j], acc[i][j]);
        }
    }

    const int j0 = jg * 8;
#pragma unroll
    for (int i = 0; i < 4; ++i) {
        const int gn = n0 + ng * 4 + i;
        if (gn >= N) continue;
        if (j0 < DH) {
            float o[8];
#pragma unroll
            for (int j = 0; j < 8; ++j) o[j] = acc[i][j] + bm1[j0 + j];
            uint2 p0, p1;
            p0.x = pk_bf16(o[0], o[1]); p0.y = pk_bf16(o[2], o[3]);
            p1.x = pk_bf16(o[4], o[5]); p1.y = pk_bf16(o[6], o[7]);
            *(uint2*)(Abf + (size_t)gn * DH + j0) = p0;
            *(uint2*)(Abf + (size_t)gn * DH + j0 + 4) = p1;
        } else {
            const int jb = j0 - DH;
            uint2 p0, p1;
            p0.x = pk_bf16(acc[i][0], acc[i][1]); p0.y = pk_bf16(acc[i][2], acc[i][3]);
            p1.x = pk_bf16(acc[i][4], acc[i][5]); p1.y = pk_bf16(acc[i][6], acc[i][7]);
            *(uint2*)(Bbf + (size_t)gn * DH + jb) = p0;
            *(uint2*)(Bbf + (size_t)gn * DH + jb + 4) = p1;
        }
    }
}

// ---------------------------------------------------------------------------
// Edge kernel: 128 edges/block in TWO 64-edge halves (LDS 17.5 KB -> 6 blk/CU).
// XCD-chunked block swizzle: each XCD owns a contiguous sorted-edge (=dst)
// range so its agg/Bbf working set fits its private L2.
// Phase 1 (4 thr/edge, 32 cols each): hidden = silu(A[src]+B[dst]+T[r])
//   -> bf16 -> sHid ([e][k], XOR-swizzled 16B chunks)
// Phase 2: wave = 32 edges x 64 cols MFMA, B-frags from global W2f.
// Phase 3: bias, edge-weight, run-merged atomicAdd into agg.
// ---------------------------------------------------------------------------
__global__ __launch_bounds__(256, 6) void k_edge(
    const float* __restrict__ x, const int* __restrict__ ei, const float* __restrict__ ew,
    const ushort_t* __restrict__ W2f, const float* __restrict__ bm2,
    const ushort_t* __restrict__ Abf, const ushort_t* __restrict__ Bbf,
    const float* __restrict__ T, float* __restrict__ agg,
    const int* __restrict__ perm, int use_perm, int N, int E)
{
    __shared__ __align__(16) ushort_t sHid[64 * DH];  // 16 KB
    __shared__ int   sSrc[EB];
    __shared__ int   sDst[EB];
    __shared__ float sEw[EB];

    const int tid = threadIdx.x;

    // XCD-chunked bijective swizzle (8 XCDs, round-robin hardware dispatch)
    const int nwg = gridDim.x;
    const int xcd = blockIdx.x & 7;
    const int idx = blockIdx.x >> 3;
    const int qch = nwg >> 3, rch = nwg & 7;
    const int bid = (xcd < rch) ? (xcd * (qch + 1) + idx)
                                : (rch * (qch + 1) + (xcd - rch) * qch + idx);
    const int e0 = bid * EB;

    if (tid < EB) {
        const int slot = e0 + tid;
        int s = 0, d = 0;
        float w = 0.f;
        if (slot < E) {
            const int e = use_perm ? perm[slot] : slot;
            const int is64 = detect64(ei);
            s = load_src(ei, is64, e, E);
            d = load_dst(ei, is64, e, E);
            w = ew[e];
        }
        sSrc[tid] = s; sDst[tid] = d; sEw[tid] = w;
    }
    __syncthreads();

    const int lane = tid & 63;
    const int wv   = tid >> 6;
    const int lr   = lane & 15;
    const int lg   = lane >> 4;
    const int m0l  = (wv & 1) * 32;       // wave's edge sub-tile within half
    const int n0   = (wv >> 1) * 64;      // wave's column sub-tile

    union FragU { unsigned u[4]; short8 s8; };

    for (int half = 0; half < 2; ++half) {
        const int eh = half * 64;

        // ---- phase 1: build 64-edge hidden tile (4 thr/edge, 32 cols) ----
        {
            const int el = tid >> 2;          // local edge 0..63
            const int q  = tid & 3;           // col quarter
            const int e  = eh + el;
            const int s = sSrc[e], d = sDst[e];
            const float2 xs = *(const float2*)(x + 2 * s);
            const float2 xd = *(const float2*)(x + 2 * d);
            const float dxv = xs.x - xd.x, dyv = xs.y - xd.y;
            const float r = sqrtf(dxv * dxv + dyv * dyv + 1e-8f);
            int ti = (int)(r * 724.0773439350246f + 0.5f);   // 1024/sqrt(2)
            ti = min(ti, NTAB - 1);

            const uint4*  pA = (const uint4*)(Abf + (size_t)s * DH + 32 * q);
            const uint4*  pB = (const uint4*)(Bbf + (size_t)d * DH + 32 * q);
            const float4* pT = (const float4*)(T + (size_t)ti * DH + 32 * q);
            uint4* rowp = (uint4*)(sHid + el * DH);
            const int swz = el & 7;
#pragma unroll
            for (int i = 0; i < 4; ++i) {
                const uint4 a = pA[i];
                const uint4 b = pB[i];
                const float4 t0 = pT[2 * i];
                const float4 t1 = pT[2 * i + 1];
                const float v0 = bflo(a.x) + bflo(b.x) + t0.x;
                const float v1 = bfhi(a.x) + bfhi(b.x) + t0.y;
                const float v2 = bflo(a.y) + bflo(b.y) + t0.z;
                const float v3 = bfhi(a.y) + bfhi(b.y) + t0.w;
                const float v4 = bflo(a.z) + bflo(b.z) + t1.x;
                const float v5 = bfhi(a.z) + bfhi(b.z) + t1.y;
                const float v6 = bflo(a.w) + bflo(b.w) + t1.z;
                const float v7 = bfhi(a.w) + bfhi(b.w) + t1.w;
                uint4 pk;
                pk.x = pk_bf16(silu_f(v0), silu_f(v1));
                pk.y = pk_bf16(silu_f(v2), silu_f(v3));
                pk.z = pk_bf16(silu_f(v4), silu_f(v5));
                pk.w = pk_bf16(silu_f(v6), silu_f(v7));
                rowp[(4 * q + i) ^ swz] = pk;
            }
        }
        __syncthreads();

        // ---- phase 2: MFMA  32 edges x 64 cols per wave ----
        floatx4 acc[2][4];
#pragma unroll
        for (int mi = 0; mi < 2; ++mi)
#pragma unroll
            for (int ni = 0; ni < 4; ++ni) acc[mi][ni] = (floatx4){0.f, 0.f, 0.f, 0.f};

#pragma unroll
        for (int kc = 0; kc < 4; ++kc) {
            const int b1 = 64 * kc + 8 * lg;
            const int b2 = b1 + 32;
            FragU af[2];
#pragma unroll
            for (int mi = 0; mi < 2; ++mi) {
                const int le2 = m0l + mi * 16 + lr;
                const char* rbase = (const char*)(sHid + le2 * DH);
                const int swz = (le2 & 7) << 4;
                const uint2 lo = *(const uint2*)(rbase + ((b1 & ~15) ^ swz) + (b1 & 15));
                const uint2 hi = *(const uint2*)(rbase + ((b2 & ~15) ^ swz) + (b2 & 15));
                af[mi].u[0] = lo.x; af[mi].u[1] = lo.y;
                af[mi].u[2] = hi.x; af[mi].u[3] = hi.y;
            }
            const ushort_t* wbase = W2f + ((size_t)(kc * 4 + lg) * 128 + n0 + lr) * 8;
            __builtin_amdgcn_s_setprio(1);
#pragma unroll
            for (int ni = 0; ni < 4; ++ni) {
                const short8 bf = *(const short8*)(wbase + ni * 128);
                acc[0][ni] = __builtin_amdgcn_mfma_f32_16x16x32_bf16(af[0].s8, bf, acc[0][ni], 0, 0, 0);
                acc[1][ni] = __builtin_amdgcn_mfma_f32_16x16x32_bf16(af[1].s8, bf, acc[1][ni], 0, 0, 0);
            }
            __builtin_amdgcn_s_setprio(0);
        }

        // ---- phase 3: bias, edge-weight, run-merged atomic scatter ----
#pragma unroll
        for (int ni = 0; ni < 4; ++ni) {
            const int col = n0 + ni * 16 + lr;
            const float bc = bm2[col];
#pragma unroll
            for (int mi = 0; mi < 2; ++mi) {
                const int sbase = eh + m0l + mi * 16 + 4 * lg;
                int cur = sDst[sbase];
                float av = (acc[mi][ni][0] + bc) * sEw[sbase];
#pragma unroll
                for (int r = 1; r < 4; ++r) {
                    const int d = sDst[sbase + r];
                    const float v = (acc[mi][ni][r] + bc) * sEw[sbase + r];
                    if (d == cur) av += v;
                    else {
                        atomicAdd(agg + (size_t)cur * DH + col, av);
                        cur = d; av = v;
                    }
                }
                atomicAdd(agg + (size_t)cur * DH + col, av);
            }
        }
        __syncthreads();   // protect sHid before next half overwrites it
    }
}

// ---------------------------------------------------------------------------
// Node MLP + residual + LayerNorm. 32 nodes/block, 256 threads.
// ---------------------------------------------------------------------------
__global__ __launch_bounds__(256) void k_node(
    const float* __restrict__ h, const float* __restrict__ agg,
    const float* __restrict__ Wh1, const float* __restrict__ bh1,
    const float* __restrict__ Wh2, const float* __restrict__ bh2,
    const float* __restrict__ ln_g, const float* __restrict__ ln_b,
    float* __restrict__ out, int N)
{
    __shared__ float sU[2 * DH][36];
    __shared__ float sHid[DH][36];
    __shared__ float sW[16][DH];
    __shared__ float sMean[32], sRstd[32];
    const int tid = threadIdx.x;
    const int n0 = blockIdx.x * 32;

    {
        const int n = tid >> 3;
        const int c0 = (tid & 7) * 16;
        const int gn = n0 + n;
#pragma unroll
        for (int i = 0; i < 4; ++i) {
            float4 v = make_float4(0.f, 0.f, 0.f, 0.f);
            if (gn < N) v = *(const float4*)(h + (size_t)gn * DH + c0 + 4 * i);
            sU[c0 + 4 * i + 0][n] = v.x; sU[c0 + 4 * i + 1][n] = v.y;
            sU[c0 + 4 * i + 2][n] = v.z; sU[c0 + 4 * i + 3][n] = v.w;
        }
#pragma unroll
        for (int i = 0; i < 4; ++i) {
            float4 v = make_float4(0.f, 0.f, 0.f, 0.f);
            if (gn < N) v = *(const float4*)(agg + (size_t)gn * DH + c0 + 4 * i);
            sU[DH + c0 + 4 * i + 0][n] = v.x; sU[DH + c0 + 4 * i + 1][n] = v.y;
            sU[DH + c0 + 4 * i + 2][n] = v.z; sU[DH + c0 + 4 * i + 3][n] = v.w;
        }
    }

    const int ng = tid & 7;
    const int jg = tid >> 3;
    const int sr = tid >> 4;
    const int sc = (tid & 15) * 8;

    float acc[4][4];
#pragma unroll
    for (int i = 0; i < 4; ++i)
#pragma unroll
        for (int j = 0; j < 4; ++j) acc[i][j] = 0.f;

    float4 rw[2];
    rw[0] = *(const float4*)(Wh1 + (size_t)sr * DH + sc);
    rw[1] = *(const float4*)(Wh1 + (size_t)sr * DH + sc + 4);
    for (int t = 0; t < 16; ++t) {
        __syncthreads();
        *(float4*)&sW[sr][sc]     = rw[0];
        *(float4*)&sW[sr][sc + 4] = rw[1];
        __syncthreads();
        if (t < 15) {
            const int k0 = 16 * (t + 1);
            rw[0] = *(const float4*)(Wh1 + (size_t)(k0 + sr) * DH + sc);
            rw[1] = *(const float4*)(Wh1 + (size_t)(k0 + sr) * DH + sc + 4);
        }
#pragma unroll
        for (int kk = 0; kk < 16; ++kk) {
            const float4 a = *(const float4*)&sU[t * 16 + kk][ng * 4];
            const float4 b = *(const float4*)&sW[kk][jg * 4];
            const float av[4] = {a.x, a.y, a.z, a.w};
            const float bv[4] = {b.x, b.y, b.z, b.w};
#pragma unroll
            for (int i = 0; i < 4; ++i)
#pragma unroll
                for (int j = 0; j < 4; ++j)
                    acc[i][j] = fmaf(av[i], bv[j], acc[i][j]);
        }
    }
#pragma unroll
    for (int jj = 0; jj < 4; ++jj) {
        const float bb = bh1[jg * 4 + jj];
#pragma unroll
        for (int i = 0; i < 4; ++i)
            sHid[jg * 4 + jj][ng * 4 + i] = silu_f(acc[i][jj] + bb);
    }

    float acc2[4][4];
#pragma unroll
    for (int i = 0; i < 4; ++i)
#pragma unroll
        for (int j = 0; j < 4; ++j) acc2[i][j] = 0.f;

    rw[0] = *(const float4*)(Wh2 + (size_t)sr * DH + sc);
    rw[1] = *(const float4*)(Wh2 + (size_t)sr * DH + sc + 4);
    for (int t = 0; t < 8; ++t) {
        __syncthreads();
        *(float4*)&sW[sr][sc]     = rw[0];
        *(float4*)&sW[sr][sc + 4] = rw[1];
        __syncthreads();
        if (t < 7) {
            const int k0 = 16 * (t + 1);
            rw[0] = *(const float4*)(Wh2 + (size_t)(k0 + sr) * DH + sc);
            rw[1] = *(const float4*)(Wh2 + (size_t)(k0 + sr) * DH + sc + 4);
        }
#pragma unroll
        for (int kk = 0; kk < 16; ++kk) {
            const float4 a = *(const float4*)&sHid[t * 16 + kk][ng * 4];
            const float4 b = *(const float4*)&sW[kk][jg * 4];
            const float av[4] = {a.x, a.y, a.z, a.w};
            const float bv[4] = {b.x, b.y, b.z, b.w};
#pragma unroll
            for (int i = 0; i < 4; ++i)
#pragma unroll
                for (int j = 0; j < 4; ++j)
                    acc2[i][j] = fmaf(av[i], bv[j], acc2[i][j]);
        }
    }

#pragma unroll
    for (int jj = 0; jj < 4; ++jj) {
        const float bb = bh2[jg * 4 + jj];
#pragma unroll
        for (int i = 0; i < 4; ++i) {
            const int gn = n0 + ng * 4 + i;
            float hv = 0.f;
            if (gn < N) hv = h[(size_t)gn * DH + jg * 4 + jj];
            sU[jg * 4 + jj][ng * 4 + i] = acc2[i][jj] + bb + hv;
        }
    }
    __syncthreads();

    {
        const int n = tid >> 3, sub = tid & 7;
        float s1 = 0.f, s2 = 0.f;
#pragma unroll
        for (int i = 0; i < 16; ++i) {
            const float z = sU[sub + 8 * i][n];
            s1 += z; s2 += z * z;
        }
#pragma unroll
        for (int m = 1; m < 8; m <<= 1) {
            s1 += __shfl_xor(s1, m, 64);
            s2 += __shfl_xor(s2, m, 64);
        }
        if (sub == 0) {
            const float mean = s1 * (1.f / 128.f);
            const float var = s2 * (1.f / 128.f) - mean * mean;
            sMean[n] = mean;
            sRstd[n] = rsqrtf(var + 1e-5f);
        }
    }
    __syncthreads();
    {
        const int n = tid >> 3, c0 = (tid & 7) * 16;
        const int gn = n0 + n;
        if (gn < N) {
            const float mean = sMean[n], rstd = sRstd[n];
#pragma unroll
            for (int i = 0; i < 4; ++i) {
                const float4 g4 = *(const float4*)(ln_g + c0 + 4 * i);
                const float4 b4 = *(const float4*)(ln_b + c0 + 4 * i);
                float4 o;
                o.x = (sU[c0 + 4 * i + 0][n] - mean) * rstd * g4.x + b4.x;
                o.y = (sU[c0 + 4 * i + 1][n] - mean) * rstd * g4.y + b4.y;
                o.z = (sU[c0 + 4 * i + 2][n] - mean) * rstd * g4.z + b4.z;
                o.w = (sU[c0 + 4 * i + 3][n] - mean) * rstd * g4.w + b4.w;
                *(float4*)(out + (size_t)gn * DH + c0 + 4 * i) = o;
            }
        }
    }
}

extern "C" void kernel_launch(void* const* d_in, const int* in_sizes, int n_in,
                              void* d_out, int out_size, void* d_ws, size_t ws_size,
                              hipStream_t stream)
{
    (void)n_in; (void)out_size;
    const float* h   = (const float*)d_in[0];
    const float* x   = (const float*)d_in[1];
    const int*   ei  = (const int*)d_in[2];
    const float* ew  = (const float*)d_in[3];
    const float* Wm1 = (const float*)d_in[4];
    const float* bm1 = (const float*)d_in[5];
    const float* Wm2 = (const float*)d_in[6];
    const float* bm2 = (const float*)d_in[7];
    const float* Wh1 = (const float*)d_in[8];
    const float* bh1 = (const float*)d_in[9];
    const float* Wh2 = (const float*)d_in[10];
    const float* bh2 = (const float*)d_in[11];
    const float* lng = (const float*)d_in[12];
    const float* lnb = (const float*)d_in[13];
    float* out = (float*)d_out;

    const int N = in_sizes[0] / DH;
    const int E = in_sizes[3];

    // ws layout: agg | counts | cursor | perm | Abf | Bbf | W2f | T
    float* agg   = (float*)d_ws;
    int* counts  = (int*)(agg + (size_t)N * DH);
    int* cursor  = counts + N;
    int* perm    = cursor + N;
    ushort_t* Abf = (ushort_t*)(perm + E);
    ushort_t* Bbf = Abf + (size_t)N * DH;
    ushort_t* W2f = Bbf + (size_t)N * DH;
    float* T      = (float*)(W2f + 16384);

    const size_t need = (size_t)N * DH * 4 + (size_t)(2 * N + E) * 4
                      + (size_t)N * DH * 4 + 32768 + (size_t)NTAB * DH * 4 + 64;
    const int use_sort = (ws_size >= need) ? 1 : 0;

    const int nb_hist = use_sort ? (E + 255) / 256 : 0;
    const int nb_prep = NTAB + 8;
    const int nb_scat = nb_hist;
    const int nb_pre  = (N + 31) / 32;

    hipMemsetAsync(agg, 0, (size_t)N * DH * sizeof(float) + (use_sort ? (size_t)N * 4 : 0), stream);
    k_hist_prep<<<nb_hist + nb_prep, 256, 0, stream>>>(ei, counts, E, Wm1, Wm2, T, W2f, nb_hist);
    if (use_sort)
        k_scan<<<1, 1024, 0, stream>>>(counts, cursor, N);
    k_scatter_pre<<<nb_scat + nb_pre, 256, 0, stream>>>(ei, cursor, perm, E,
                                                        h, Wm1, bm1, Abf, Bbf, N, nb_scat);
    k_edge<<<(E + EB - 1) / EB, 256, 0, stream>>>(x, ei, ew, W2f, bm2, Abf, Bbf, T,
                                                  agg, perm, use_sort, N, E);
    k_node<<<(N + 31) / 32, 256, 0, stream>>>(h, agg, Wh1, bh1, Wh2, bh2, lng, lnb, out, N);
}

// Round 7
// 601.598 us; speedup vs baseline: 5.4867x; 1.1010x over previous
//
#include <hip/hip_runtime.h>
#include <hip/hip_bf16.h>
#include <math.h>

#define DH 128
#define NRBF 16
#define EB 128     // edges per k_edge block (two 64-edge halves)
#define NTAB 1025
#define SEGCAP 32  // max LDS-resident dst segments per block

typedef unsigned short ushort_t;
typedef __attribute__((ext_vector_type(8))) short short8;
typedef __attribute__((ext_vector_type(4))) float floatx4;

__device__ __forceinline__ float silu_f(float v) {
    return v / (1.f + __expf(-v));
}

__device__ __forceinline__ unsigned pk_bf16(float lo, float hi) {
    __hip_bfloat162 h = __float22bfloat162_rn(make_float2(lo, hi));
    union { __hip_bfloat162 h2; unsigned u; } cv;
    cv.h2 = h;
    return cv.u;
}
__device__ __forceinline__ float bflo(unsigned u) { return __uint_as_float(u << 16); }
__device__ __forceinline__ float bfhi(unsigned u) { return __uint_as_float(u & 0xffff0000u); }

// int64 vs int32 edge_index layout: int64 little-endian -> odd 32-bit words all 0.
__device__ __forceinline__ int detect64(const int* __restrict__ ei) {
    int z = 0;
#pragma unroll
    for (int i = 0; i < 8; ++i) z |= ei[2 * i + 1];
    return (z == 0) ? 1 : 0;
}
__device__ __forceinline__ int load_dst(const int* ei, int is64, int e, int E) {
    return is64 ? ei[2 * E + 2 * e] : ei[E + e];
}
__device__ __forceinline__ int load_src(const int* ei, int is64, int e, int E) {
    return is64 ? ei[2 * e] : ei[e];
}

// ---------------------------------------------------------------------------
// Merged: histogram | RBF-table rows (bf16) | W2f fragment-permute
// ---------------------------------------------------------------------------
__global__ __launch_bounds__(256) void k_hist_prep(
    const int* __restrict__ ei, int* __restrict__ counts, int E,
    const float* __restrict__ Wm1, const float* __restrict__ Wm2,
    ushort_t* __restrict__ Tbf, ushort_t* __restrict__ W2f, int nb_hist)
{
    const int b = blockIdx.x, tid = threadIdx.x;
    if (b < nb_hist) {
        const int e = b * 256 + tid;
        if (e < E) {
            const int is64 = detect64(ei);
            atomicAdd(&counts[load_dst(ei, is64, e, E)], 1);
        }
        return;
    }
    const int b2 = b - nb_hist;
    if (b2 < NTAB) {
        if (tid < 64) {
            const float WIDTH = 0.09428090415820634f;  // sqrt(2)/15
            const float GAMMA = 56.25f;                // 1/(2*WIDTH^2)
            const float DELTA = 1.4142135623730951f / 1024.0f;
            const float r = (float)b2 * DELTA;
            const int c0 = 2 * tid;
            float a0 = 0.f, a1 = 0.f;
#pragma unroll
            for (int q = 0; q < NRBF; ++q) {
                const float dr = r - (float)q * WIDTH;
                const float w = __expf(-GAMMA * dr * dr);
                a0 = fmaf(w, Wm1[(256 + q) * DH + c0], a0);
                a1 = fmaf(w, Wm1[(256 + q) * DH + c0 + 1], a1);
            }
            *(unsigned*)(Tbf + (size_t)b2 * DH + c0) = pk_bf16(a0, a1);
        }
        return;
    }
    // W2f permute: 8 blocks x 256 threads cover u = 0..2047
    const int u = (b2 - NTAB) * 256 + tid;
    const int col = u & 127, lgc = u >> 7;
    const int lg = lgc & 3, kc = lgc >> 2;
    unsigned o[4];
#pragma unroll
    for (int j = 0; j < 2; ++j) {
        o[j]     = pk_bf16(Wm2[(kc * 32 + 4 * lg + 2 * j) * DH + col],
                           Wm2[(kc * 32 + 4 * lg + 2 * j + 1) * DH + col]);
        o[2 + j] = pk_bf16(Wm2[(kc * 32 + 16 + 4 * lg + 2 * j) * DH + col],
                           Wm2[(kc * 32 + 16 + 4 * lg + 2 * j + 1) * DH + col]);
    }
    *(uint4*)(W2f + 8 * u) = make_uint4(o[0], o[1], o[2], o[3]);
}

// ---------------------------------------------------------------------------
// Exclusive prefix sum of counts -> cursor. int4 vectorized. (N % 4 == 0 here)
// ---------------------------------------------------------------------------
__global__ __launch_bounds__(1024) void k_scan(const int* __restrict__ counts,
                                               int* __restrict__ cursor, int N) {
    __shared__ int wsum[16];
    __shared__ int sCarry;
    const int tid = threadIdx.x, lane = tid & 63, wid = tid >> 6;
    if (tid == 0) sCarry = 0;
    __syncthreads();
    for (int c0 = 0; c0 < N; c0 += 4096) {
        const int idx = c0 + tid * 4;
        int4 v = make_int4(0, 0, 0, 0);
        if (idx < N) v = *(const int4*)(counts + idx);
        const int t01 = v.x + v.y;
        const int t012 = t01 + v.z;
        const int tot = t012 + v.w;
        int incl = tot;
#pragma unroll
        for (int d = 1; d < 64; d <<= 1) {
            int t = __shfl_up(incl, d, 64);
            if (lane >= d) incl += t;
        }
        if (lane == 63) wsum[wid] = incl;
        __syncthreads();
        if (wid == 0) {
            int s = (lane < 16) ? wsum[lane] : 0;
#pragma unroll
            for (int d = 1; d < 16; d <<= 1) {
                int t = __shfl_up(s, d, 64);
                if (lane >= d) s += t;
            }
            if (lane < 16) wsum[lane] = s;
        }
        __syncthreads();
        const int ex = sCarry + (wid > 0 ? wsum[wid - 1] : 0) + incl - tot;
        if (idx + 3 < N) {
            *(int4*)(cursor + idx) = make_int4(ex, ex + v.x, ex + t01, ex + t012);
        } else if (idx < N) {
            cursor[idx] = ex;
            if (idx + 1 < N) cursor[idx + 1] = ex + v.x;
            if (idx + 2 < N) cursor[idx + 2] = ex + t01;
        }
        __syncthreads();
        if (tid == 0) sCarry += wsum[15];
        __syncthreads();
    }
}

// ---------------------------------------------------------------------------
// Merged: scatter sorted payloads (src,dst,ew) | precompute A/B -> bf16
// ---------------------------------------------------------------------------
__global__ __launch_bounds__(256) void k_scatter_pre(
    const int* __restrict__ ei, const float* __restrict__ ew,
    int* __restrict__ cursor, int* __restrict__ srcS, int* __restrict__ dstS,
    float* __restrict__ ewS, int E,
    const float* __restrict__ h, const float* __restrict__ Wm1, const float* __restrict__ bm1,
    ushort_t* __restrict__ Abf, ushort_t* __restrict__ Bbf, int N, int nb_scat)
{
    __shared__ float sH[DH][36];
    __shared__ float sW[16][256];
    const int tid = threadIdx.x;

    if ((int)blockIdx.x < nb_scat) {
        const int e = blockIdx.x * 256 + tid;
        if (e < E) {
            const int is64 = detect64(ei);
            const int s = load_src(ei, is64, e, E);
            const int d = load_dst(ei, is64, e, E);
            const int pos = atomicAdd(&cursor[d], 1);
            srcS[pos] = s;
            dstS[pos] = d;
            ewS[pos] = ew[e];
        }
        return;
    }

    const int n0 = (blockIdx.x - nb_scat) * 32;
    {
        const int n = tid >> 3;
        const int c0 = (tid & 7) * 16;
        const int gn = n0 + n;
#pragma unroll
        for (int i = 0; i < 4; ++i) {
            float4 v = make_float4(0.f, 0.f, 0.f, 0.f);
            if (gn < N) v = *(const float4*)(h + (size_t)gn * DH + c0 + 4 * i);
            sH[c0 + 4 * i + 0][n] = v.x;
            sH[c0 + 4 * i + 1][n] = v.y;
            sH[c0 + 4 * i + 2][n] = v.z;
            sH[c0 + 4 * i + 3][n] = v.w;
        }
    }

    const int ng = tid & 7;
    const int jg = tid >> 3;
    const int sr = tid >> 4;
    const int sc = (tid & 15) * 16;

    float acc[4][8];
#pragma unroll
    for (int i = 0; i < 4; ++i)
#pragma unroll
        for (int j = 0; j < 8; ++j) acc[i][j] = 0.f;

    float4 rw[4];
#pragma unroll
    for (int i = 0; i < 4; ++i) {
        const int c = sc + 4 * i;
        const float* p = (c < DH) ? (Wm1 + (size_t)sr * DH + c)
                                  : (Wm1 + (size_t)(DH + sr) * DH + (c - DH));
        rw[i] = *(const float4*)p;
    }

    for (int t = 0; t < 8; ++t) {
        __syncthreads();
#pragma unroll
        for (int i = 0; i < 4; ++i) *(float4*)&sW[sr][sc + 4 * i] = rw[i];
        __syncthreads();
        if (t < 7) {
            const int k0 = 16 * (t + 1);
#pragma unroll
            for (int i = 0; i < 4; ++i) {
                const int c = sc + 4 * i;
                const float* p = (c < DH) ? (Wm1 + (size_t)(k0 + sr) * DH + c)
                                          : (Wm1 + (size_t)(DH + k0 + sr) * DH + (c - DH));
                rw[i] = *(const float4*)p;
            }
        }
#pragma unroll
        for (int kk = 0; kk < 16; ++kk) {
            const float4 a  = *(const float4*)&sH[t * 16 + kk][ng * 4];
            const float4 b0 = *(const float4*)&sW[kk][jg * 8];
            const float4 b1 = *(const float4*)&sW[kk][jg * 8 + 4];
            const float av[4] = {a.x, a.y, a.z, a.w};
            const float bv[8] = {b0.x, b0.y, b0.z, b0.w, b1.x, b1.y, b1.z, b1.w};
#pragma unroll
            for (int i = 0; i < 4; ++i)
#pragma unroll
                for (int j = 0; j < 8; ++j)
                    acc[i][j] = fmaf(av[i], bv[j], acc[i][j]);
        }
    }

    const int j0 = jg * 8;
#pragma unroll
    for (int i = 0; i < 4; ++i) {
        const int gn = n0 + ng * 4 + i;
        if (gn >= N) continue;
        if (j0 < DH) {
            float o[8];
#pragma unroll
            for (int j = 0; j < 8; ++j) o[j] = acc[i][j] + bm1[j0 + j];
            uint2 p0, p1;
            p0.x = pk_bf16(o[0], o[1]); p0.y = pk_bf16(o[2], o[3]);
            p1.x = pk_bf16(o[4], o[5]); p1.y = pk_bf16(o[6], o[7]);
            *(uint2*)(Abf + (size_t)gn * DH + j0) = p0;
            *(uint2*)(Abf + (size_t)gn * DH + j0 + 4) = p1;
        } else {
            const int jb = j0 - DH;
            uint2 p0, p1;
            p0.x = pk_bf16(acc[i][0], acc[i][1]); p0.y = pk_bf16(acc[i][2], acc[i][3]);
            p1.x = pk_bf16(acc[i][4], acc[i][5]); p1.y = pk_bf16(acc[i][6], acc[i][7]);
            *(uint2*)(Bbf + (size_t)gn * DH + jb) = p0;
            *(uint2*)(Bbf + (size_t)gn * DH + jb + 4) = p1;
        }
    }
}

// ---------------------------------------------------------------------------
// Edge kernel with LDS segment accumulation.
//   staging: coalesced sorted payloads; per-slot rbf index; lid seg-scan.
//   per half: phase1 build hidden -> sHid (swizzled bf16),
//             phase2 MFMA (W2f global), phase3 run-merge by lid ->
//             ds_add into ldsAgg[lid][col] (global atomic only if lid>=SEGCAP).
//   flush: interior segments plain store, boundary segments atomicAdd.
// ---------------------------------------------------------------------------
__global__ __launch_bounds__(256, 4) void k_edge(
    const float* __restrict__ x, const int* __restrict__ ei, const float* __restrict__ ew,
    const int* __restrict__ srcS, const int* __restrict__ dstS, const float* __restrict__ ewS,
    const ushort_t* __restrict__ W2f, const float* __restrict__ bm2,
    const ushort_t* __restrict__ Abf, const ushort_t* __restrict__ Bbf,
    const ushort_t* __restrict__ Tbf, float* __restrict__ agg,
    int sorted, int N, int E)
{
    __shared__ __align__(16) ushort_t sHid[64 * DH];      // 16 KB
    __shared__ __align__(16) float ldsAgg[SEGCAP][DH];    // 16 KB
    __shared__ int   sSrc[EB];
    __shared__ int   sDst[EB];
    __shared__ int   sLid[EB];
    __shared__ int   sTi[EB];
    __shared__ float sEw[EB];
    __shared__ int   sSegStart[SEGCAP];
    __shared__ int   sNseg, sW0tot;

    const int tid = threadIdx.x;

    // XCD-chunked bijective swizzle (8 XCDs, round-robin hardware dispatch)
    const int nwg = gridDim.x;
    const int xcd = blockIdx.x & 7;
    const int cidx = blockIdx.x >> 3;
    const int qch = nwg >> 3, rch = nwg & 7;
    const int bid = (xcd < rch) ? (xcd * (qch + 1) + cidx)
                                : (rch * (qch + 1) + (xcd - rch) * qch + cidx);
    const int e0 = bid * EB;

    // zero ldsAgg: 4096 floats = 1024 float4
    {
        const float4 z = make_float4(0.f, 0.f, 0.f, 0.f);
        float4* za = (float4*)&ldsAgg[0][0];
#pragma unroll
        for (int i = 0; i < 4; ++i) za[tid + 256 * i] = z;
    }

    // ---- staging (coalesced) ----
    if (tid < EB) {
        const int slot = e0 + tid;
        int s = 0, d = 0, ti = 0;
        float w = 0.f;
        const int is64 = sorted ? 0 : detect64(ei);
        if (slot < E) {
            if (sorted) { s = srcS[slot]; d = dstS[slot]; w = ewS[slot]; }
            else { s = load_src(ei, is64, slot, E); d = load_dst(ei, is64, slot, E); w = ew[slot]; }
            const float2 xs = *(const float2*)(x + 2 * s);
            const float2 xd = *(const float2*)(x + 2 * d);
            const float dxv = xs.x - xd.x, dyv = xs.y - xd.y;
            const float r = sqrtf(dxv * dxv + dyv * dyv + 1e-8f);
            ti = (int)(r * 724.0773439350246f + 0.5f);   // 1024/sqrt(2)
            ti = min(ti, NTAB - 1);
        } else {
            // pad: merge into last real segment, zero weight
            d = sorted ? dstS[E - 1] : load_dst(ei, is64, E - 1, E);
        }
        sSrc[tid] = s; sDst[tid] = d; sEw[tid] = w; sTi[tid] = ti;
    }
    __syncthreads();

    // ---- lid segment scan over 128 slots (2 waves) ----
    int bflag = 0, incl = 0;
    if (tid < EB) {
        bflag = (tid > 0) && (sDst[tid] != sDst[tid - 1]);
        incl = bflag;
#pragma unroll
        for (int dd = 1; dd < 64; dd <<= 1) {
            int t = __shfl_up(incl, dd, 64);
            if ((tid & 63) >= dd) incl += t;
        }
    }
    if (tid == 63) sW0tot = incl;
    __syncthreads();
    if (tid >= 64 && tid < EB) incl += sW0tot;
    if (tid < EB) {
        sLid[tid] = incl;
        if ((bflag || tid == 0) && incl < SEGCAP) sSegStart[incl] = tid;
        if (tid == EB - 1) sNseg = incl + 1;
    }
    __syncthreads();

    const int lane = tid & 63;
    const int wv   = tid >> 6;
    const int lr   = lane & 15;
    const int lg   = lane >> 4;
    const int m0l  = (wv & 1) * 32;       // wave's edge sub-tile within half
    const int n0   = (wv >> 1) * 64;      // wave's column sub-tile

    // bias per (ni): same for both halves
    float bc4[4];
#pragma unroll
    for (int ni = 0; ni < 4; ++ni) bc4[ni] = bm2[n0 + ni * 16 + lr];

    union FragU { unsigned u[4]; short8 s8; };

    for (int half = 0; half < 2; ++half) {
        const int eh = half * 64;

        // ---- phase 1: build 64-edge hidden tile (4 thr/edge, 32 cols) ----
        {
            const int el = tid >> 2;          // local edge 0..63
            const int q  = tid & 3;           // col quarter
            const int le = eh + el;
            const int s  = sSrc[le];
            const int ti = sTi[le];
            const uint4* pA = (const uint4*)(Abf + (size_t)s * DH + 32 * q);
            const uint4* pB = (const uint4*)(Bbf + (size_t)sDst[le] * DH + 32 * q);
            const uint4* pT = (const uint4*)(Tbf + (size_t)ti * DH + 32 * q);
            uint4* rowp = (uint4*)(sHid + el * DH);
            const int swz = el & 7;
#pragma unroll
            for (int i = 0; i < 4; ++i) {
                const uint4 a = pA[i];
                const uint4 b = pB[i];
                const uint4 t = pT[i];
                const float v0 = bflo(a.x) + bflo(b.x) + bflo(t.x);
                const float v1 = bfhi(a.x) + bfhi(b.x) + bfhi(t.x);
                const float v2 = bflo(a.y) + bflo(b.y) + bflo(t.y);
                const float v3 = bfhi(a.y) + bfhi(b.y) + bfhi(t.y);
                const float v4 = bflo(a.z) + bflo(b.z) + bflo(t.z);
                const float v5 = bfhi(a.z) + bfhi(b.z) + bfhi(t.z);
                const float v6 = bflo(a.w) + bflo(b.w) + bflo(t.w);
                const float v7 = bfhi(a.w) + bfhi(b.w) + bfhi(t.w);
                uint4 pk;
                pk.x = pk_bf16(silu_f(v0), silu_f(v1));
                pk.y = pk_bf16(silu_f(v2), silu_f(v3));
                pk.z = pk_bf16(silu_f(v4), silu_f(v5));
                pk.w = pk_bf16(silu_f(v6), silu_f(v7));
                rowp[(4 * q + i) ^ swz] = pk;
            }
        }
        __syncthreads();

        // ---- phase 2: MFMA  32 edges x 64 cols per wave ----
        floatx4 acc[2][4];
#pragma unroll
        for (int mi = 0; mi < 2; ++mi)
#pragma unroll
            for (int ni = 0; ni < 4; ++ni) acc[mi][ni] = (floatx4){0.f, 0.f, 0.f, 0.f};

#pragma unroll
        for (int kc = 0; kc < 4; ++kc) {
            const int b1 = 64 * kc + 8 * lg;
            const int b2 = b1 + 32;
            FragU af[2];
#pragma unroll
            for (int mi = 0; mi < 2; ++mi) {
                const int le2 = m0l + mi * 16 + lr;
                const char* rbase = (const char*)(sHid + le2 * DH);
                const int swz = (le2 & 7) << 4;
                const uint2 lo = *(const uint2*)(rbase + ((b1 & ~15) ^ swz) + (b1 & 15));
                const uint2 hi = *(const uint2*)(rbase + ((b2 & ~15) ^ swz) + (b2 & 15));
                af[mi].u[0] = lo.x; af[mi].u[1] = lo.y;
                af[mi].u[2] = hi.x; af[mi].u[3] = hi.y;
            }
            const ushort_t* wbase = W2f + ((size_t)(kc * 4 + lg) * 128 + n0 + lr) * 8;
            __builtin_amdgcn_s_setprio(1);
#pragma unroll
            for (int ni = 0; ni < 4; ++ni) {
                const short8 bf = *(const short8*)(wbase + ni * 128);
                acc[0][ni] = __builtin_amdgcn_mfma_f32_16x16x32_bf16(af[0].s8, bf, acc[0][ni], 0, 0, 0);
                acc[1][ni] = __builtin_amdgcn_mfma_f32_16x16x32_bf16(af[1].s8, bf, acc[1][ni], 0, 0, 0);
            }
            __builtin_amdgcn_s_setprio(0);
        }

        // ---- phase 3: run-merge by lid -> LDS segment accumulation ----
        int   lid4[2][4];
        float ew4[2][4];
        int   hs[2];
#pragma unroll
        for (int mi = 0; mi < 2; ++mi) {
            const int sb = eh + m0l + mi * 16 + 4 * lg;
            hs[mi] = sb;
#pragma unroll
            for (int r = 0; r < 4; ++r) { lid4[mi][r] = sLid[sb + r]; ew4[mi][r] = sEw[sb + r]; }
        }
#pragma unroll
        for (int ni = 0; ni < 4; ++ni) {
            const int col = n0 + ni * 16 + lr;
            const float bc = bc4[ni];
#pragma unroll
            for (int mi = 0; mi < 2; ++mi) {
                int cur = lid4[mi][0], curSlot = hs[mi];
                float av = (acc[mi][ni][0] + bc) * ew4[mi][0];
#pragma unroll
                for (int r = 1; r < 4; ++r) {
                    const int l2 = lid4[mi][r];
                    const float v = (acc[mi][ni][r] + bc) * ew4[mi][r];
                    if (l2 == cur) av += v;
                    else {
                        if (cur < SEGCAP) atomicAdd(&ldsAgg[cur][col], av);
                        else atomicAdd(agg + (size_t)sDst[curSlot] * DH + col, av);
                        cur = l2; curSlot = hs[mi] + r; av = v;
                    }
                }
                if (cur < SEGCAP) atomicAdd(&ldsAgg[cur][col], av);
                else atomicAdd(agg + (size_t)sDst[curSlot] * DH + col, av);
            }
        }
        __syncthreads();   // protect sHid for next half; ds_adds drained
    }

    // ---- flush: interior segments plain store, boundary atomicAdd ----
    const int ns = sNseg;
    const int gmax = (ns < SEGCAP) ? ns : SEGCAP;
    for (int idx = tid; idx < (gmax << 7); idx += 256) {
        const int g = idx >> 7, col = idx & 127;
        const float v = ldsAgg[g][col];
        const int dst = sDst[sSegStart[g]];
        float* p = agg + (size_t)dst * DH + col;
        if (sorted && g > 0 && g < ns - 1) *p = v;
        else atomicAdd(p, v);
    }
}

// ---------------------------------------------------------------------------
// Node MLP + residual + LayerNorm. 32 nodes/block, 256 threads.
// ---------------------------------------------------------------------------
__global__ __launch_bounds__(256) void k_node(
    const float* __restrict__ h, const float* __restrict__ agg,
    const float* __restrict__ Wh1, const float* __restrict__ bh1,
    const float* __restrict__ Wh2, const float* __restrict__ bh2,
    const float* __restrict__ ln_g, const float* __restrict__ ln_b,
    float* __restrict__ out, int N)
{
    __shared__ float sU[2 * DH][36];
    __shared__ float sHid[DH][36];
    __shared__ float sW[16][DH];
    __shared__ float sMean[32], sRstd[32];
    const int tid = threadIdx.x;
    const int n0 = blockIdx.x * 32;

    {
        const int n = tid >> 3;
        const int c0 = (tid & 7) * 16;
        const int gn = n0 + n;
#pragma unroll
        for (int i = 0; i < 4; ++i) {
            float4 v = make_float4(0.f, 0.f, 0.f, 0.f);
            if (gn < N) v = *(const float4*)(h + (size_t)gn * DH + c0 + 4 * i);
            sU[c0 + 4 * i + 0][n] = v.x; sU[c0 + 4 * i + 1][n] = v.y;
            sU[c0 + 4 * i + 2][n] = v.z; sU[c0 + 4 * i + 3][n] = v.w;
        }
#pragma unroll
        for (int i = 0; i < 4; ++i) {
            float4 v = make_float4(0.f, 0.f, 0.f, 0.f);
            if (gn < N) v = *(const float4*)(agg + (size_t)gn * DH + c0 + 4 * i);
            sU[DH + c0 + 4 * i + 0][n] = v.x; sU[DH + c0 + 4 * i + 1][n] = v.y;
            sU[DH + c0 + 4 * i + 2][n] = v.z; sU[DH + c0 + 4 * i + 3][n] = v.w;
        }
    }

    const int ng = tid & 7;
    const int jg = tid >> 3;
    const int sr = tid >> 4;
    const int sc = (tid & 15) * 8;

    float acc[4][4];
#pragma unroll
    for (int i = 0; i < 4; ++i)
#pragma unroll
        for (int j = 0; j < 4; ++j) acc[i][j] = 0.f;

    float4 rw[2];
    rw[0] = *(const float4*)(Wh1 + (size_t)sr * DH + sc);
    rw[1] = *(const float4*)(Wh1 + (size_t)sr * DH + sc + 4);
    for (int t = 0; t < 16; ++t) {
        __syncthreads();
        *(float4*)&sW[sr][sc]     = rw[0];
        *(float4*)&sW[sr][sc + 4] = rw[1];
        __syncthreads();
        if (t < 15) {
            const int k0 = 16 * (t + 1);
            rw[0] = *(const float4*)(Wh1 + (size_t)(k0 + sr) * DH + sc);
            rw[1] = *(const float4*)(Wh1 + (size_t)(k0 + sr) * DH + sc + 4);
        }
#pragma unroll
        for (int kk = 0; kk < 16; ++kk) {
            const float4 a = *(const float4*)&sU[t * 16 + kk][ng * 4];
            const float4 b = *(const float4*)&sW[kk][jg * 4];
            const float av[4] = {a.x, a.y, a.z, a.w};
            const float bv[4] = {b.x, b.y, b.z, b.w};
#pragma unroll
            for (int i = 0; i < 4; ++i)
#pragma unroll
                for (int j = 0; j < 4; ++j)
                    acc[i][j] = fmaf(av[i], bv[j], acc[i][j]);
        }
    }
#pragma unroll
    for (int jj = 0; jj < 4; ++jj) {
        const float bb = bh1[jg * 4 + jj];
#pragma unroll
        for (int i = 0; i < 4; ++i)
            sHid[jg * 4 + jj][ng * 4 + i] = silu_f(acc[i][jj] + bb);
    }

    float acc2[4][4];
#pragma unroll
    for (int i = 0; i < 4; ++i)
#pragma unroll
        for (int j = 0; j < 4; ++j) acc2[i][j] = 0.f;

    rw[0] = *(const float4*)(Wh2 + (size_t)sr * DH + sc);
    rw[1] = *(const float4*)(Wh2 + (size_t)sr * DH + sc + 4);
    for (int t = 0; t < 8; ++t) {
        __syncthreads();
        *(float4*)&sW[sr][sc]     = rw[0];
        *(float4*)&sW[sr][sc + 4] = rw[1];
        __syncthreads();
        if (t < 7) {
            const int k0 = 16 * (t + 1);
            rw[0] = *(const float4*)(Wh2 + (size_t)(k0 + sr) * DH + sc);
            rw[1] = *(const float4*)(Wh2 + (size_t)(k0 + sr) * DH + sc + 4);
        }
#pragma unroll
        for (int kk = 0; kk < 16; ++kk) {
            const float4 a = *(const float4*)&sHid[t * 16 + kk][ng * 4];
            const float4 b = *(const float4*)&sW[kk][jg * 4];
            const float av[4] = {a.x, a.y, a.z, a.w};
            const float bv[4] = {b.x, b.y, b.z, b.w};
#pragma unroll
            for (int i = 0; i < 4; ++i)
#pragma unroll
                for (int j = 0; j < 4; ++j)
                    acc2[i][j] = fmaf(av[i], bv[j], acc2[i][j]);
        }
    }

#pragma unroll
    for (int jj = 0; jj < 4; ++jj) {
        const float bb = bh2[jg * 4 + jj];
#pragma unroll
        for (int i = 0; i < 4; ++i) {
            const int gn = n0 + ng * 4 + i;
            float hv = 0.f;
            if (gn < N) hv = h[(size_t)gn * DH + jg * 4 + jj];
            sU[jg * 4 + jj][ng * 4 + i] = acc2[i][jj] + bb + hv;
        }
    }
    __syncthreads();

    {
        const int n = tid >> 3, sub = tid & 7;
        float s1 = 0.f, s2 = 0.f;
#pragma unroll
        for (int i = 0; i < 16; ++i) {
            const float z = sU[sub + 8 * i][n];
            s1 += z; s2 += z * z;
        }
#pragma unroll
        for (int m = 1; m < 8; m <<= 1) {
            s1 += __shfl_xor(s1, m, 64);
            s2 += __shfl_xor(s2, m, 64);
        }
        if (sub == 0) {
            const float mean = s1 * (1.f / 128.f);
            const float var = s2 * (1.f / 128.f) - mean * mean;
            sMean[n] = mean;
            sRstd[n] = rsqrtf(var + 1e-5f);
        }
    }
    __syncthreads();
    {
        const int n = tid >> 3, c0 = (tid & 7) * 16;
        const int gn = n0 + n;
        if (gn < N) {
            const float mean = sMean[n], rstd = sRstd[n];
#pragma unroll
            for (int i = 0; i < 4; ++i) {
                const float4 g4 = *(const float4*)(ln_g + c0 + 4 * i);
                const float4 b4 = *(const float4*)(ln_b + c0 + 4 * i);
                float4 o;
                o.x = (sU[c0 + 4 * i + 0][n] - mean) * rstd * g4.x + b4.x;
                o.y = (sU[c0 + 4 * i + 1][n] - mean) * rstd * g4.y + b4.y;
                o.z = (sU[c0 + 4 * i + 2][n] - mean) * rstd * g4.z + b4.z;
                o.w = (sU[c0 + 4 * i + 3][n] - mean) * rstd * g4.w + b4.w;
                *(float4*)(out + (size_t)gn * DH + c0 + 4 * i) = o;
            }
        }
    }
}

extern "C" void kernel_launch(void* const* d_in, const int* in_sizes, int n_in,
                              void* d_out, int out_size, void* d_ws, size_t ws_size,
                              hipStream_t stream)
{
    (void)n_in; (void)out_size;
    const float* h   = (const float*)d_in[0];
    const float* x   = (const float*)d_in[1];
    const int*   ei  = (const int*)d_in[2];
    const float* ew  = (const float*)d_in[3];
    const float* Wm1 = (const float*)d_in[4];
    const float* bm1 = (const float*)d_in[5];
    const float* Wm2 = (const float*)d_in[6];
    const float* bm2 = (const float*)d_in[7];
    const float* Wh1 = (const float*)d_in[8];
    const float* bh1 = (const float*)d_in[9];
    const float* Wh2 = (const float*)d_in[10];
    const float* bh2 = (const float*)d_in[11];
    const float* lng = (const float*)d_in[12];
    const float* lnb = (const float*)d_in[13];
    float* out = (float*)d_out;

    const int N = in_sizes[0] / DH;
    const int E = in_sizes[3];

    // ws layout: mandatory first: agg | Abf | Bbf | W2f | Tbf
    //            then optional:  counts | cursor | srcS | dstS | ewS
    float*    agg = (float*)d_ws;
    ushort_t* Abf = (ushort_t*)(agg + (size_t)N * DH);
    ushort_t* Bbf = Abf + (size_t)N * DH;
    ushort_t* W2f = Bbf + (size_t)N * DH;
    ushort_t* Tbf = W2f + 16384;
    int* counts   = (int*)(Tbf + (size_t)NTAB * DH);
    int* cursor   = counts + N;
    int* srcS     = cursor + N;
    int* dstS     = srcS + E;
    float* ewS    = (float*)(dstS + E);

    const size_t need = (size_t)N * DH * 4 + (size_t)N * DH * 4 + 32768
                      + (size_t)NTAB * DH * 2 + (size_t)(2 * N + 3 * E) * 4 + 64;
    const int use_sort = (ws_size >= need) ? 1 : 0;

    const int nb_hist = use_sort ? (E + 255) / 256 : 0;
    const int nb_prep = NTAB + 8;
    const int nb_scat = nb_hist;
    const int nb_pre  = (N + 31) / 32;

    // zero agg (+ counts if sorting; counts is right after Tbf, not contiguous
    // with agg -> separate memset)
    hipMemsetAsync(agg, 0, (size_t)N * DH * sizeof(float), stream);
    if (use_sort)
        hipMemsetAsync(counts, 0, (size_t)N * sizeof(int), stream);
    k_hist_prep<<<nb_hist + nb_prep, 256, 0, stream>>>(ei, counts, E, Wm1, Wm2, Tbf, W2f, nb_hist);
    if (use_sort)
        k_scan<<<1, 1024, 0, stream>>>(counts, cursor, N);
    k_scatter_pre<<<nb_scat + nb_pre, 256, 0, stream>>>(ei, ew, cursor, srcS, dstS, ewS, E,
                                                        h, Wm1, bm1, Abf, Bbf, N, nb_scat);
    k_edge<<<(E + EB - 1) / EB, 256, 0, stream>>>(x, ei, ew, srcS, dstS, ewS,
                                                  W2f, bm2, Abf, Bbf, Tbf, agg,
                                                  use_sort, N, E);
    k_node<<<(N + 31) / 32, 256, 0, stream>>>(h, agg, Wh1, bh1, Wh2, bh2, lng, lnb, out, N);
}

// Round 8
// 436.757 us; speedup vs baseline: 7.5575x; 1.3774x over previous
//
#include <hip/hip_runtime.h>
#include <hip/hip_bf16.h>
#include <math.h>

#define DH 128
#define NRBF 16
#define EB 128     // edges per k_edge block (two 64-edge halves)
#define NTAB 1025
#define SEGCAP 32  // max LDS-resident dst segments per block

typedef unsigned short ushort_t;
typedef __attribute__((ext_vector_type(8))) short short8;
typedef __attribute__((ext_vector_type(4))) float floatx4;

__device__ __forceinline__ float silu_f(float v) {
    return v / (1.f + __expf(-v));
}
__device__ __forceinline__ unsigned pk_bf16(float lo, float hi) {
    __hip_bfloat162 h = __float22bfloat162_rn(make_float2(lo, hi));
    union { __hip_bfloat162 h2; unsigned u; } cv;
    cv.h2 = h;
    return cv.u;
}
__device__ __forceinline__ ushort_t f2bf1(float f) {
    unsigned u = __float_as_uint(f);
    u += 0x7FFFu + ((u >> 16) & 1u);
    return (ushort_t)(u >> 16);
}
__device__ __forceinline__ float bflo(unsigned u) { return __uint_as_float(u << 16); }
__device__ __forceinline__ float bfhi(unsigned u) { return __uint_as_float(u & 0xffff0000u); }
__device__ __forceinline__ float bf2f(ushort_t u) { return __uint_as_float(((unsigned)u) << 16); }

__device__ __forceinline__ int detect64(const int* __restrict__ ei) {
    int z = 0;
#pragma unroll
    for (int i = 0; i < 8; ++i) z |= ei[2 * i + 1];
    return (z == 0) ? 1 : 0;
}
__device__ __forceinline__ int load_dst(const int* ei, int is64, int e, int E) {
    return is64 ? ei[2 * E + 2 * e] : ei[E + e];
}
__device__ __forceinline__ int load_src(const int* ei, int is64, int e, int E) {
    return is64 ? ei[2 * e] : ei[e];
}

// ---------------------------------------------------------------------------
// Merged prep: histogram | Tbf rows (4/block) | W2f | W1mf | W1hf | W2hf
// All W*f tables are bf16 fragment-linear: entry ((kc*4+lg)*COLS + c)*8 + j
// holds rows {kc*32+4lg+j} (j<4) and {kc*32+16+4lg+j-4} (j>=4) at col c.
// ---------------------------------------------------------------------------
__global__ __launch_bounds__(256) void k_hist_prep(
    const int* __restrict__ ei, int* __restrict__ counts, int E,
    const float* __restrict__ Wm1, const float* __restrict__ Wm2,
    const float* __restrict__ Wh1, const float* __restrict__ Wh2,
    ushort_t* __restrict__ Tbf, ushort_t* __restrict__ W2f,
    ushort_t* __restrict__ W1mf, ushort_t* __restrict__ W1hf,
    ushort_t* __restrict__ W2hf, int nb_hist)
{
    const int b = blockIdx.x, tid = threadIdx.x;
    if (b < nb_hist) {
        const int e = b * 256 + tid;
        if (e < E) {
            const int is64 = detect64(ei);
            atomicAdd(&counts[load_dst(ei, is64, e, E)], 1);
        }
        return;
    }
    int b2 = b - nb_hist;
    if (b2 < 257) {   // Tbf: 4 rows/block
        const int i = b2 * 4 + (tid >> 6);
        if (i < NTAB) {
            const float WIDTH = 0.09428090415820634f;  // sqrt(2)/15
            const float GAMMA = 56.25f;                // 1/(2*WIDTH^2)
            const float DELTA = 1.4142135623730951f / 1024.0f;
            const float r = (float)i * DELTA;
            const int c0 = (tid & 63) * 2;
            float a0 = 0.f, a1 = 0.f;
#pragma unroll
            for (int q = 0; q < NRBF; ++q) {
                const float dr = r - (float)q * WIDTH;
                const float w = __expf(-GAMMA * dr * dr);
                a0 = fmaf(w, Wm1[(256 + q) * DH + c0], a0);
                a1 = fmaf(w, Wm1[(256 + q) * DH + c0 + 1], a1);
            }
            *(unsigned*)(Tbf + (size_t)i * DH + c0) = pk_bf16(a0, a1);
        }
        return;
    }
    b2 -= 257;
    if (b2 < 8) {   // W2f (Wm2, K=128, 128 cols)
        const int u = b2 * 256 + tid;
        const int col = u & 127, kclg = u >> 7;
        const int lg = kclg & 3, kc = kclg >> 2;
        unsigned o[4];
#pragma unroll
        for (int j = 0; j < 2; ++j) {
            o[j]     = pk_bf16(Wm2[(kc * 32 + 4 * lg + 2 * j) * DH + col],
                               Wm2[(kc * 32 + 4 * lg + 2 * j + 1) * DH + col]);
            o[2 + j] = pk_bf16(Wm2[(kc * 32 + 16 + 4 * lg + 2 * j) * DH + col],
                               Wm2[(kc * 32 + 16 + 4 * lg + 2 * j + 1) * DH + col]);
        }
        *(uint4*)(W2f + 8 * u) = make_uint4(o[0], o[1], o[2], o[3]);
        return;
    }
    b2 -= 8;
    if (b2 < 16) {  // W1mf (Wm1 rows 0..255, K=128, 256 "cols": A|B)
        const int u = b2 * 256 + tid;          // 0..4095
        const int c = u & 255, kclg = u >> 8;
        const int lg = kclg & 3, kc = kclg >> 2;
        const int base = (c < 128) ? 0 : 128;
        const int cc = c & 127;
        unsigned o[4];
#pragma unroll
        for (int j = 0; j < 2; ++j) {
            o[j]     = pk_bf16(Wm1[(base + kc * 32 + 4 * lg + 2 * j) * DH + cc],
                               Wm1[(base + kc * 32 + 4 * lg + 2 * j + 1) * DH + cc]);
            o[2 + j] = pk_bf16(Wm1[(base + kc * 32 + 16 + 4 * lg + 2 * j) * DH + cc],
                               Wm1[(base + kc * 32 + 16 + 4 * lg + 2 * j + 1) * DH + cc]);
        }
        *(uint4*)(W1mf + 8 * u) = make_uint4(o[0], o[1], o[2], o[3]);
        return;
    }
    b2 -= 16;
    if (b2 < 16) {  // W1hf (Wh1, K=256, 128 cols)
        const int u = b2 * 256 + tid;          // 0..4095
        const int col = u & 127, kclg = u >> 7; // 0..31
        const int lg = kclg & 3, kc = kclg >> 2;
        unsigned o[4];
#pragma unroll
        for (int j = 0; j < 2; ++j) {
            o[j]     = pk_bf16(Wh1[(kc * 32 + 4 * lg + 2 * j) * DH + col],
                               Wh1[(kc * 32 + 4 * lg + 2 * j + 1) * DH + col]);
            o[2 + j] = pk_bf16(Wh1[(kc * 32 + 16 + 4 * lg + 2 * j) * DH + col],
                               Wh1[(kc * 32 + 16 + 4 * lg + 2 * j + 1) * DH + col]);
        }
        *(uint4*)(W1hf + 8 * u) = make_uint4(o[0], o[1], o[2], o[3]);
        return;
    }
    b2 -= 16;
    {   // W2hf (Wh2, K=128, 128 cols)
        const int u = b2 * 256 + tid;
        const int col = u & 127, kclg = u >> 7;
        const int lg = kclg & 3, kc = kclg >> 2;
        unsigned o[4];
#pragma unroll
        for (int j = 0; j < 2; ++j) {
            o[j]     = pk_bf16(Wh2[(kc * 32 + 4 * lg + 2 * j) * DH + col],
                               Wh2[(kc * 32 + 4 * lg + 2 * j + 1) * DH + col]);
            o[2 + j] = pk_bf16(Wh2[(kc * 32 + 16 + 4 * lg + 2 * j) * DH + col],
                               Wh2[(kc * 32 + 16 + 4 * lg + 2 * j + 1) * DH + col]);
        }
        *(uint4*)(W2hf + 8 * u) = make_uint4(o[0], o[1], o[2], o[3]);
    }
}

// ---------------------------------------------------------------------------
// Exclusive prefix sum of counts -> cursor.
// ---------------------------------------------------------------------------
__global__ __launch_bounds__(1024) void k_scan(const int* __restrict__ counts,
                                               int* __restrict__ cursor, int N) {
    __shared__ int wsum[16];
    __shared__ int sCarry;
    const int tid = threadIdx.x, lane = tid & 63, wid = tid >> 6;
    if (tid == 0) sCarry = 0;
    __syncthreads();
    for (int c0 = 0; c0 < N; c0 += 4096) {
        const int idx = c0 + tid * 4;
        int4 v = make_int4(0, 0, 0, 0);
        if (idx < N) v = *(const int4*)(counts + idx);
        const int t01 = v.x + v.y;
        const int t012 = t01 + v.z;
        const int tot = t012 + v.w;
        int incl = tot;
#pragma unroll
        for (int d = 1; d < 64; d <<= 1) {
            int t = __shfl_up(incl, d, 64);
            if (lane >= d) incl += t;
        }
        if (lane == 63) wsum[wid] = incl;
        __syncthreads();
        if (wid == 0) {
            int s = (lane < 16) ? wsum[lane] : 0;
#pragma unroll
            for (int d = 1; d < 16; d <<= 1) {
                int t = __shfl_up(s, d, 64);
                if (lane >= d) s += t;
            }
            if (lane < 16) wsum[lane] = s;
        }
        __syncthreads();
        const int ex = sCarry + (wid > 0 ? wsum[wid - 1] : 0) + incl - tot;
        if (idx + 3 < N) {
            *(int4*)(cursor + idx) = make_int4(ex, ex + v.x, ex + t01, ex + t012);
        } else if (idx < N) {
            cursor[idx] = ex;
            if (idx + 1 < N) cursor[idx + 1] = ex + v.x;
            if (idx + 2 < N) cursor[idx + 2] = ex + t01;
        }
        __syncthreads();
        if (tid == 0) sCarry += wsum[15];
        __syncthreads();
    }
}

// ---------------------------------------------------------------------------
// Merged: scatter packed payloads | MFMA precompute A/B -> bf16
//   pre: 64 nodes/block, 4 waves, each wave 16 rows x 256 cols, K=128.
// ---------------------------------------------------------------------------
__global__ __launch_bounds__(256) void k_scatter_pre(
    const int* __restrict__ ei, const float* __restrict__ ew, const float* __restrict__ x,
    int* __restrict__ cursor, uint2* __restrict__ spk, int* __restrict__ dstS,
    int E, int pack,
    const float* __restrict__ h, const float* __restrict__ bm1,
    const ushort_t* __restrict__ W1mf,
    ushort_t* __restrict__ Abf, ushort_t* __restrict__ Bbf, int N, int nb_scat)
{
    const int tid = threadIdx.x;

    if ((int)blockIdx.x < nb_scat) {
        const int e = blockIdx.x * 256 + tid;
        if (e < E) {
            const int is64 = detect64(ei);
            const int s = load_src(ei, is64, e, E);
            const int d = load_dst(ei, is64, e, E);
            const int pos = atomicAdd(&cursor[d], 1);
            unsigned x0 = (unsigned)s;
            if (pack) {
                const float2 xs = *(const float2*)(x + 2 * s);
                const float2 xd = *(const float2*)(x + 2 * d);
                const float dxv = xs.x - xd.x, dyv = xs.y - xd.y;
                const float r = sqrtf(dxv * dxv + dyv * dyv + 1e-8f);
                int ti = (int)(r * 724.0773439350246f + 0.5f);
                ti = min(ti, NTAB - 1);
                x0 |= ((unsigned)ti << 16);
            }
            spk[pos] = make_uint2(x0, __float_as_uint(ew[e]));
            dstS[pos] = d;
        }
        return;
    }

    __shared__ __align__(16) ushort_t sIn[64 * DH];   // 16 KB swizzled bf16 h
    const int nblk = ((int)blockIdx.x - nb_scat) * 64;

    {   // stage h -> bf16 LDS (swizzled 16B chunks)
        const int row = tid >> 2, q = tid & 3;
        const int gn = nblk + row;
        const float4* ps = (const float4*)(h + (size_t)gn * DH + 32 * q);
        uint4* rowp = (uint4*)(sIn + row * DH);
        const int swz = row & 7;
#pragma unroll
        for (int i = 0; i < 4; ++i) {
            uint4 o = make_uint4(0, 0, 0, 0);
            if (gn < N) {
                const float4 g0 = ps[2 * i], g1 = ps[2 * i + 1];
                o.x = pk_bf16(g0.x, g0.y); o.y = pk_bf16(g0.z, g0.w);
                o.z = pk_bf16(g1.x, g1.y); o.w = pk_bf16(g1.z, g1.w);
            }
            rowp[(4 * q + i) ^ swz] = o;
        }
    }
    __syncthreads();

    const int lane = tid & 63, wv = tid >> 6;
    const int lr = lane & 15, lg = lane >> 4;
    const int m0l = wv * 16;

    union FragU { unsigned u[4]; short8 s8; };
    floatx4 acc[16];
#pragma unroll
    for (int ni = 0; ni < 16; ++ni) acc[ni] = (floatx4){0.f, 0.f, 0.f, 0.f};

#pragma unroll
    for (int kc = 0; kc < 4; ++kc) {
        const int b1 = 64 * kc + 8 * lg;
        const int b2 = b1 + 32;
        const int row = m0l + lr;
        const char* rbase = (const char*)(sIn + row * DH);
        const int swz = (row & 7) << 4;
        FragU af;
        const uint2 lo = *(const uint2*)(rbase + ((b1 & ~15) ^ swz) + (b1 & 15));
        const uint2 hi = *(const uint2*)(rbase + ((b2 & ~15) ^ swz) + (b2 & 15));
        af.u[0] = lo.x; af.u[1] = lo.y; af.u[2] = hi.x; af.u[3] = hi.y;
        const ushort_t* wbase = W1mf + ((size_t)(kc * 4 + lg) * 256 + lr) * 8;
        __builtin_amdgcn_s_setprio(1);
#pragma unroll
        for (int ni = 0; ni < 16; ++ni) {
            const short8 bf = *(const short8*)(wbase + ni * 128);
            acc[ni] = __builtin_amdgcn_mfma_f32_16x16x32_bf16(af.s8, bf, acc[ni], 0, 0, 0);
        }
        __builtin_amdgcn_s_setprio(0);
    }

    float bm1v[8];
#pragma unroll
    for (int ni = 0; ni < 8; ++ni) bm1v[ni] = bm1[ni * 16 + lr];
#pragma unroll
    for (int r = 0; r < 4; ++r) {
        const int gn = nblk + m0l + 4 * lg + r;
        if (gn < N) {
#pragma unroll
            for (int ni = 0; ni < 8; ++ni)
                Abf[(size_t)gn * DH + ni * 16 + lr] = f2bf1(acc[ni][r] + bm1v[ni]);
#pragma unroll
            for (int ni = 8; ni < 16; ++ni)
                Bbf[(size_t)gn * DH + (ni - 8) * 16 + lr] = f2bf1(acc[ni][r]);
        }
    }
}

// ---------------------------------------------------------------------------
// Edge kernel (R7 structure, packed payloads).
// ---------------------------------------------------------------------------
__global__ __launch_bounds__(256, 4) void k_edge(
    const float* __restrict__ x, const int* __restrict__ ei, const float* __restrict__ ew,
    const uint2* __restrict__ spk, const int* __restrict__ dstS,
    const ushort_t* __restrict__ W2f, const float* __restrict__ bm2,
    const ushort_t* __restrict__ Abf, const ushort_t* __restrict__ Bbf,
    const ushort_t* __restrict__ Tbf, float* __restrict__ agg,
    int sorted, int pack, int N, int E)
{
    __shared__ __align__(16) ushort_t sHid[64 * DH];      // 16 KB
    __shared__ __align__(16) float ldsAgg[SEGCAP][DH];    // 16 KB
    __shared__ int   sSrc[EB];
    __shared__ int   sDst[EB];
    __shared__ int   sLid[EB];
    __shared__ int   sTi[EB];
    __shared__ float sEw[EB];
    __shared__ int   sSegStart[SEGCAP];
    __shared__ int   sNseg, sW0tot;

    const int tid = threadIdx.x;

    const int nwg = gridDim.x;
    const int xcd = blockIdx.x & 7;
    const int cidx = blockIdx.x >> 3;
    const int qch = nwg >> 3, rch = nwg & 7;
    const int bid = (xcd < rch) ? (xcd * (qch + 1) + cidx)
                                : (rch * (qch + 1) + (xcd - rch) * qch + cidx);
    const int e0 = bid * EB;

    {
        const float4 z = make_float4(0.f, 0.f, 0.f, 0.f);
        float4* za = (float4*)&ldsAgg[0][0];
#pragma unroll
        for (int i = 0; i < 4; ++i) za[tid + 256 * i] = z;
    }

    if (tid < EB) {
        const int slot = e0 + tid;
        int s = 0, d = 0, ti = 0;
        float w = 0.f;
        if (slot < E) {
            if (sorted) {
                const uint2 v = spk[slot];
                d = dstS[slot];
                w = __uint_as_float(v.y);
                if (pack) { s = (int)(v.x & 0xFFFFu); ti = (int)(v.x >> 16); }
                else {
                    s = (int)v.x;
                    const float2 xs = *(const float2*)(x + 2 * s);
                    const float2 xd = *(const float2*)(x + 2 * d);
                    const float dxv = xs.x - xd.x, dyv = xs.y - xd.y;
                    const float r = sqrtf(dxv * dxv + dyv * dyv + 1e-8f);
                    ti = min((int)(r * 724.0773439350246f + 0.5f), NTAB - 1);
                }
            } else {
                const int is64 = detect64(ei);
                s = load_src(ei, is64, slot, E);
                d = load_dst(ei, is64, slot, E);
                w = ew[slot];
                const float2 xs = *(const float2*)(x + 2 * s);
                const float2 xd = *(const float2*)(x + 2 * d);
                const float dxv = xs.x - xd.x, dyv = xs.y - xd.y;
                const float r = sqrtf(dxv * dxv + dyv * dyv + 1e-8f);
                ti = min((int)(r * 724.0773439350246f + 0.5f), NTAB - 1);
            }
        } else {
            d = sorted ? dstS[E - 1] : load_dst(ei, detect64(ei), E - 1, E);
        }
        sSrc[tid] = s; sDst[tid] = d; sEw[tid] = w; sTi[tid] = ti;
    }
    __syncthreads();

    // lid segment scan
    int bflag = 0, incl = 0;
    if (tid < EB) {
        bflag = (tid > 0) && (sDst[tid] != sDst[tid - 1]);
        incl = bflag;
#pragma unroll
        for (int dd = 1; dd < 64; dd <<= 1) {
            int t = __shfl_up(incl, dd, 64);
            if ((tid & 63) >= dd) incl += t;
        }
    }
    if (tid == 63) sW0tot = incl;
    __syncthreads();
    if (tid >= 64 && tid < EB) incl += sW0tot;
    if (tid < EB) {
        sLid[tid] = incl;
        if ((bflag || tid == 0) && incl < SEGCAP) sSegStart[incl] = tid;
        if (tid == EB - 1) sNseg = incl + 1;
    }
    __syncthreads();

    const int lane = tid & 63;
    const int wv   = tid >> 6;
    const int lr   = lane & 15;
    const int lg   = lane >> 4;
    const int m0l  = (wv & 1) * 32;
    const int n0   = (wv >> 1) * 64;

    float bc4[4];
#pragma unroll
    for (int ni = 0; ni < 4; ++ni) bc4[ni] = bm2[n0 + ni * 16 + lr];

    union FragU { unsigned u[4]; short8 s8; };

    for (int half = 0; half < 2; ++half) {
        const int eh = half * 64;

        {   // phase 1
            const int el = tid >> 2;
            const int q  = tid & 3;
            const int le = eh + el;
            const int s  = sSrc[le];
            const int ti = sTi[le];
            const uint4* pA = (const uint4*)(Abf + (size_t)s * DH + 32 * q);
            const uint4* pB = (const uint4*)(Bbf + (size_t)sDst[le] * DH + 32 * q);
            const uint4* pT = (const uint4*)(Tbf + (size_t)ti * DH + 32 * q);
            uint4* rowp = (uint4*)(sHid + el * DH);
            const int swz = el & 7;
#pragma unroll
            for (int i = 0; i < 4; ++i) {
                const uint4 a = pA[i];
                const uint4 b = pB[i];
                const uint4 t = pT[i];
                const float v0 = bflo(a.x) + bflo(b.x) + bflo(t.x);
                const float v1 = bfhi(a.x) + bfhi(b.x) + bfhi(t.x);
                const float v2 = bflo(a.y) + bflo(b.y) + bflo(t.y);
                const float v3 = bfhi(a.y) + bfhi(b.y) + bfhi(t.y);
                const float v4 = bflo(a.z) + bflo(b.z) + bflo(t.z);
                const float v5 = bfhi(a.z) + bfhi(b.z) + bfhi(t.z);
                const float v6 = bflo(a.w) + bflo(b.w) + bflo(t.w);
                const float v7 = bfhi(a.w) + bfhi(b.w) + bfhi(t.w);
                uint4 pk;
                pk.x = pk_bf16(silu_f(v0), silu_f(v1));
                pk.y = pk_bf16(silu_f(v2), silu_f(v3));
                pk.z = pk_bf16(silu_f(v4), silu_f(v5));
                pk.w = pk_bf16(silu_f(v6), silu_f(v7));
                rowp[(4 * q + i) ^ swz] = pk;
            }
        }
        __syncthreads();

        // phase 2
        floatx4 acc[2][4];
#pragma unroll
        for (int mi = 0; mi < 2; ++mi)
#pragma unroll
            for (int ni = 0; ni < 4; ++ni) acc[mi][ni] = (floatx4){0.f, 0.f, 0.f, 0.f};

#pragma unroll
        for (int kc = 0; kc < 4; ++kc) {
            const int b1 = 64 * kc + 8 * lg;
            const int b2 = b1 + 32;
            FragU af[2];
#pragma unroll
            for (int mi = 0; mi < 2; ++mi) {
                const int le2 = m0l + mi * 16 + lr;
                const char* rbase = (const char*)(sHid + le2 * DH);
                const int swz = (le2 & 7) << 4;
                const uint2 lo = *(const uint2*)(rbase + ((b1 & ~15) ^ swz) + (b1 & 15));
                const uint2 hi = *(const uint2*)(rbase + ((b2 & ~15) ^ swz) + (b2 & 15));
                af[mi].u[0] = lo.x; af[mi].u[1] = lo.y;
                af[mi].u[2] = hi.x; af[mi].u[3] = hi.y;
            }
            const ushort_t* wbase = W2f + ((size_t)(kc * 4 + lg) * 128 + n0 + lr) * 8;
            __builtin_amdgcn_s_setprio(1);
#pragma unroll
            for (int ni = 0; ni < 4; ++ni) {
                const short8 bf = *(const short8*)(wbase + ni * 128);
                acc[0][ni] = __builtin_amdgcn_mfma_f32_16x16x32_bf16(af[0].s8, bf, acc[0][ni], 0, 0, 0);
                acc[1][ni] = __builtin_amdgcn_mfma_f32_16x16x32_bf16(af[1].s8, bf, acc[1][ni], 0, 0, 0);
            }
            __builtin_amdgcn_s_setprio(0);
        }

        // phase 3
        int   lid4[2][4];
        float ew4[2][4];
        int   hs[2];
#pragma unroll
        for (int mi = 0; mi < 2; ++mi) {
            const int sb = eh + m0l + mi * 16 + 4 * lg;
            hs[mi] = sb;
#pragma unroll
            for (int r = 0; r < 4; ++r) { lid4[mi][r] = sLid[sb + r]; ew4[mi][r] = sEw[sb + r]; }
        }
#pragma unroll
        for (int ni = 0; ni < 4; ++ni) {
            const int col = n0 + ni * 16 + lr;
            const float bc = bc4[ni];
#pragma unroll
            for (int mi = 0; mi < 2; ++mi) {
                int cur = lid4[mi][0], curSlot = hs[mi];
                float av = (acc[mi][ni][0] + bc) * ew4[mi][0];
#pragma unroll
                for (int r = 1; r < 4; ++r) {
                    const int l2 = lid4[mi][r];
                    const float v = (acc[mi][ni][r] + bc) * ew4[mi][r];
                    if (l2 == cur) av += v;
                    else {
                        if (cur < SEGCAP) atomicAdd(&ldsAgg[cur][col], av);
                        else atomicAdd(agg + (size_t)sDst[curSlot] * DH + col, av);
                        cur = l2; curSlot = hs[mi] + r; av = v;
                    }
                }
                if (cur < SEGCAP) atomicAdd(&ldsAgg[cur][col], av);
                else atomicAdd(agg + (size_t)sDst[curSlot] * DH + col, av);
            }
        }
        __syncthreads();
    }

    // flush
    const int ns = sNseg;
    const int gmax = (ns < SEGCAP) ? ns : SEGCAP;
    for (int idx = tid; idx < (gmax << 7); idx += 256) {
        const int g = idx >> 7, col = idx & 127;
        const float v = ldsAgg[g][col];
        const int dst = sDst[sSegStart[g]];
        float* p = agg + (size_t)dst * DH + col;
        if (sorted && g > 0 && g < ns - 1) *p = v;
        else atomicAdd(p, v);
    }
}

// ---------------------------------------------------------------------------
// Node MLP via MFMA + residual + LayerNorm.
// 64 nodes/block, 4 waves; wave = 16 rows x 128 cols. GEMM1 K=256, GEMM2 K=128.
// ---------------------------------------------------------------------------
__global__ __launch_bounds__(256) void k_node(
    const float* __restrict__ h, const float* __restrict__ agg,
    const ushort_t* __restrict__ W1hf, const float* __restrict__ bh1,
    const ushort_t* __restrict__ W2hf, const float* __restrict__ bh2,
    const float* __restrict__ ln_g, const float* __restrict__ ln_b,
    float* __restrict__ out, int N)
{
    __shared__ __align__(16) ushort_t sIn[64 * 256];   // 32 KB: [h | agg] bf16
    __shared__ __align__(16) ushort_t sHid[64 * DH];   // 16 KB
    const int tid = threadIdx.x;
    const int nblk = blockIdx.x * 64;

    {   // stage [h|agg] -> bf16 sIn (swizzled)
        const int row = tid >> 2, q = tid & 3;
        const int gn = nblk + row;
        const float4* ps = (q < 2) ? (const float4*)(h + (size_t)gn * DH + 64 * q)
                                   : (const float4*)(agg + (size_t)gn * DH + 64 * (q - 2));
        uint4* rowp = (uint4*)(sIn + row * 256);
        const int swz = row & 7;
#pragma unroll
        for (int i = 0; i < 8; ++i) {
            uint4 o = make_uint4(0, 0, 0, 0);
            if (gn < N) {
                const float4 g0 = ps[2 * i], g1 = ps[2 * i + 1];
                o.x = pk_bf16(g0.x, g0.y); o.y = pk_bf16(g0.z, g0.w);
                o.z = pk_bf16(g1.x, g1.y); o.w = pk_bf16(g1.z, g1.w);
            }
            rowp[(8 * q + i) ^ swz] = o;
        }
    }
    __syncthreads();

    const int lane = tid & 63, wv = tid >> 6;
    const int lr = lane & 15, lg = lane >> 4;
    const int m0l = wv * 16;

    union FragU { unsigned u[4]; short8 s8; };

    // GEMM1: hid = silu(u_in @ Wh1 + bh1), K=256
    floatx4 acc[8];
#pragma unroll
    for (int ni = 0; ni < 8; ++ni) acc[ni] = (floatx4){0.f, 0.f, 0.f, 0.f};

#pragma unroll
    for (int kc = 0; kc < 8; ++kc) {
        const int b1 = 64 * kc + 8 * lg;
        const int b2 = b1 + 32;
        const int row = m0l + lr;
        const char* rbase = (const char*)(sIn + row * 256);
        const int swz = (row & 7) << 4;
        FragU af;
        const uint2 lo = *(const uint2*)(rbase + ((b1 & ~15) ^ swz) + (b1 & 15));
        const uint2 hi = *(const uint2*)(rbase + ((b2 & ~15) ^ swz) + (b2 & 15));
        af.u[0] = lo.x; af.u[1] = lo.y; af.u[2] = hi.x; af.u[3] = hi.y;
        const ushort_t* wbase = W1hf + ((size_t)(kc * 4 + lg) * 128 + lr) * 8;
        __builtin_amdgcn_s_setprio(1);
#pragma unroll
        for (int ni = 0; ni < 8; ++ni) {
            const short8 bf = *(const short8*)(wbase + ni * 128);
            acc[ni] = __builtin_amdgcn_mfma_f32_16x16x32_bf16(af.s8, bf, acc[ni], 0, 0, 0);
        }
        __builtin_amdgcn_s_setprio(0);
    }

    {   // silu + bias -> sHid (bf16, swizzled). In-wave rows only.
        float bh1v[8];
#pragma unroll
        for (int ni = 0; ni < 8; ++ni) bh1v[ni] = bh1[ni * 16 + lr];
#pragma unroll
        for (int r = 0; r < 4; ++r) {
            const int row = m0l + 4 * lg + r;
            const int swz = row & 7;
            ushort_t* rp = sHid + row * DH;
#pragma unroll
            for (int ni = 0; ni < 8; ++ni) {
                const int col = ni * 16 + lr;
                rp[(((col >> 3) ^ swz) << 3) + (col & 7)] =
                    f2bf1(silu_f(acc[ni][r] + bh1v[ni]));
            }
        }
    }
    // no barrier: wave reads only rows it wrote (R4-proven in-wave LDS ordering)

    // GEMM2: h_up = hid @ Wh2 + bh2, K=128
    floatx4 acc2[8];
#pragma unroll
    for (int ni = 0; ni < 8; ++ni) acc2[ni] = (floatx4){0.f, 0.f, 0.f, 0.f};

#pragma unroll
    for (int kc = 0; kc < 4; ++kc) {
        const int b1 = 64 * kc + 8 * lg;
        const int b2 = b1 + 32;
        const int row = m0l + lr;
        const char* rbase = (const char*)(sHid + row * DH);
        const int swz = (row & 7) << 4;
        FragU af;
        const uint2 lo = *(const uint2*)(rbase + ((b1 & ~15) ^ swz) + (b1 & 15));
        const uint2 hi = *(const uint2*)(rbase + ((b2 & ~15) ^ swz) + (b2 & 15));
        af.u[0] = lo.x; af.u[1] = lo.y; af.u[2] = hi.x; af.u[3] = hi.y;
        const ushort_t* wbase = W2hf + ((size_t)(kc * 4 + lg) * 128 + lr) * 8;
        __builtin_amdgcn_s_setprio(1);
#pragma unroll
        for (int ni = 0; ni < 8; ++ni) {
            const short8 bf = *(const short8*)(wbase + ni * 128);
            acc2[ni] = __builtin_amdgcn_mfma_f32_16x16x32_bf16(af.s8, bf, acc2[ni], 0, 0, 0);
        }
        __builtin_amdgcn_s_setprio(0);
    }

    // epilogue: residual (bf16 h from sIn) + LayerNorm per row (16-lane reduce)
    float gv[8], bv[8], b2v[8];
#pragma unroll
    for (int ni = 0; ni < 8; ++ni) {
        const int col = ni * 16 + lr;
        gv[ni] = ln_g[col]; bv[ni] = ln_b[col]; b2v[ni] = bh2[col];
    }
#pragma unroll
    for (int r = 0; r < 4; ++r) {
        const int row = m0l + 4 * lg + r;
        const int gn = nblk + row;
        const int swz = row & 7;
        float z[8];
        float s1 = 0.f, s2 = 0.f;
#pragma unroll
        for (int ni = 0; ni < 8; ++ni) {
            const int col = ni * 16 + lr;
            const float hv = bf2f(sIn[row * 256 + (((col >> 3) ^ swz) << 3) + (col & 7)]);
            z[ni] = acc2[ni][r] + b2v[ni] + hv;
            s1 += z[ni]; s2 += z[ni] * z[ni];
        }
#pragma unroll
        for (int m = 1; m < 16; m <<= 1) {
            s1 += __shfl_xor(s1, m, 64);
            s2 += __shfl_xor(s2, m, 64);
        }
        const float mean = s1 * (1.f / 128.f);
        const float var = s2 * (1.f / 128.f) - mean * mean;
        const float rstd = rsqrtf(var + 1e-5f);
        if (gn < N) {
#pragma unroll
            for (int ni = 0; ni < 8; ++ni) {
                const int col = ni * 16 + lr;
                out[(size_t)gn * DH + col] = (z[ni] - mean) * rstd * gv[ni] + bv[ni];
            }
        }
    }
}

extern "C" void kernel_launch(void* const* d_in, const int* in_sizes, int n_in,
                              void* d_out, int out_size, void* d_ws, size_t ws_size,
                              hipStream_t stream)
{
    (void)n_in; (void)out_size;
    const float* h   = (const float*)d_in[0];
    const float* x   = (const float*)d_in[1];
    const int*   ei  = (const int*)d_in[2];
    const float* ew  = (const float*)d_in[3];
    const float* Wm1 = (const float*)d_in[4];
    const float* bm1 = (const float*)d_in[5];
    const float* Wm2 = (const float*)d_in[6];
    const float* bm2 = (const float*)d_in[7];
    const float* Wh1 = (const float*)d_in[8];
    const float* bh1 = (const float*)d_in[9];
    const float* Wh2 = (const float*)d_in[10];
    const float* bh2 = (const float*)d_in[11];
    const float* lng = (const float*)d_in[12];
    const float* lnb = (const float*)d_in[13];
    float* out = (float*)d_out;

    const int N = in_sizes[0] / DH;
    const int E = in_sizes[3];

    // ws: agg | Abf | Bbf | W2f | Tbf | W1mf | W1hf | W2hf | [counts cursor spk dstS]
    float*    agg  = (float*)d_ws;
    ushort_t* Abf  = (ushort_t*)(agg + (size_t)N * DH);
    ushort_t* Bbf  = Abf + (size_t)N * DH;
    ushort_t* W2f  = Bbf + (size_t)N * DH;
    ushort_t* Tbf  = W2f + 16384;
    ushort_t* W1mf = Tbf + (size_t)NTAB * DH;
    ushort_t* W1hf = W1mf + 32768;
    ushort_t* W2hf = W1hf + 32768;
    int*   counts  = (int*)(W2hf + 16384);
    int*   cursor  = counts + N;
    uint2* spk     = (uint2*)(cursor + N);
    int*   dstS    = (int*)(spk + E);

    const size_t mand = (size_t)N * DH * 4 + (size_t)N * DH * 4
                      + ((size_t)16384 + (size_t)NTAB * DH + 32768 + 32768 + 16384) * 2;
    const size_t need = mand + (size_t)(2 * N) * 4 + (size_t)E * 12 + 64;
    const int use_sort = (ws_size >= need) ? 1 : 0;
    const int pack = use_sort && (N <= 65535);

    const int nb_hist = use_sort ? (E + 255) / 256 : 0;
    const int nb_prep = 257 + 8 + 16 + 16 + 8;
    const int nb_scat = nb_hist;
    const int nb_pre  = (N + 63) / 64;

    hipMemsetAsync(agg, 0, (size_t)N * DH * sizeof(float), stream);
    if (use_sort)
        hipMemsetAsync(counts, 0, (size_t)N * sizeof(int), stream);
    k_hist_prep<<<nb_hist + nb_prep, 256, 0, stream>>>(ei, counts, E, Wm1, Wm2, Wh1, Wh2,
                                                       Tbf, W2f, W1mf, W1hf, W2hf, nb_hist);
    if (use_sort)
        k_scan<<<1, 1024, 0, stream>>>(counts, cursor, N);
    k_scatter_pre<<<nb_scat + nb_pre, 256, 0, stream>>>(ei, ew, x, cursor, spk, dstS, E, pack,
                                                        h, bm1, W1mf, Abf, Bbf, N, nb_scat);
    k_edge<<<(E + EB - 1) / EB, 256, 0, stream>>>(x, ei, ew, spk, dstS,
                                                  W2f, bm2, Abf, Bbf, Tbf, agg,
                                                  use_sort, pack, N, E);
    k_node<<<(N + 63) / 64, 256, 0, stream>>>(h, agg, W1hf, bh1, W2hf, bh2, lng, lnb, out, N);
}

// Round 9
// 415.511 us; speedup vs baseline: 7.9440x; 1.0511x over previous
//
#include <hip/hip_runtime.h>
#include <hip/hip_bf16.h>
#include <math.h>

#define DH 128
#define NRBF 16
#define EB 128     // edges per k_edge block (4 waves x 32 edges)
#define NTAB 1025
#define SEGCAP 32  // max LDS-resident dst segments per block

typedef unsigned short ushort_t;
typedef __attribute__((ext_vector_type(8))) short short8;
typedef __attribute__((ext_vector_type(4))) float floatx4;

__device__ __forceinline__ float silu_f(float v) {
    return v / (1.f + __expf(-v));
}
__device__ __forceinline__ unsigned pk_bf16(float lo, float hi) {
    __hip_bfloat162 h = __float22bfloat162_rn(make_float2(lo, hi));
    union { __hip_bfloat162 h2; unsigned u; } cv;
    cv.h2 = h;
    return cv.u;
}
__device__ __forceinline__ ushort_t f2bf1(float f) {
    unsigned u = __float_as_uint(f);
    u += 0x7FFFu + ((u >> 16) & 1u);
    return (ushort_t)(u >> 16);
}
__device__ __forceinline__ float bflo(unsigned u) { return __uint_as_float(u << 16); }
__device__ __forceinline__ float bfhi(unsigned u) { return __uint_as_float(u & 0xffff0000u); }
__device__ __forceinline__ float bf2f(ushort_t u) { return __uint_as_float(((unsigned)u) << 16); }

__device__ __forceinline__ int detect64(const int* __restrict__ ei) {
    int z = 0;
#pragma unroll
    for (int i = 0; i < 8; ++i) z |= ei[2 * i + 1];
    return (z == 0) ? 1 : 0;
}
__device__ __forceinline__ int load_dst(const int* ei, int is64, int e, int E) {
    return is64 ? ei[2 * E + 2 * e] : ei[E + e];
}
__device__ __forceinline__ int load_src(const int* ei, int is64, int e, int E) {
    return is64 ? ei[2 * e] : ei[e];
}

// ---------------------------------------------------------------------------
// Merged prep: histogram | Tbf rows (4/block) | W2f | W1mf | W1hf | W2hf
// ---------------------------------------------------------------------------
__global__ __launch_bounds__(256) void k_hist_prep(
    const int* __restrict__ ei, int* __restrict__ counts, int E,
    const float* __restrict__ Wm1, const float* __restrict__ Wm2,
    const float* __restrict__ Wh1, const float* __restrict__ Wh2,
    ushort_t* __restrict__ Tbf, ushort_t* __restrict__ W2f,
    ushort_t* __restrict__ W1mf, ushort_t* __restrict__ W1hf,
    ushort_t* __restrict__ W2hf, int nb_hist)
{
    const int b = blockIdx.x, tid = threadIdx.x;
    if (b < nb_hist) {
        const int e = b * 256 + tid;
        if (e < E) {
            const int is64 = detect64(ei);
            atomicAdd(&counts[load_dst(ei, is64, e, E)], 1);
        }
        return;
    }
    int b2 = b - nb_hist;
    if (b2 < 257) {
        const int i = b2 * 4 + (tid >> 6);
        if (i < NTAB) {
            const float WIDTH = 0.09428090415820634f;
            const float GAMMA = 56.25f;
            const float DELTA = 1.4142135623730951f / 1024.0f;
            const float r = (float)i * DELTA;
            const int c0 = (tid & 63) * 2;
            float a0 = 0.f, a1 = 0.f;
#pragma unroll
            for (int q = 0; q < NRBF; ++q) {
                const float dr = r - (float)q * WIDTH;
                const float w = __expf(-GAMMA * dr * dr);
                a0 = fmaf(w, Wm1[(256 + q) * DH + c0], a0);
                a1 = fmaf(w, Wm1[(256 + q) * DH + c0 + 1], a1);
            }
            *(unsigned*)(Tbf + (size_t)i * DH + c0) = pk_bf16(a0, a1);
        }
        return;
    }
    b2 -= 257;
    if (b2 < 8) {
        const int u = b2 * 256 + tid;
        const int col = u & 127, kclg = u >> 7;
        const int lg = kclg & 3, kc = kclg >> 2;
        unsigned o[4];
#pragma unroll
        for (int j = 0; j < 2; ++j) {
            o[j]     = pk_bf16(Wm2[(kc * 32 + 4 * lg + 2 * j) * DH + col],
                               Wm2[(kc * 32 + 4 * lg + 2 * j + 1) * DH + col]);
            o[2 + j] = pk_bf16(Wm2[(kc * 32 + 16 + 4 * lg + 2 * j) * DH + col],
                               Wm2[(kc * 32 + 16 + 4 * lg + 2 * j + 1) * DH + col]);
        }
        *(uint4*)(W2f + 8 * u) = make_uint4(o[0], o[1], o[2], o[3]);
        return;
    }
    b2 -= 8;
    if (b2 < 16) {
        const int u = b2 * 256 + tid;
        const int c = u & 255, kclg = u >> 8;
        const int lg = kclg & 3, kc = kclg >> 2;
        const int base = (c < 128) ? 0 : 128;
        const int cc = c & 127;
        unsigned o[4];
#pragma unroll
        for (int j = 0; j < 2; ++j) {
            o[j]     = pk_bf16(Wm1[(base + kc * 32 + 4 * lg + 2 * j) * DH + cc],
                               Wm1[(base + kc * 32 + 4 * lg + 2 * j + 1) * DH + cc]);
            o[2 + j] = pk_bf16(Wm1[(base + kc * 32 + 16 + 4 * lg + 2 * j) * DH + cc],
                               Wm1[(base + kc * 32 + 16 + 4 * lg + 2 * j + 1) * DH + cc]);
        }
        *(uint4*)(W1mf + 8 * u) = make_uint4(o[0], o[1], o[2], o[3]);
        return;
    }
    b2 -= 16;
    if (b2 < 16) {
        const int u = b2 * 256 + tid;
        const int col = u & 127, kclg = u >> 7;
        const int lg = kclg & 3, kc = kclg >> 2;
        unsigned o[4];
#pragma unroll
        for (int j = 0; j < 2; ++j) {
            o[j]     = pk_bf16(Wh1[(kc * 32 + 4 * lg + 2 * j) * DH + col],
                               Wh1[(kc * 32 + 4 * lg + 2 * j + 1) * DH + col]);
            o[2 + j] = pk_bf16(Wh1[(kc * 32 + 16 + 4 * lg + 2 * j) * DH + col],
                               Wh1[(kc * 32 + 16 + 4 * lg + 2 * j + 1) * DH + col]);
        }
        *(uint4*)(W1hf + 8 * u) = make_uint4(o[0], o[1], o[2], o[3]);
        return;
    }
    b2 -= 16;
    {
        const int u = b2 * 256 + tid;
        const int col = u & 127, kclg = u >> 7;
        const int lg = kclg & 3, kc = kclg >> 2;
        unsigned o[4];
#pragma unroll
        for (int j = 0; j < 2; ++j) {
            o[j]     = pk_bf16(Wh2[(kc * 32 + 4 * lg + 2 * j) * DH + col],
                               Wh2[(kc * 32 + 4 * lg + 2 * j + 1) * DH + col]);
            o[2 + j] = pk_bf16(Wh2[(kc * 32 + 16 + 4 * lg + 2 * j) * DH + col],
                               Wh2[(kc * 32 + 16 + 4 * lg + 2 * j + 1) * DH + col]);
        }
        *(uint4*)(W2hf + 8 * u) = make_uint4(o[0], o[1], o[2], o[3]);
    }
}

// ---------------------------------------------------------------------------
// Exclusive prefix sum of counts -> cursor.
// ---------------------------------------------------------------------------
__global__ __launch_bounds__(1024) void k_scan(const int* __restrict__ counts,
                                               int* __restrict__ cursor, int N) {
    __shared__ int wsum[16];
    __shared__ int sCarry;
    const int tid = threadIdx.x, lane = tid & 63, wid = tid >> 6;
    if (tid == 0) sCarry = 0;
    __syncthreads();
    for (int c0 = 0; c0 < N; c0 += 4096) {
        const int idx = c0 + tid * 4;
        int4 v = make_int4(0, 0, 0, 0);
        if (idx < N) v = *(const int4*)(counts + idx);
        const int t01 = v.x + v.y;
        const int t012 = t01 + v.z;
        const int tot = t012 + v.w;
        int incl = tot;
#pragma unroll
        for (int d = 1; d < 64; d <<= 1) {
            int t = __shfl_up(incl, d, 64);
            if (lane >= d) incl += t;
        }
        if (lane == 63) wsum[wid] = incl;
        __syncthreads();
        if (wid == 0) {
            int s = (lane < 16) ? wsum[lane] : 0;
#pragma unroll
            for (int d = 1; d < 16; d <<= 1) {
                int t = __shfl_up(s, d, 64);
                if (lane >= d) s += t;
            }
            if (lane < 16) wsum[lane] = s;
        }
        __syncthreads();
        const int ex = sCarry + (wid > 0 ? wsum[wid - 1] : 0) + incl - tot;
        if (idx + 3 < N) {
            *(int4*)(cursor + idx) = make_int4(ex, ex + v.x, ex + t01, ex + t012);
        } else if (idx < N) {
            cursor[idx] = ex;
            if (idx + 1 < N) cursor[idx + 1] = ex + v.x;
            if (idx + 2 < N) cursor[idx + 2] = ex + t01;
        }
        __syncthreads();
        if (tid == 0) sCarry += wsum[15];
        __syncthreads();
    }
}

// ---------------------------------------------------------------------------
// Merged: scatter packed payloads | MFMA precompute A/B -> bf16
// ---------------------------------------------------------------------------
__global__ __launch_bounds__(256) void k_scatter_pre(
    const int* __restrict__ ei, const float* __restrict__ ew, const float* __restrict__ x,
    int* __restrict__ cursor, uint2* __restrict__ spk, int* __restrict__ dstS,
    int E, int pack,
    const float* __restrict__ h, const float* __restrict__ bm1,
    const ushort_t* __restrict__ W1mf,
    ushort_t* __restrict__ Abf, ushort_t* __restrict__ Bbf, int N, int nb_scat)
{
    const int tid = threadIdx.x;

    if ((int)blockIdx.x < nb_scat) {
        const int e = blockIdx.x * 256 + tid;
        if (e < E) {
            const int is64 = detect64(ei);
            const int s = load_src(ei, is64, e, E);
            const int d = load_dst(ei, is64, e, E);
            const int pos = atomicAdd(&cursor[d], 1);
            unsigned x0 = (unsigned)s;
            if (pack) {
                const float2 xs = *(const float2*)(x + 2 * s);
                const float2 xd = *(const float2*)(x + 2 * d);
                const float dxv = xs.x - xd.x, dyv = xs.y - xd.y;
                const float r = sqrtf(dxv * dxv + dyv * dyv + 1e-8f);
                int ti = (int)(r * 724.0773439350246f + 0.5f);
                ti = min(ti, NTAB - 1);
                x0 |= ((unsigned)ti << 16);
            }
            spk[pos] = make_uint2(x0, __float_as_uint(ew[e]));
            dstS[pos] = d;
        }
        return;
    }

    __shared__ __align__(16) ushort_t sIn[64 * DH];
    const int nblk = ((int)blockIdx.x - nb_scat) * 64;

    {
        const int row = tid >> 2, q = tid & 3;
        const int gn = nblk + row;
        const float4* ps = (const float4*)(h + (size_t)gn * DH + 32 * q);
        uint4* rowp = (uint4*)(sIn + row * DH);
        const int swz = row & 7;
#pragma unroll
        for (int i = 0; i < 4; ++i) {
            uint4 o = make_uint4(0, 0, 0, 0);
            if (gn < N) {
                const float4 g0 = ps[2 * i], g1 = ps[2 * i + 1];
                o.x = pk_bf16(g0.x, g0.y); o.y = pk_bf16(g0.z, g0.w);
                o.z = pk_bf16(g1.x, g1.y); o.w = pk_bf16(g1.z, g1.w);
            }
            rowp[(4 * q + i) ^ swz] = o;
        }
    }
    __syncthreads();

    const int lane = tid & 63, wv = tid >> 6;
    const int lr = lane & 15, lg = lane >> 4;
    const int m0l = wv * 16;

    union FragU { unsigned u[4]; short8 s8; };
    floatx4 acc[16];
#pragma unroll
    for (int ni = 0; ni < 16; ++ni) acc[ni] = (floatx4){0.f, 0.f, 0.f, 0.f};

#pragma unroll
    for (int kc = 0; kc < 4; ++kc) {
        const int b1 = 64 * kc + 8 * lg;
        const int b2 = b1 + 32;
        const int row = m0l + lr;
        const char* rbase = (const char*)(sIn + row * DH);
        const int swz = (row & 7) << 4;
        FragU af;
        const uint2 lo = *(const uint2*)(rbase + ((b1 & ~15) ^ swz) + (b1 & 15));
        const uint2 hi = *(const uint2*)(rbase + ((b2 & ~15) ^ swz) + (b2 & 15));
        af.u[0] = lo.x; af.u[1] = lo.y; af.u[2] = hi.x; af.u[3] = hi.y;
        const ushort_t* wbase = W1mf + ((size_t)(kc * 4 + lg) * 256 + lr) * 8;
        __builtin_amdgcn_s_setprio(1);
#pragma unroll
        for (int ni = 0; ni < 16; ++ni) {
            const short8 bf = *(const short8*)(wbase + ni * 128);
            acc[ni] = __builtin_amdgcn_mfma_f32_16x16x32_bf16(af.s8, bf, acc[ni], 0, 0, 0);
        }
        __builtin_amdgcn_s_setprio(0);
    }

    float bm1v[8];
#pragma unroll
    for (int ni = 0; ni < 8; ++ni) bm1v[ni] = bm1[ni * 16 + lr];
#pragma unroll
    for (int r = 0; r < 4; ++r) {
        const int gn = nblk + m0l + 4 * lg + r;
        if (gn < N) {
#pragma unroll
            for (int ni = 0; ni < 8; ++ni)
                Abf[(size_t)gn * DH + ni * 16 + lr] = f2bf1(acc[ni][r] + bm1v[ni]);
#pragma unroll
            for (int ni = 8; ni < 16; ++ni)
                Bbf[(size_t)gn * DH + (ni - 8) * 16 + lr] = f2bf1(acc[ni][r]);
        }
    }
}

// ---------------------------------------------------------------------------
// Edge kernel, wave-independent restructure:
//  - direct payload reads + early gather prefetch (overlap staging/scan)
//  - 3 barriers up front (staging/scan), then each wave runs its 32 edges
//    (two 16-edge subtiles) with ZERO barriers: build sHid slice in-wave,
//    MFMA, run-merged ds_atomics into shared ldsAgg.
//  - one barrier before flush.
// ---------------------------------------------------------------------------
__global__ __launch_bounds__(256, 4) void k_edge(
    const float* __restrict__ x, const int* __restrict__ ei, const float* __restrict__ ew,
    const uint2* __restrict__ spk, const int* __restrict__ dstS,
    const ushort_t* __restrict__ W2f, const float* __restrict__ bm2,
    const ushort_t* __restrict__ Abf, const ushort_t* __restrict__ Bbf,
    const ushort_t* __restrict__ Tbf, float* __restrict__ agg,
    int sorted, int pack, int N, int E)
{
    __shared__ __align__(16) ushort_t sHid[4][16 * DH];   // 16 KB, per-wave slice
    __shared__ __align__(16) float ldsAgg[SEGCAP][DH];    // 16 KB
    __shared__ int   sSrc[EB];
    __shared__ int   sDst[EB];
    __shared__ int   sLid[EB];
    __shared__ int   sTi[EB];
    __shared__ float sEw[EB];
    __shared__ int   sSegStart[SEGCAP];
    __shared__ int   sNseg, sW0tot;

    const int tid  = threadIdx.x;
    const int lane = tid & 63;
    const int wv   = tid >> 6;
    const int lr   = lane & 15;
    const int lg   = lane >> 4;
    const int e4   = lane >> 2;    // edge within 16-edge subtile
    const int q    = lane & 3;     // col quarter
    const int wbase = wv * 32;

    // XCD-chunked bijective swizzle
    const int nwg = gridDim.x;
    const int xcd = blockIdx.x & 7;
    const int cidx = blockIdx.x >> 3;
    const int qch = nwg >> 3, rch = nwg & 7;
    const int bid = (xcd < rch) ? (xcd * (qch + 1) + cidx)
                                : (rch * (qch + 1) + (xcd - rch) * qch + cidx);
    const int e0 = bid * EB;

    const int fast = sorted && pack;

    // ---- early prefetch: st0 A/B/T + st1 A (random gathers in flight
    //      across the staging barriers; drained once at the barrier) ----
    uint4 a0[4], b0[4], t0v[4], a1[4], b1[4], t1v[4];
    int d1g = 0, t1g = 0;
    if (fast) {
        const int sl0 = min(e0 + wbase + e4, E - 1);
        const int sl1 = min(e0 + wbase + 16 + e4, E - 1);
        const uint2 v0 = spk[sl0], v1 = spk[sl1];
        const int s0g = (int)(v0.x & 0xFFFFu), t0g = (int)(v0.x >> 16);
        const int s1g = (int)(v1.x & 0xFFFFu);
        t1g = (int)(v1.x >> 16);
        const int d0g = dstS[sl0];
        d1g = dstS[sl1];
        const uint4* pA0 = (const uint4*)(Abf + (size_t)s0g * DH + 32 * q);
        const uint4* pB0 = (const uint4*)(Bbf + (size_t)d0g * DH + 32 * q);
        const uint4* pT0 = (const uint4*)(Tbf + (size_t)t0g * DH + 32 * q);
        const uint4* pA1 = (const uint4*)(Abf + (size_t)s1g * DH + 32 * q);
#pragma unroll
        for (int i = 0; i < 4; ++i) {
            a0[i] = pA0[i]; b0[i] = pB0[i]; t0v[i] = pT0[i]; a1[i] = pA1[i];
        }
    }

    // zero ldsAgg
    {
        const float4 z = make_float4(0.f, 0.f, 0.f, 0.f);
        float4* za = (float4*)&ldsAgg[0][0];
#pragma unroll
        for (int i = 0; i < 4; ++i) za[tid + 256 * i] = z;
    }

    // staging
    if (tid < EB) {
        const int slot = e0 + tid;
        int s = 0, d = 0, ti = 0;
        float w = 0.f;
        if (slot < E) {
            if (sorted) {
                const uint2 v = spk[slot];
                d = dstS[slot];
                w = __uint_as_float(v.y);
                if (pack) { s = (int)(v.x & 0xFFFFu); ti = (int)(v.x >> 16); }
                else {
                    s = (int)v.x;
                    const float2 xs = *(const float2*)(x + 2 * s);
                    const float2 xd = *(const float2*)(x + 2 * d);
                    const float dxv = xs.x - xd.x, dyv = xs.y - xd.y;
                    const float r = sqrtf(dxv * dxv + dyv * dyv + 1e-8f);
                    ti = min((int)(r * 724.0773439350246f + 0.5f), NTAB - 1);
                }
            } else {
                const int is64 = detect64(ei);
                s = load_src(ei, is64, slot, E);
                d = load_dst(ei, is64, slot, E);
                w = ew[slot];
                const float2 xs = *(const float2*)(x + 2 * s);
                const float2 xd = *(const float2*)(x + 2 * d);
                const float dxv = xs.x - xd.x, dyv = xs.y - xd.y;
                const float r = sqrtf(dxv * dxv + dyv * dyv + 1e-8f);
                ti = min((int)(r * 724.0773439350246f + 0.5f), NTAB - 1);
            }
        } else {
            d = sorted ? dstS[E - 1] : load_dst(ei, detect64(ei), E - 1, E);
        }
        sSrc[tid] = s; sDst[tid] = d; sEw[tid] = w; sTi[tid] = ti;
    }
    __syncthreads();

    // lid segment scan
    int bflag = 0, incl = 0;
    if (tid < EB) {
        bflag = (tid > 0) && (sDst[tid] != sDst[tid - 1]);
        incl = bflag;
#pragma unroll
        for (int dd = 1; dd < 64; dd <<= 1) {
            int t = __shfl_up(incl, dd, 64);
            if ((tid & 63) >= dd) incl += t;
        }
    }
    if (tid == 63) sW0tot = incl;
    __syncthreads();
    if (tid >= 64 && tid < EB) incl += sW0tot;
    if (tid < EB) {
        sLid[tid] = incl;
        if ((bflag || tid == 0) && incl < SEGCAP) sSegStart[incl] = tid;
        if (tid == EB - 1) sNseg = incl + 1;
    }
    __syncthreads();

    // ---- barrier-free wave section ----
    if (!fast) {  // fallback: load subtile 0 + st1 A now
        const int le0 = wbase + e4;
        const int s0g = sSrc[le0], d0g = sDst[le0], t0g = sTi[le0];
        const uint4* pA0 = (const uint4*)(Abf + (size_t)s0g * DH + 32 * q);
        const uint4* pB0 = (const uint4*)(Bbf + (size_t)d0g * DH + 32 * q);
        const uint4* pT0 = (const uint4*)(Tbf + (size_t)t0g * DH + 32 * q);
#pragma unroll
        for (int i = 0; i < 4; ++i) { a0[i] = pA0[i]; b0[i] = pB0[i]; t0v[i] = pT0[i]; }
        const int le1 = wbase + 16 + e4;
        const int s1g = sSrc[le1];
        d1g = sDst[le1]; t1g = sTi[le1];
        const uint4* pA1 = (const uint4*)(Abf + (size_t)s1g * DH + 32 * q);
#pragma unroll
        for (int i = 0; i < 4; ++i) a1[i] = pA1[i];
    }

    float bc8[8];
#pragma unroll
    for (int ni = 0; ni < 8; ++ni) bc8[ni] = bm2[ni * 16 + lr];

    union FragU { unsigned u[4]; short8 s8; };
    ushort_t* slice = &sHid[wv][0];
    floatx4 acc[8];

#define BUILD_HID(aA, bB, tT)                                                   \
    {                                                                           \
        uint4* rowp = (uint4*)(slice + e4 * DH);                                \
        const int swzw = e4 & 7;                                                \
        _Pragma("unroll")                                                       \
        for (int i = 0; i < 4; ++i) {                                           \
            const uint4 a = aA[i]; const uint4 b = bB[i]; const uint4 t = tT[i];\
            const float v0 = bflo(a.x) + bflo(b.x) + bflo(t.x);                 \
            const float v1 = bfhi(a.x) + bfhi(b.x) + bfhi(t.x);                 \
            const float v2 = bflo(a.y) + bflo(b.y) + bflo(t.y);                 \
            const float v3 = bfhi(a.y) + bfhi(b.y) + bfhi(t.y);                 \
            const float v4 = bflo(a.z) + bflo(b.z) + bflo(t.z);                 \
            const float v5 = bfhi(a.z) + bfhi(b.z) + bfhi(t.z);                 \
            const float v6 = bflo(a.w) + bflo(b.w) + bflo(t.w);                 \
            const float v7 = bfhi(a.w) + bfhi(b.w) + bfhi(t.w);                 \
            uint4 pk;                                                           \
            pk.x = pk_bf16(silu_f(v0), silu_f(v1));                             \
            pk.y = pk_bf16(silu_f(v2), silu_f(v3));                             \
            pk.z = pk_bf16(silu_f(v4), silu_f(v5));                             \
            pk.w = pk_bf16(silu_f(v6), silu_f(v7));                             \
            rowp[(4 * q + i) ^ swzw] = pk;                                      \
        }                                                                       \
    }

#define MFMA_ST()                                                               \
    {                                                                           \
        _Pragma("unroll")                                                       \
        for (int ni = 0; ni < 8; ++ni) acc[ni] = (floatx4){0.f, 0.f, 0.f, 0.f}; \
        _Pragma("unroll")                                                       \
        for (int kc = 0; kc < 4; ++kc) {                                        \
            const int bo1 = 64 * kc + 8 * lg;                                   \
            const int bo2 = bo1 + 32;                                           \
            const char* rbase = (const char*)(slice + lr * DH);                 \
            const int swzf = (lr & 7) << 4;                                     \
            FragU af;                                                           \
            const uint2 lo = *(const uint2*)(rbase + ((bo1 & ~15) ^ swzf) + (bo1 & 15)); \
            const uint2 hi = *(const uint2*)(rbase + ((bo2 & ~15) ^ swzf) + (bo2 & 15)); \
            af.u[0] = lo.x; af.u[1] = lo.y; af.u[2] = hi.x; af.u[3] = hi.y;     \
            const ushort_t* wb2 = W2f + ((size_t)(kc * 4 + lg) * 128 + lr) * 8; \
            __builtin_amdgcn_s_setprio(1);                                      \
            _Pragma("unroll")                                                   \
            for (int ni = 0; ni < 8; ++ni) {                                    \
                const short8 bf = *(const short8*)(wb2 + ni * 128);             \
                acc[ni] = __builtin_amdgcn_mfma_f32_16x16x32_bf16(af.s8, bf, acc[ni], 0, 0, 0); \
            }                                                                   \
            __builtin_amdgcn_s_setprio(0);                                      \
        }                                                                       \
    }

#define PHASE3(ST)                                                              \
    {                                                                           \
        const int sb = wbase + (ST) * 16 + 4 * lg;                              \
        int lid4[4]; float ew4[4];                                              \
        _Pragma("unroll")                                                       \
        for (int r = 0; r < 4; ++r) { lid4[r] = sLid[sb + r]; ew4[r] = sEw[sb + r]; } \
        _Pragma("unroll")                                                       \
        for (int ni = 0; ni < 8; ++ni) {                                        \
            const int col = ni * 16 + lr;                                       \
            const float bc = bc8[ni];                                           \
            int cur = lid4[0], curSlot = sb;                                    \
            float av = (acc[ni][0] + bc) * ew4[0];                              \
            _Pragma("unroll")                                                   \
            for (int r = 1; r < 4; ++r) {                                       \
                const int l2 = lid4[r];                                         \
                const float v = (acc[ni][r] + bc) * ew4[r];                     \
                if (l2 == cur) av += v;                                         \
                else {                                                          \
                    if (cur < SEGCAP) atomicAdd(&ldsAgg[cur][col], av);         \
                    else atomicAdd(agg + (size_t)sDst[curSlot] * DH + col, av); \
                    cur = l2; curSlot = sb + r; av = v;                         \
                }                                                               \
            }                                                                   \
            if (cur < SEGCAP) atomicAdd(&ldsAgg[cur][col], av);                 \
            else atomicAdd(agg + (size_t)sDst[curSlot] * DH + col, av);         \
        }                                                                       \
    }

    // ---- subtile 0 ----
    BUILD_HID(a0, b0, t0v);
    MFMA_ST();
    {   // issue st1 B/T (L2-hot) under st0's scatter
        const uint4* pB1 = (const uint4*)(Bbf + (size_t)d1g * DH + 32 * q);
        const uint4* pT1 = (const uint4*)(Tbf + (size_t)t1g * DH + 32 * q);
#pragma unroll
        for (int i = 0; i < 4; ++i) { b1[i] = pB1[i]; t1v[i] = pT1[i]; }
    }
    PHASE3(0);

    // ---- subtile 1 ----
    BUILD_HID(a1, b1, t1v);
    MFMA_ST();
    PHASE3(1);

    __syncthreads();

    // flush
    const int ns = sNseg;
    const int gmax = (ns < SEGCAP) ? ns : SEGCAP;
    for (int idx = tid; idx < (gmax << 7); idx += 256) {
        const int g = idx >> 7, col = idx & 127;
        const float v = ldsAgg[g][col];
        const int dst = sDst[sSegStart[g]];
        float* p = agg + (size_t)dst * DH + col;
        if (sorted && g > 0 && g < ns - 1) *p = v;
        else atomicAdd(p, v);
    }
#undef BUILD_HID
#undef MFMA_ST
#undef PHASE3
}

// ---------------------------------------------------------------------------
// Node MLP via MFMA + residual + LayerNorm.
// ---------------------------------------------------------------------------
__global__ __launch_bounds__(256) void k_node(
    const float* __restrict__ h, const float* __restrict__ agg,
    const ushort_t* __restrict__ W1hf, const float* __restrict__ bh1,
    const ushort_t* __restrict__ W2hf, const float* __restrict__ bh2,
    const float* __restrict__ ln_g, const float* __restrict__ ln_b,
    float* __restrict__ out, int N)
{
    __shared__ __align__(16) ushort_t sIn[64 * 256];
    __shared__ __align__(16) ushort_t sHid[64 * DH];
    const int tid = threadIdx.x;
    const int nblk = blockIdx.x * 64;

    {
        const int row = tid >> 2, q = tid & 3;
        const int gn = nblk + row;
        const float4* ps = (q < 2) ? (const float4*)(h + (size_t)gn * DH + 64 * q)
                                   : (const float4*)(agg + (size_t)gn * DH + 64 * (q - 2));
        uint4* rowp = (uint4*)(sIn + row * 256);
        const int swz = row & 7;
#pragma unroll
        for (int i = 0; i < 8; ++i) {
            uint4 o = make_uint4(0, 0, 0, 0);
            if (gn < N) {
                const float4 g0 = ps[2 * i], g1 = ps[2 * i + 1];
                o.x = pk_bf16(g0.x, g0.y); o.y = pk_bf16(g0.z, g0.w);
                o.z = pk_bf16(g1.x, g1.y); o.w = pk_bf16(g1.z, g1.w);
            }
            rowp[(8 * q + i) ^ swz] = o;
        }
    }
    __syncthreads();

    const int lane = tid & 63, wv = tid >> 6;
    const int lr = lane & 15, lg = lane >> 4;
    const int m0l = wv * 16;

    union FragU { unsigned u[4]; short8 s8; };

    floatx4 acc[8];
#pragma unroll
    for (int ni = 0; ni < 8; ++ni) acc[ni] = (floatx4){0.f, 0.f, 0.f, 0.f};

#pragma unroll
    for (int kc = 0; kc < 8; ++kc) {
        const int b1 = 64 * kc + 8 * lg;
        const int b2 = b1 + 32;
        const int row = m0l + lr;
        const char* rbase = (const char*)(sIn + row * 256);
        const int swz = (row & 7) << 4;
        FragU af;
        const uint2 lo = *(const uint2*)(rbase + ((b1 & ~15) ^ swz) + (b1 & 15));
        const uint2 hi = *(const uint2*)(rbase + ((b2 & ~15) ^ swz) + (b2 & 15));
        af.u[0] = lo.x; af.u[1] = lo.y; af.u[2] = hi.x; af.u[3] = hi.y;
        const ushort_t* wbase = W1hf + ((size_t)(kc * 4 + lg) * 128 + lr) * 8;
        __builtin_amdgcn_s_setprio(1);
#pragma unroll
        for (int ni = 0; ni < 8; ++ni) {
            const short8 bf = *(const short8*)(wbase + ni * 128);
            acc[ni] = __builtin_amdgcn_mfma_f32_16x16x32_bf16(af.s8, bf, acc[ni], 0, 0, 0);
        }
        __builtin_amdgcn_s_setprio(0);
    }

    {
        float bh1v[8];
#pragma unroll
        for (int ni = 0; ni < 8; ++ni) bh1v[ni] = bh1[ni * 16 + lr];
#pragma unroll
        for (int r = 0; r < 4; ++r) {
            const int row = m0l + 4 * lg + r;
            const int swz = row & 7;
            ushort_t* rp = sHid + row * DH;
#pragma unroll
            for (int ni = 0; ni < 8; ++ni) {
                const int col = ni * 16 + lr;
                rp[(((col >> 3) ^ swz) << 3) + (col & 7)] =
                    f2bf1(silu_f(acc[ni][r] + bh1v[ni]));
            }
        }
    }

    floatx4 acc2[8];
#pragma unroll
    for (int ni = 0; ni < 8; ++ni) acc2[ni] = (floatx4){0.f, 0.f, 0.f, 0.f};

#pragma unroll
    for (int kc = 0; kc < 4; ++kc) {
        const int b1 = 64 * kc + 8 * lg;
        const int b2 = b1 + 32;
        const int row = m0l + lr;
        const char* rbase = (const char*)(sHid + row * DH);
        const int swz = (row & 7) << 4;
        FragU af;
        const uint2 lo = *(const uint2*)(rbase + ((b1 & ~15) ^ swz) + (b1 & 15));
        const uint2 hi = *(const uint2*)(rbase + ((b2 & ~15) ^ swz) + (b2 & 15));
        af.u[0] = lo.x; af.u[1] = lo.y; af.u[2] = hi.x; af.u[3] = hi.y;
        const ushort_t* wbase = W2hf + ((size_t)(kc * 4 + lg) * 128 + lr) * 8;
        __builtin_amdgcn_s_setprio(1);
#pragma unroll
        for (int ni = 0; ni < 8; ++ni) {
            const short8 bf = *(const short8*)(wbase + ni * 128);
            acc2[ni] = __builtin_amdgcn_mfma_f32_16x16x32_bf16(af.s8, bf, acc2[ni], 0, 0, 0);
        }
        __builtin_amdgcn_s_setprio(0);
    }

    float gv[8], bv[8], b2v[8];
#pragma unroll
    for (int ni = 0; ni < 8; ++ni) {
        const int col = ni * 16 + lr;
        gv[ni] = ln_g[col]; bv[ni] = ln_b[col]; b2v[ni] = bh2[col];
    }
#pragma unroll
    for (int r = 0; r < 4; ++r) {
        const int row = m0l + 4 * lg + r;
        const int gn = nblk + row;
        const int swz = row & 7;
        float z[8];
        float s1 = 0.f, s2 = 0.f;
#pragma unroll
        for (int ni = 0; ni < 8; ++ni) {
            const int col = ni * 16 + lr;
            const float hv = bf2f(sIn[row * 256 + (((col >> 3) ^ swz) << 3) + (col & 7)]);
            z[ni] = acc2[ni][r] + b2v[ni] + hv;
            s1 += z[ni]; s2 += z[ni] * z[ni];
        }
#pragma unroll
        for (int m = 1; m < 16; m <<= 1) {
            s1 += __shfl_xor(s1, m, 64);
            s2 += __shfl_xor(s2, m, 64);
        }
        const float mean = s1 * (1.f / 128.f);
        const float var = s2 * (1.f / 128.f) - mean * mean;
        const float rstd = rsqrtf(var + 1e-5f);
        if (gn < N) {
#pragma unroll
            for (int ni = 0; ni < 8; ++ni) {
                const int col = ni * 16 + lr;
                out[(size_t)gn * DH + col] = (z[ni] - mean) * rstd * gv[ni] + bv[ni];
            }
        }
    }
}

extern "C" void kernel_launch(void* const* d_in, const int* in_sizes, int n_in,
                              void* d_out, int out_size, void* d_ws, size_t ws_size,
                              hipStream_t stream)
{
    (void)n_in; (void)out_size;
    const float* h   = (const float*)d_in[0];
    const float* x   = (const float*)d_in[1];
    const int*   ei  = (const int*)d_in[2];
    const float* ew  = (const float*)d_in[3];
    const float* Wm1 = (const float*)d_in[4];
    const float* bm1 = (const float*)d_in[5];
    const float* Wm2 = (const float*)d_in[6];
    const float* bm2 = (const float*)d_in[7];
    const float* Wh1 = (const float*)d_in[8];
    const float* bh1 = (const float*)d_in[9];
    const float* Wh2 = (const float*)d_in[10];
    const float* bh2 = (const float*)d_in[11];
    const float* lng = (const float*)d_in[12];
    const float* lnb = (const float*)d_in[13];
    float* out = (float*)d_out;

    const int N = in_sizes[0] / DH;
    const int E = in_sizes[3];

    float*    agg  = (float*)d_ws;
    ushort_t* Abf  = (ushort_t*)(agg + (size_t)N * DH);
    ushort_t* Bbf  = Abf + (size_t)N * DH;
    ushort_t* W2f  = Bbf + (size_t)N * DH;
    ushort_t* Tbf  = W2f + 16384;
    ushort_t* W1mf = Tbf + (size_t)NTAB * DH;
    ushort_t* W1hf = W1mf + 32768;
    ushort_t* W2hf = W1hf + 32768;
    int*   counts  = (int*)(W2hf + 16384);
    int*   cursor  = counts + N;
    uint2* spk     = (uint2*)(cursor + N);
    int*   dstS    = (int*)(spk + E);

    const size_t mand = (size_t)N * DH * 4 + (size_t)N * DH * 4
                      + ((size_t)16384 + (size_t)NTAB * DH + 32768 + 32768 + 16384) * 2;
    const size_t need = mand + (size_t)(2 * N) * 4 + (size_t)E * 12 + 64;
    const int use_sort = (ws_size >= need) ? 1 : 0;
    const int pack = use_sort && (N <= 65535);

    const int nb_hist = use_sort ? (E + 255) / 256 : 0;
    const int nb_prep = 257 + 8 + 16 + 16 + 8;
    const int nb_scat = nb_hist;
    const int nb_pre  = (N + 63) / 64;

    hipMemsetAsync(agg, 0, (size_t)N * DH * sizeof(float), stream);
    if (use_sort)
        hipMemsetAsync(counts, 0, (size_t)N * sizeof(int), stream);
    k_hist_prep<<<nb_hist + nb_prep, 256, 0, stream>>>(ei, counts, E, Wm1, Wm2, Wh1, Wh2,
                                                       Tbf, W2f, W1mf, W1hf, W2hf, nb_hist);
    if (use_sort)
        k_scan<<<1, 1024, 0, stream>>>(counts, cursor, N);
    k_scatter_pre<<<nb_scat + nb_pre, 256, 0, stream>>>(ei, ew, x, cursor, spk, dstS, E, pack,
                                                        h, bm1, W1mf, Abf, Bbf, N, nb_scat);
    k_edge<<<(E + EB - 1) / EB, 256, 0, stream>>>(x, ei, ew, spk, dstS,
                                                  W2f, bm2, Abf, Bbf, Tbf, agg,
                                                  use_sort, pack, N, E);
    k_node<<<(N + 63) / 64, 256, 0, stream>>>(h, agg, W1hf, bh1, W2hf, bh2, lng, lnb, out, N);
}

// Round 10
// 404.942 us; speedup vs baseline: 8.1513x; 1.0261x over previous
//
#include <hip/hip_runtime.h>
#include <hip/hip_bf16.h>
#include <math.h>

#define DH 128
#define NRBF 16
#define EB 128     // edges per k_edge block (4 waves x 32 edges)
#define NTAB 1025
#define SEGCAP 32  // max LDS-resident dst segments per block

typedef unsigned short ushort_t;
typedef __attribute__((ext_vector_type(8))) short short8;
typedef __attribute__((ext_vector_type(4))) float floatx4;

__device__ __forceinline__ float silu_f(float v) {
    return v / (1.f + __expf(-v));
}
__device__ __forceinline__ unsigned pk_bf16(float lo, float hi) {
    __hip_bfloat162 h = __float22bfloat162_rn(make_float2(lo, hi));
    union { __hip_bfloat162 h2; unsigned u; } cv;
    cv.h2 = h;
    return cv.u;
}
__device__ __forceinline__ ushort_t f2bf1(float f) {
    unsigned u = __float_as_uint(f);
    u += 0x7FFFu + ((u >> 16) & 1u);
    return (ushort_t)(u >> 16);
}
__device__ __forceinline__ float bflo(unsigned u) { return __uint_as_float(u << 16); }
__device__ __forceinline__ float bfhi(unsigned u) { return __uint_as_float(u & 0xffff0000u); }
__device__ __forceinline__ float bf2f(ushort_t u) { return __uint_as_float(((unsigned)u) << 16); }

__device__ __forceinline__ int detect64(const int* __restrict__ ei) {
    int z = 0;
#pragma unroll
    for (int i = 0; i < 8; ++i) z |= ei[2 * i + 1];
    return (z == 0) ? 1 : 0;
}
__device__ __forceinline__ int load_dst(const int* ei, int is64, int e, int E) {
    return is64 ? ei[2 * E + 2 * e] : ei[E + e];
}
__device__ __forceinline__ int load_src(const int* ei, int is64, int e, int E) {
    return is64 ? ei[2 * e] : ei[e];
}

// ---------------------------------------------------------------------------
// Merged prep: histogram | Tbf rows (4/block) | W2f | W1mf | W1hf | W2hf
// ---------------------------------------------------------------------------
__global__ __launch_bounds__(256) void k_hist_prep(
    const int* __restrict__ ei, int* __restrict__ counts, int E,
    const float* __restrict__ Wm1, const float* __restrict__ Wm2,
    const float* __restrict__ Wh1, const float* __restrict__ Wh2,
    ushort_t* __restrict__ Tbf, ushort_t* __restrict__ W2f,
    ushort_t* __restrict__ W1mf, ushort_t* __restrict__ W1hf,
    ushort_t* __restrict__ W2hf, int nb_hist)
{
    const int b = blockIdx.x, tid = threadIdx.x;
    if (b < nb_hist) {
        const int e = b * 256 + tid;
        if (e < E) {
            const int is64 = detect64(ei);
            atomicAdd(&counts[load_dst(ei, is64, e, E)], 1);
        }
        return;
    }
    int b2 = b - nb_hist;
    if (b2 < 257) {
        const int i = b2 * 4 + (tid >> 6);
        if (i < NTAB) {
            const float WIDTH = 0.09428090415820634f;
            const float GAMMA = 56.25f;
            const float DELTA = 1.4142135623730951f / 1024.0f;
            const float r = (float)i * DELTA;
            const int c0 = (tid & 63) * 2;
            float a0 = 0.f, a1 = 0.f;
#pragma unroll
            for (int q = 0; q < NRBF; ++q) {
                const float dr = r - (float)q * WIDTH;
                const float w = __expf(-GAMMA * dr * dr);
                a0 = fmaf(w, Wm1[(256 + q) * DH + c0], a0);
                a1 = fmaf(w, Wm1[(256 + q) * DH + c0 + 1], a1);
            }
            *(unsigned*)(Tbf + (size_t)i * DH + c0) = pk_bf16(a0, a1);
        }
        return;
    }
    b2 -= 257;
    if (b2 < 8) {
        const int u = b2 * 256 + tid;
        const int col = u & 127, kclg = u >> 7;
        const int lg = kclg & 3, kc = kclg >> 2;
        unsigned o[4];
#pragma unroll
        for (int j = 0; j < 2; ++j) {
            o[j]     = pk_bf16(Wm2[(kc * 32 + 4 * lg + 2 * j) * DH + col],
                               Wm2[(kc * 32 + 4 * lg + 2 * j + 1) * DH + col]);
            o[2 + j] = pk_bf16(Wm2[(kc * 32 + 16 + 4 * lg + 2 * j) * DH + col],
                               Wm2[(kc * 32 + 16 + 4 * lg + 2 * j + 1) * DH + col]);
        }
        *(uint4*)(W2f + 8 * u) = make_uint4(o[0], o[1], o[2], o[3]);
        return;
    }
    b2 -= 8;
    if (b2 < 16) {
        const int u = b2 * 256 + tid;
        const int c = u & 255, kclg = u >> 8;
        const int lg = kclg & 3, kc = kclg >> 2;
        const int base = (c < 128) ? 0 : 128;
        const int cc = c & 127;
        unsigned o[4];
#pragma unroll
        for (int j = 0; j < 2; ++j) {
            o[j]     = pk_bf16(Wm1[(base + kc * 32 + 4 * lg + 2 * j) * DH + cc],
                               Wm1[(base + kc * 32 + 4 * lg + 2 * j + 1) * DH + cc]);
            o[2 + j] = pk_bf16(Wm1[(base + kc * 32 + 16 + 4 * lg + 2 * j) * DH + cc],
                               Wm1[(base + kc * 32 + 16 + 4 * lg + 2 * j + 1) * DH + cc]);
        }
        *(uint4*)(W1mf + 8 * u) = make_uint4(o[0], o[1], o[2], o[3]);
        return;
    }
    b2 -= 16;
    if (b2 < 16) {
        const int u = b2 * 256 + tid;
        const int col = u & 127, kclg = u >> 7;
        const int lg = kclg & 3, kc = kclg >> 2;
        unsigned o[4];
#pragma unroll
        for (int j = 0; j < 2; ++j) {
            o[j]     = pk_bf16(Wh1[(kc * 32 + 4 * lg + 2 * j) * DH + col],
                               Wh1[(kc * 32 + 4 * lg + 2 * j + 1) * DH + col]);
            o[2 + j] = pk_bf16(Wh1[(kc * 32 + 16 + 4 * lg + 2 * j) * DH + col],
                               Wh1[(kc * 32 + 16 + 4 * lg + 2 * j + 1) * DH + col]);
        }
        *(uint4*)(W1hf + 8 * u) = make_uint4(o[0], o[1], o[2], o[3]);
        return;
    }
    b2 -= 16;
    {
        const int u = b2 * 256 + tid;
        const int col = u & 127, kclg = u >> 7;
        const int lg = kclg & 3, kc = kclg >> 2;
        unsigned o[4];
#pragma unroll
        for (int j = 0; j < 2; ++j) {
            o[j]     = pk_bf16(Wh2[(kc * 32 + 4 * lg + 2 * j) * DH + col],
                               Wh2[(kc * 32 + 4 * lg + 2 * j + 1) * DH + col]);
            o[2 + j] = pk_bf16(Wh2[(kc * 32 + 16 + 4 * lg + 2 * j) * DH + col],
                               Wh2[(kc * 32 + 16 + 4 * lg + 2 * j + 1) * DH + col]);
        }
        *(uint4*)(W2hf + 8 * u) = make_uint4(o[0], o[1], o[2], o[3]);
    }
}

// ---------------------------------------------------------------------------
// Exclusive prefix sum of counts -> cursor.
// ---------------------------------------------------------------------------
__global__ __launch_bounds__(1024) void k_scan(const int* __restrict__ counts,
                                               int* __restrict__ cursor, int N) {
    __shared__ int wsum[16];
    __shared__ int sCarry;
    const int tid = threadIdx.x, lane = tid & 63, wid = tid >> 6;
    if (tid == 0) sCarry = 0;
    __syncthreads();
    for (int c0 = 0; c0 < N; c0 += 4096) {
        const int idx = c0 + tid * 4;
        int4 v = make_int4(0, 0, 0, 0);
        if (idx < N) v = *(const int4*)(counts + idx);
        const int t01 = v.x + v.y;
        const int t012 = t01 + v.z;
        const int tot = t012 + v.w;
        int incl = tot;
#pragma unroll
        for (int d = 1; d < 64; d <<= 1) {
            int t = __shfl_up(incl, d, 64);
            if (lane >= d) incl += t;
        }
        if (lane == 63) wsum[wid] = incl;
        __syncthreads();
        if (wid == 0) {
            int s = (lane < 16) ? wsum[lane] : 0;
#pragma unroll
            for (int d = 1; d < 16; d <<= 1) {
                int t = __shfl_up(s, d, 64);
                if (lane >= d) s += t;
            }
            if (lane < 16) wsum[lane] = s;
        }
        __syncthreads();
        const int ex = sCarry + (wid > 0 ? wsum[wid - 1] : 0) + incl - tot;
        if (idx + 3 < N) {
            *(int4*)(cursor + idx) = make_int4(ex, ex + v.x, ex + t01, ex + t012);
        } else if (idx < N) {
            cursor[idx] = ex;
            if (idx + 1 < N) cursor[idx + 1] = ex + v.x;
            if (idx + 2 < N) cursor[idx + 2] = ex + t01;
        }
        __syncthreads();
        if (tid == 0) sCarry += wsum[15];
        __syncthreads();
    }
}

// ---------------------------------------------------------------------------
// Merged: scatter packed payloads | MFMA precompute A/B -> bf16
// ---------------------------------------------------------------------------
__global__ __launch_bounds__(256) void k_scatter_pre(
    const int* __restrict__ ei, const float* __restrict__ ew, const float* __restrict__ x,
    int* __restrict__ cursor, uint2* __restrict__ spk, int* __restrict__ dstS,
    int E, int pack,
    const float* __restrict__ h, const float* __restrict__ bm1,
    const ushort_t* __restrict__ W1mf,
    ushort_t* __restrict__ Abf, ushort_t* __restrict__ Bbf, int N, int nb_scat)
{
    const int tid = threadIdx.x;

    if ((int)blockIdx.x < nb_scat) {
        const int e = blockIdx.x * 256 + tid;
        if (e < E) {
            const int is64 = detect64(ei);
            const int s = load_src(ei, is64, e, E);
            const int d = load_dst(ei, is64, e, E);
            const int pos = atomicAdd(&cursor[d], 1);
            unsigned x0 = (unsigned)s;
            if (pack) {
                const float2 xs = *(const float2*)(x + 2 * s);
                const float2 xd = *(const float2*)(x + 2 * d);
                const float dxv = xs.x - xd.x, dyv = xs.y - xd.y;
                const float r = sqrtf(dxv * dxv + dyv * dyv + 1e-8f);
                int ti = (int)(r * 724.0773439350246f + 0.5f);
                ti = min(ti, NTAB - 1);
                x0 |= ((unsigned)ti << 16);
            }
            spk[pos] = make_uint2(x0, __float_as_uint(ew[e]));
            dstS[pos] = d;
        }
        return;
    }

    __shared__ __align__(16) ushort_t sIn[64 * DH];
    const int nblk = ((int)blockIdx.x - nb_scat) * 64;

    {
        const int row = tid >> 2, q = tid & 3;
        const int gn = nblk + row;
        const float4* ps = (const float4*)(h + (size_t)gn * DH + 32 * q);
        uint4* rowp = (uint4*)(sIn + row * DH);
        const int swz = row & 7;
#pragma unroll
        for (int i = 0; i < 4; ++i) {
            uint4 o = make_uint4(0, 0, 0, 0);
            if (gn < N) {
                const float4 g0 = ps[2 * i], g1 = ps[2 * i + 1];
                o.x = pk_bf16(g0.x, g0.y); o.y = pk_bf16(g0.z, g0.w);
                o.z = pk_bf16(g1.x, g1.y); o.w = pk_bf16(g1.z, g1.w);
            }
            rowp[(4 * q + i) ^ swz] = o;
        }
    }
    __syncthreads();

    const int lane = tid & 63, wv = tid >> 6;
    const int lr = lane & 15, lg = lane >> 4;
    const int m0l = wv * 16;

    union FragU { unsigned u[4]; short8 s8; };
    floatx4 acc[16];
#pragma unroll
    for (int ni = 0; ni < 16; ++ni) acc[ni] = (floatx4){0.f, 0.f, 0.f, 0.f};

#pragma unroll
    for (int kc = 0; kc < 4; ++kc) {
        const int b1 = 64 * kc + 8 * lg;
        const int b2 = b1 + 32;
        const int row = m0l + lr;
        const char* rbase = (const char*)(sIn + row * DH);
        const int swz = (row & 7) << 4;
        FragU af;
        const uint2 lo = *(const uint2*)(rbase + ((b1 & ~15) ^ swz) + (b1 & 15));
        const uint2 hi = *(const uint2*)(rbase + ((b2 & ~15) ^ swz) + (b2 & 15));
        af.u[0] = lo.x; af.u[1] = lo.y; af.u[2] = hi.x; af.u[3] = hi.y;
        const ushort_t* wbase = W1mf + ((size_t)(kc * 4 + lg) * 256 + lr) * 8;
        __builtin_amdgcn_s_setprio(1);
#pragma unroll
        for (int ni = 0; ni < 16; ++ni) {
            const short8 bf = *(const short8*)(wbase + ni * 128);
            acc[ni] = __builtin_amdgcn_mfma_f32_16x16x32_bf16(af.s8, bf, acc[ni], 0, 0, 0);
        }
        __builtin_amdgcn_s_setprio(0);
    }

    float bm1v[8];
#pragma unroll
    for (int ni = 0; ni < 8; ++ni) bm1v[ni] = bm1[ni * 16 + lr];
#pragma unroll
    for (int r = 0; r < 4; ++r) {
        const int gn = nblk + m0l + 4 * lg + r;
        if (gn < N) {
#pragma unroll
            for (int ni = 0; ni < 8; ++ni)
                Abf[(size_t)gn * DH + ni * 16 + lr] = f2bf1(acc[ni][r] + bm1v[ni]);
#pragma unroll
            for (int ni = 8; ni < 16; ++ni)
                Bbf[(size_t)gn * DH + (ni - 8) * 16 + lr] = f2bf1(acc[ni][r]);
        }
    }
}

// ---------------------------------------------------------------------------
// Edge kernel. R9 wave-independent structure, but:
//  - W2f staged ONCE into LDS (sW2f); MFMA B-frags via ds_read_b128 instead
//    of ~4k global 16B requests per wave (request-rate wall fix)
//  - launch_bounds(256,2): register budget lets the early prefetch stay live
// ---------------------------------------------------------------------------
__global__ __launch_bounds__(256, 2) void k_edge(
    const float* __restrict__ x, const int* __restrict__ ei, const float* __restrict__ ew,
    const uint2* __restrict__ spk, const int* __restrict__ dstS,
    const ushort_t* __restrict__ W2f, const float* __restrict__ bm2,
    const ushort_t* __restrict__ Abf, const ushort_t* __restrict__ Bbf,
    const ushort_t* __restrict__ Tbf, float* __restrict__ agg,
    int sorted, int pack, int N, int E)
{
    __shared__ __align__(16) ushort_t sHid[4][16 * DH];   // 16 KB per-wave slices
    __shared__ __align__(16) ushort_t sW2f[16384];        // 32 KB Wm2 fragment-linear
    __shared__ __align__(16) float ldsAgg[SEGCAP][DH];    // 16 KB
    __shared__ int   sSrc[EB];
    __shared__ int   sDst[EB];
    __shared__ int   sLid[EB];
    __shared__ int   sTi[EB];
    __shared__ float sEw[EB];
    __shared__ int   sSegStart[SEGCAP];
    __shared__ int   sNseg, sW0tot;

    const int tid  = threadIdx.x;
    const int lane = tid & 63;
    const int wv   = tid >> 6;
    const int lr   = lane & 15;
    const int lg   = lane >> 4;
    const int e4   = lane >> 2;    // edge within 16-edge subtile
    const int q    = lane & 3;     // col quarter
    const int wbase = wv * 32;

    // XCD-chunked bijective swizzle
    const int nwg = gridDim.x;
    const int xcd = blockIdx.x & 7;
    const int cidx = blockIdx.x >> 3;
    const int qch = nwg >> 3, rch = nwg & 7;
    const int bid = (xcd < rch) ? (xcd * (qch + 1) + cidx)
                                : (rch * (qch + 1) + (xcd - rch) * qch + cidx);
    const int e0 = bid * EB;

    const int fast = sorted && pack;

    // ---- early prefetch: st0 A/B/T + st1 A (in flight across staging) ----
    uint4 a0[4], b0[4], t0v[4], a1[4], b1[4], t1v[4];
    int d1g = 0, t1g = 0;
    if (fast) {
        const int sl0 = min(e0 + wbase + e4, E - 1);
        const int sl1 = min(e0 + wbase + 16 + e4, E - 1);
        const uint2 v0 = spk[sl0], v1 = spk[sl1];
        const int s0g = (int)(v0.x & 0xFFFFu), t0g = (int)(v0.x >> 16);
        const int s1g = (int)(v1.x & 0xFFFFu);
        t1g = (int)(v1.x >> 16);
        const int d0g = dstS[sl0];
        d1g = dstS[sl1];
        const uint4* pA0 = (const uint4*)(Abf + (size_t)s0g * DH + 32 * q);
        const uint4* pB0 = (const uint4*)(Bbf + (size_t)d0g * DH + 32 * q);
        const uint4* pT0 = (const uint4*)(Tbf + (size_t)t0g * DH + 32 * q);
        const uint4* pA1 = (const uint4*)(Abf + (size_t)s1g * DH + 32 * q);
#pragma unroll
        for (int i = 0; i < 4; ++i) {
            a0[i] = pA0[i]; b0[i] = pB0[i]; t0v[i] = pT0[i]; a1[i] = pA1[i];
        }
    }

    // stage W2f -> LDS (coalesced, once per block)
    {
        const uint4* s4 = (const uint4*)W2f;
        uint4* d4 = (uint4*)sW2f;
#pragma unroll
        for (int i = 0; i < 8; ++i) d4[tid + 256 * i] = s4[tid + 256 * i];
    }
    // zero ldsAgg
    {
        const float4 z = make_float4(0.f, 0.f, 0.f, 0.f);
        float4* za = (float4*)&ldsAgg[0][0];
#pragma unroll
        for (int i = 0; i < 4; ++i) za[tid + 256 * i] = z;
    }

    // staging
    if (tid < EB) {
        const int slot = e0 + tid;
        int s = 0, d = 0, ti = 0;
        float w = 0.f;
        if (slot < E) {
            if (sorted) {
                const uint2 v = spk[slot];
                d = dstS[slot];
                w = __uint_as_float(v.y);
                if (pack) { s = (int)(v.x & 0xFFFFu); ti = (int)(v.x >> 16); }
                else {
                    s = (int)v.x;
                    const float2 xs = *(const float2*)(x + 2 * s);
                    const float2 xd = *(const float2*)(x + 2 * d);
                    const float dxv = xs.x - xd.x, dyv = xs.y - xd.y;
                    const float r = sqrtf(dxv * dxv + dyv * dyv + 1e-8f);
                    ti = min((int)(r * 724.0773439350246f + 0.5f), NTAB - 1);
                }
            } else {
                const int is64 = detect64(ei);
                s = load_src(ei, is64, slot, E);
                d = load_dst(ei, is64, slot, E);
                w = ew[slot];
                const float2 xs = *(const float2*)(x + 2 * s);
                const float2 xd = *(const float2*)(x + 2 * d);
                const float dxv = xs.x - xd.x, dyv = xs.y - xd.y;
                const float r = sqrtf(dxv * dxv + dyv * dyv + 1e-8f);
                ti = min((int)(r * 724.0773439350246f + 0.5f), NTAB - 1);
            }
        } else {
            d = sorted ? dstS[E - 1] : load_dst(ei, detect64(ei), E - 1, E);
        }
        sSrc[tid] = s; sDst[tid] = d; sEw[tid] = w; sTi[tid] = ti;
    }
    __syncthreads();

    // lid segment scan
    int bflag = 0, incl = 0;
    if (tid < EB) {
        bflag = (tid > 0) && (sDst[tid] != sDst[tid - 1]);
        incl = bflag;
#pragma unroll
        for (int dd = 1; dd < 64; dd <<= 1) {
            int t = __shfl_up(incl, dd, 64);
            if ((tid & 63) >= dd) incl += t;
        }
    }
    if (tid == 63) sW0tot = incl;
    __syncthreads();
    if (tid >= 64 && tid < EB) incl += sW0tot;
    if (tid < EB) {
        sLid[tid] = incl;
        if ((bflag || tid == 0) && incl < SEGCAP) sSegStart[incl] = tid;
        if (tid == EB - 1) sNseg = incl + 1;
    }
    __syncthreads();

    // ---- barrier-free wave section ----
    if (!fast) {
        const int le0 = wbase + e4;
        const int s0g = sSrc[le0], d0g = sDst[le0], t0g = sTi[le0];
        const uint4* pA0 = (const uint4*)(Abf + (size_t)s0g * DH + 32 * q);
        const uint4* pB0 = (const uint4*)(Bbf + (size_t)d0g * DH + 32 * q);
        const uint4* pT0 = (const uint4*)(Tbf + (size_t)t0g * DH + 32 * q);
#pragma unroll
        for (int i = 0; i < 4; ++i) { a0[i] = pA0[i]; b0[i] = pB0[i]; t0v[i] = pT0[i]; }
        const int le1 = wbase + 16 + e4;
        const int s1g = sSrc[le1];
        d1g = sDst[le1]; t1g = sTi[le1];
        const uint4* pA1 = (const uint4*)(Abf + (size_t)s1g * DH + 32 * q);
#pragma unroll
        for (int i = 0; i < 4; ++i) a1[i] = pA1[i];
    }

    float bc8[8];
#pragma unroll
    for (int ni = 0; ni < 8; ++ni) bc8[ni] = bm2[ni * 16 + lr];

    union FragU { unsigned u[4]; short8 s8; };
    ushort_t* slice = &sHid[wv][0];
    floatx4 acc[8];

#define BUILD_HID(aA, bB, tT)                                                   \
    {                                                                           \
        uint4* rowp = (uint4*)(slice + e4 * DH);                                \
        const int swzw = e4 & 7;                                                \
        _Pragma("unroll")                                                       \
        for (int i = 0; i < 4; ++i) {                                           \
            const uint4 a = aA[i]; const uint4 b = bB[i]; const uint4 t = tT[i];\
            const float v0 = bflo(a.x) + bflo(b.x) + bflo(t.x);                 \
            const float v1 = bfhi(a.x) + bfhi(b.x) + bfhi(t.x);                 \
            const float v2 = bflo(a.y) + bflo(b.y) + bflo(t.y);                 \
            const float v3 = bfhi(a.y) + bfhi(b.y) + bfhi(t.y);                 \
            const float v4 = bflo(a.z) + bflo(b.z) + bflo(t.z);                 \
            const float v5 = bfhi(a.z) + bfhi(b.z) + bfhi(t.z);                 \
            const float v6 = bflo(a.w) + bflo(b.w) + bflo(t.w);                 \
            const float v7 = bfhi(a.w) + bfhi(b.w) + bfhi(t.w);                 \
            uint4 pk;                                                           \
            pk.x = pk_bf16(silu_f(v0), silu_f(v1));                             \
            pk.y = pk_bf16(silu_f(v2), silu_f(v3));                             \
            pk.z = pk_bf16(silu_f(v4), silu_f(v5));                             \
            pk.w = pk_bf16(silu_f(v6), silu_f(v7));                             \
            rowp[(4 * q + i) ^ swzw] = pk;                                      \
        }                                                                       \
    }

#define MFMA_ST()                                                               \
    {                                                                           \
        _Pragma("unroll")                                                       \
        for (int ni = 0; ni < 8; ++ni) acc[ni] = (floatx4){0.f, 0.f, 0.f, 0.f}; \
        _Pragma("unroll")                                                       \
        for (int kc = 0; kc < 4; ++kc) {                                        \
            const int bo1 = 64 * kc + 8 * lg;                                   \
            const int bo2 = bo1 + 32;                                           \
            const char* rbase = (const char*)(slice + lr * DH);                 \
            const int swzf = (lr & 7) << 4;                                     \
            FragU af;                                                           \
            const uint2 lo = *(const uint2*)(rbase + ((bo1 & ~15) ^ swzf) + (bo1 & 15)); \
            const uint2 hi = *(const uint2*)(rbase + ((bo2 & ~15) ^ swzf) + (bo2 & 15)); \
            af.u[0] = lo.x; af.u[1] = lo.y; af.u[2] = hi.x; af.u[3] = hi.y;     \
            const ushort_t* wb2 = sW2f + ((kc * 4 + lg) * 128 + lr) * 8;        \
            __builtin_amdgcn_s_setprio(1);                                      \
            _Pragma("unroll")                                                   \
            for (int ni = 0; ni < 8; ++ni) {                                    \
                const short8 bf = *(const short8*)(wb2 + ni * 128);             \
                acc[ni] = __builtin_amdgcn_mfma_f32_16x16x32_bf16(af.s8, bf, acc[ni], 0, 0, 0); \
            }                                                                   \
            __builtin_amdgcn_s_setprio(0);                                      \
        }                                                                       \
    }

#define PHASE3(ST)                                                              \
    {                                                                           \
        const int sb = wbase + (ST) * 16 + 4 * lg;                              \
        int lid4[4]; float ew4[4];                                              \
        _Pragma("unroll")                                                       \
        for (int r = 0; r < 4; ++r) { lid4[r] = sLid[sb + r]; ew4[r] = sEw[sb + r]; } \
        _Pragma("unroll")                                                       \
        for (int ni = 0; ni < 8; ++ni) {                                        \
            const int col = ni * 16 + lr;                                       \
            const float bc = bc8[ni];                                           \
            int cur = lid4[0], curSlot = sb;                                    \
            float av = (acc[ni][0] + bc) * ew4[0];                              \
            _Pragma("unroll")                                                   \
            for (int r = 1; r < 4; ++r) {                                       \
                const int l2 = lid4[r];                                         \
                const float v = (acc[ni][r] + bc) * ew4[r];                     \
                if (l2 == cur) av += v;                                         \
                else {                                                          \
                    if (cur < SEGCAP) atomicAdd(&ldsAgg[cur][col], av);         \
                    else atomicAdd(agg + (size_t)sDst[curSlot] * DH + col, av); \
                    cur = l2; curSlot = sb + r; av = v;                         \
                }                                                               \
            }                                                                   \
            if (cur < SEGCAP) atomicAdd(&ldsAgg[cur][col], av);                 \
            else atomicAdd(agg + (size_t)sDst[curSlot] * DH + col, av);         \
        }                                                                       \
    }

    // ---- subtile 0 ----
    BUILD_HID(a0, b0, t0v);
    MFMA_ST();
    {   // issue st1 B/T (L2-hot) under st0's scatter
        const uint4* pB1 = (const uint4*)(Bbf + (size_t)d1g * DH + 32 * q);
        const uint4* pT1 = (const uint4*)(Tbf + (size_t)t1g * DH + 32 * q);
#pragma unroll
        for (int i = 0; i < 4; ++i) { b1[i] = pB1[i]; t1v[i] = pT1[i]; }
    }
    PHASE3(0);

    // ---- subtile 1 ----
    BUILD_HID(a1, b1, t1v);
    MFMA_ST();
    PHASE3(1);

    __syncthreads();

    // flush
    const int ns = sNseg;
    const int gmax = (ns < SEGCAP) ? ns : SEGCAP;
    for (int idx = tid; idx < (gmax << 7); idx += 256) {
        const int g = idx >> 7, col = idx & 127;
        const float v = ldsAgg[g][col];
        const int dst = sDst[sSegStart[g]];
        float* p = agg + (size_t)dst * DH + col;
        if (sorted && g > 0 && g < ns - 1) *p = v;
        else atomicAdd(p, v);
    }
#undef BUILD_HID
#undef MFMA_ST
#undef PHASE3
}

// ---------------------------------------------------------------------------
// Node MLP via MFMA + residual + LayerNorm.
// ---------------------------------------------------------------------------
__global__ __launch_bounds__(256) void k_node(
    const float* __restrict__ h, const float* __restrict__ agg,
    const ushort_t* __restrict__ W1hf, const float* __restrict__ bh1,
    const ushort_t* __restrict__ W2hf, const float* __restrict__ bh2,
    const float* __restrict__ ln_g, const float* __restrict__ ln_b,
    float* __restrict__ out, int N)
{
    __shared__ __align__(16) ushort_t sIn[64 * 256];
    __shared__ __align__(16) ushort_t sHid[64 * DH];
    const int tid = threadIdx.x;
    const int nblk = blockIdx.x * 64;

    {
        const int row = tid >> 2, q = tid & 3;
        const int gn = nblk + row;
        const float4* ps = (q < 2) ? (const float4*)(h + (size_t)gn * DH + 64 * q)
                                   : (const float4*)(agg + (size_t)gn * DH + 64 * (q - 2));
        uint4* rowp = (uint4*)(sIn + row * 256);
        const int swz = row & 7;
#pragma unroll
        for (int i = 0; i < 8; ++i) {
            uint4 o = make_uint4(0, 0, 0, 0);
            if (gn < N) {
                const float4 g0 = ps[2 * i], g1 = ps[2 * i + 1];
                o.x = pk_bf16(g0.x, g0.y); o.y = pk_bf16(g0.z, g0.w);
                o.z = pk_bf16(g1.x, g1.y); o.w = pk_bf16(g1.z, g1.w);
            }
            rowp[(8 * q + i) ^ swz] = o;
        }
    }
    __syncthreads();

    const int lane = tid & 63, wv = tid >> 6;
    const int lr = lane & 15, lg = lane >> 4;
    const int m0l = wv * 16;

    union FragU { unsigned u[4]; short8 s8; };

    floatx4 acc[8];
#pragma unroll
    for (int ni = 0; ni < 8; ++ni) acc[ni] = (floatx4){0.f, 0.f, 0.f, 0.f};

#pragma unroll
    for (int kc = 0; kc < 8; ++kc) {
        const int b1 = 64 * kc + 8 * lg;
        const int b2 = b1 + 32;
        const int row = m0l + lr;
        const char* rbase = (const char*)(sIn + row * 256);
        const int swz = (row & 7) << 4;
        FragU af;
        const uint2 lo = *(const uint2*)(rbase + ((b1 & ~15) ^ swz) + (b1 & 15));
        const uint2 hi = *(const uint2*)(rbase + ((b2 & ~15) ^ swz) + (b2 & 15));
        af.u[0] = lo.x; af.u[1] = lo.y; af.u[2] = hi.x; af.u[3] = hi.y;
        const ushort_t* wbase = W1hf + ((size_t)(kc * 4 + lg) * 128 + lr) * 8;
        __builtin_amdgcn_s_setprio(1);
#pragma unroll
        for (int ni = 0; ni < 8; ++ni) {
            const short8 bf = *(const short8*)(wbase + ni * 128);
            acc[ni] = __builtin_amdgcn_mfma_f32_16x16x32_bf16(af.s8, bf, acc[ni], 0, 0, 0);
        }
        __builtin_amdgcn_s_setprio(0);
    }

    {
        float bh1v[8];
#pragma unroll
        for (int ni = 0; ni < 8; ++ni) bh1v[ni] = bh1[ni * 16 + lr];
#pragma unroll
        for (int r = 0; r < 4; ++r) {
            const int row = m0l + 4 * lg + r;
            const int swz = row & 7;
            ushort_t* rp = sHid + row * DH;
#pragma unroll
            for (int ni = 0; ni < 8; ++ni) {
                const int col = ni * 16 + lr;
                rp[(((col >> 3) ^ swz) << 3) + (col & 7)] =
                    f2bf1(silu_f(acc[ni][r] + bh1v[ni]));
            }
        }
    }

    floatx4 acc2[8];
#pragma unroll
    for (int ni = 0; ni < 8; ++ni) acc2[ni] = (floatx4){0.f, 0.f, 0.f, 0.f};

#pragma unroll
    for (int kc = 0; kc < 4; ++kc) {
        const int b1 = 64 * kc + 8 * lg;
        const int b2 = b1 + 32;
        const int row = m0l + lr;
        const char* rbase = (const char*)(sHid + row * DH);
        const int swz = (row & 7) << 4;
        FragU af;
        const uint2 lo = *(const uint2*)(rbase + ((b1 & ~15) ^ swz) + (b1 & 15));
        const uint2 hi = *(const uint2*)(rbase + ((b2 & ~15) ^ swz) + (b2 & 15));
        af.u[0] = lo.x; af.u[1] = lo.y; af.u[2] = hi.x; af.u[3] = hi.y;
        const ushort_t* wbase = W2hf + ((size_t)(kc * 4 + lg) * 128 + lr) * 8;
        __builtin_amdgcn_s_setprio(1);
#pragma unroll
        for (int ni = 0; ni < 8; ++ni) {
            const short8 bf = *(const short8*)(wbase + ni * 128);
            acc2[ni] = __builtin_amdgcn_mfma_f32_16x16x32_bf16(af.s8, bf, acc2[ni], 0, 0, 0);
        }
        __builtin_amdgcn_s_setprio(0);
    }

    float gv[8], bv[8], b2v[8];
#pragma unroll
    for (int ni = 0; ni < 8; ++ni) {
        const int col = ni * 16 + lr;
        gv[ni] = ln_g[col]; bv[ni] = ln_b[col]; b2v[ni] = bh2[col];
    }
#pragma unroll
    for (int r = 0; r < 4; ++r) {
        const int row = m0l + 4 * lg + r;
        const int gn = nblk + row;
        const int swz = row & 7;
        float z[8];
        float s1 = 0.f, s2 = 0.f;
#pragma unroll
        for (int ni = 0; ni < 8; ++ni) {
            const int col = ni * 16 + lr;
            const float hv = bf2f(sIn[row * 256 + (((col >> 3) ^ swz) << 3) + (col & 7)]);
            z[ni] = acc2[ni][r] + b2v[ni] + hv;
            s1 += z[ni]; s2 += z[ni] * z[ni];
        }
#pragma unroll
        for (int m = 1; m < 16; m <<= 1) {
            s1 += __shfl_xor(s1, m, 64);
            s2 += __shfl_xor(s2, m, 64);
        }
        const float mean = s1 * (1.f / 128.f);
        const float var = s2 * (1.f / 128.f) - mean * mean;
        const float rstd = rsqrtf(var + 1e-5f);
        if (gn < N) {
#pragma unroll
            for (int ni = 0; ni < 8; ++ni) {
                const int col = ni * 16 + lr;
                out[(size_t)gn * DH + col] = (z[ni] - mean) * rstd * gv[ni] + bv[ni];
            }
        }
    }
}

extern "C" void kernel_launch(void* const* d_in, const int* in_sizes, int n_in,
                              void* d_out, int out_size, void* d_ws, size_t ws_size,
                              hipStream_t stream)
{
    (void)n_in; (void)out_size;
    const float* h   = (const float*)d_in[0];
    const float* x   = (const float*)d_in[1];
    const int*   ei  = (const int*)d_in[2];
    const float* ew  = (const float*)d_in[3];
    const float* Wm1 = (const float*)d_in[4];
    const float* bm1 = (const float*)d_in[5];
    const float* Wm2 = (const float*)d_in[6];
    const float* bm2 = (const float*)d_in[7];
    const float* Wh1 = (const float*)d_in[8];
    const float* bh1 = (const float*)d_in[9];
    const float* Wh2 = (const float*)d_in[10];
    const float* bh2 = (const float*)d_in[11];
    const float* lng = (const float*)d_in[12];
    const float* lnb = (const float*)d_in[13];
    float* out = (float*)d_out;

    const int N = in_sizes[0] / DH;
    const int E = in_sizes[3];

    float*    agg  = (float*)d_ws;
    ushort_t* Abf  = (ushort_t*)(agg + (size_t)N * DH);
    ushort_t* Bbf  = Abf + (size_t)N * DH;
    ushort_t* W2f  = Bbf + (size_t)N * DH;
    ushort_t* Tbf  = W2f + 16384;
    ushort_t* W1mf = Tbf + (size_t)NTAB * DH;
    ushort_t* W1hf = W1mf + 32768;
    ushort_t* W2hf = W1hf + 32768;
    int*   counts  = (int*)(W2hf + 16384);
    int*   cursor  = counts + N;
    uint2* spk     = (uint2*)(cursor + N);
    int*   dstS    = (int*)(spk + E);

    const size_t mand = (size_t)N * DH * 4 + (size_t)N * DH * 4
                      + ((size_t)16384 + (size_t)NTAB * DH + 32768 + 32768 + 16384) * 2;
    const size_t need = mand + (size_t)(2 * N) * 4 + (size_t)E * 12 + 64;
    const int use_sort = (ws_size >= need) ? 1 : 0;
    const int pack = use_sort && (N <= 65535);

    const int nb_hist = use_sort ? (E + 255) / 256 : 0;
    const int nb_prep = 257 + 8 + 16 + 16 + 8;
    const int nb_scat = nb_hist;
    const int nb_pre  = (N + 63) / 64;

    hipMemsetAsync(agg, 0, (size_t)N * DH * sizeof(float), stream);
    if (use_sort)
        hipMemsetAsync(counts, 0, (size_t)N * sizeof(int), stream);
    k_hist_prep<<<nb_hist + nb_prep, 256, 0, stream>>>(ei, counts, E, Wm1, Wm2, Wh1, Wh2,
                                                       Tbf, W2f, W1mf, W1hf, W2hf, nb_hist);
    if (use_sort)
        k_scan<<<1, 1024, 0, stream>>>(counts, cursor, N);
    k_scatter_pre<<<nb_scat + nb_pre, 256, 0, stream>>>(ei, ew, x, cursor, spk, dstS, E, pack,
                                                        h, bm1, W1mf, Abf, Bbf, N, nb_scat);
    k_edge<<<(E + EB - 1) / EB, 256, 0, stream>>>(x, ei, ew, spk, dstS,
                                                  W2f, bm2, Abf, Bbf, Tbf, agg,
                                                  use_sort, pack, N, E);
    k_node<<<(N + 63) / 64, 256, 0, stream>>>(h, agg, W1hf, bh1, W2hf, bh2, lng, lnb, out, N);
}